// Round 2
// baseline (449.503 us; speedup 1.0000x reference)
//
#include <hip/hip_runtime.h>
#include <hip/hip_bf16.h>

// TSP decoder forward: B=64, POMO=200, N=1000, EMB=128, H=8, D=16.
// Pipeline: k1 proj K/V + nodes->f16 | k2 q=q_first+q_last(+LoRA) |
// k3 per-(b,h) attention (K/V in LDS, f16 fdot2) | k4 combine(+LoRA) |
// k5 mh@nodes^T + 10*tanh + mask + softmax.

typedef _Float16 f16;
typedef _Float16 f16x2 __attribute__((ext_vector_type(2)));
typedef _Float16 f16x8 __attribute__((ext_vector_type(8)));

#define LORA_SCALE 1.0f

__device__ __forceinline__ f16x2 pk2(f16 a, f16 b){ f16x2 r; r[0]=a; r[1]=b; return r; }

#if __has_builtin(__builtin_amdgcn_fdot2)
__device__ __forceinline__ float fdot2f(f16x2 a, f16x2 b, float c){ return __builtin_amdgcn_fdot2(a, b, c, false); }
#else
__device__ __forceinline__ float fdot2f(f16x2 a, f16x2 b, float c){ return c + (float)a[0]*(float)b[0] + (float)a[1]*(float)b[1]; }
#endif

#if __has_builtin(__builtin_amdgcn_cvt_pkrtz)
__device__ __forceinline__ f16x2 pkrtz(float a, float b){
  return __builtin_bit_cast(f16x2, __builtin_amdgcn_cvt_pkrtz(a, b));
}
#else
__device__ __forceinline__ f16x2 pkrtz(float a, float b){ return pk2((f16)a, (f16)b); }
#endif

__device__ __forceinline__ float dot8f(f16x8 a, f16x8 b, float c){
  c = fdot2f(pk2(a[0],a[1]), pk2(b[0],b[1]), c);
  c = fdot2f(pk2(a[2],a[3]), pk2(b[2],b[3]), c);
  c = fdot2f(pk2(a[4],a[5]), pk2(b[4],b[5]), c);
  c = fdot2f(pk2(a[6],a[7]), pk2(b[6],b[7]), c);
  return c;
}

__device__ __forceinline__ float wave_max(float v){
  #pragma unroll
  for (int off = 32; off; off >>= 1) v = fmaxf(v, __shfl_xor(v, off, 64));
  return v;
}
__device__ __forceinline__ float wave_sum(float v){
  #pragma unroll
  for (int off = 32; off; off >>= 1) v += __shfl_xor(v, off, 64);
  return v;
}

// ---------------- k1: K/V projection + nodes -> f16 ----------------
// grid (25, 64), 256 thr. Tile = 40 node rows.
// Kp layout: [bh][plane(2)][n(1000)][8]  (two 8-dim planes -> 16B-stride LDS reads later)
// Vt layout: [bh][d(16)][n(1000)]        (transposed for PV phase)
#define K1_TILE 40
__global__ __launch_bounds__(256) void k1_proj(const float* __restrict__ nodes,
    const float* __restrict__ Wk, const float* __restrict__ Wv,
    f16* __restrict__ nodesF, f16* __restrict__ Kp, f16* __restrict__ Vt)
{
  __shared__ f16 lds[K1_TILE*128];
  const int tid = threadIdx.x;
  const int b = blockIdx.y;
  const int n0 = blockIdx.x * K1_TILE;
  {
    const float4* src = (const float4*)(nodes + ((size_t)b*1000 + n0)*128);
    f16x2* l2 = (f16x2*)lds;
    f16x2* nd = (f16x2*)(nodesF + ((size_t)b*1000 + n0)*128);
    for (int i = tid; i < K1_TILE*32; i += 256) {
      float4 v = src[i];
      f16x2 lo = pkrtz(v.x, v.y), hi = pkrtz(v.z, v.w);
      l2[2*i] = lo; l2[2*i+1] = hi;
      nd[2*i] = lo; nd[2*i+1] = hi;
    }
  }
  __syncthreads();
  const int col = tid;
  const bool isv = col >= 128;
  const int c = col & 127;
  const float* wrow = (isv ? Wv : Wk) + c*128;
  float acc[K1_TILE];
  #pragma unroll
  for (int r = 0; r < K1_TILE; ++r) acc[r] = 0.f;
  for (int c0 = 0; c0 < 128; c0 += 16) {
    float4 w0 = *(const float4*)(wrow + c0);
    float4 w1 = *(const float4*)(wrow + c0 + 4);
    float4 w2 = *(const float4*)(wrow + c0 + 8);
    float4 w3 = *(const float4*)(wrow + c0 + 12);
    f16x2 wv[8] = { pkrtz(w0.x,w0.y), pkrtz(w0.z,w0.w), pkrtz(w1.x,w1.y), pkrtz(w1.z,w1.w),
                    pkrtz(w2.x,w2.y), pkrtz(w2.z,w2.w), pkrtz(w3.x,w3.y), pkrtz(w3.z,w3.w) };
    #pragma unroll
    for (int r = 0; r < K1_TILE; ++r) {
      const f16x8* lr = (const f16x8*)(lds + r*128 + c0);
      f16x8 a0 = lr[0], a1 = lr[1];
      float s = acc[r];
      s = fdot2f(pk2(a0[0],a0[1]), wv[0], s);
      s = fdot2f(pk2(a0[2],a0[3]), wv[1], s);
      s = fdot2f(pk2(a0[4],a0[5]), wv[2], s);
      s = fdot2f(pk2(a0[6],a0[7]), wv[3], s);
      s = fdot2f(pk2(a1[0],a1[1]), wv[4], s);
      s = fdot2f(pk2(a1[2],a1[3]), wv[5], s);
      s = fdot2f(pk2(a1[4],a1[5]), wv[6], s);
      s = fdot2f(pk2(a1[6],a1[7]), wv[7], s);
      acc[r] = s;
    }
  }
  const int bh = b*8 + (c >> 4);
  const int d = c & 15;
  if (!isv) {
    f16* dst = Kp + (((size_t)bh*2 + (d>>3))*1000)*8 + (d & 7);
    #pragma unroll
    for (int r = 0; r < K1_TILE; ++r) dst[(size_t)(n0+r)*8] = (f16)acc[r];
  } else {
    f16* dst = Vt + ((size_t)bh*16 + d)*1000;
    #pragma unroll
    for (int r = 0; r < K1_TILE; ++r) dst[n0 + r] = (f16)acc[r];
  }
}

// ---------------- k2: q = q1@Wqf^T + last@Wql^T + LoRA ----------------
// grid 400, 256 thr, 32 rows/block. qF layout: [bh][m(200)][16]
__global__ __launch_bounds__(256) void k2_q(const float* __restrict__ q1,
    const float* __restrict__ last, const float* __restrict__ Wqf,
    const float* __restrict__ Wql, const float* __restrict__ lqA,
    const float* __restrict__ lqB, f16* __restrict__ qF)
{
  __shared__ f16 q1r[32*128];
  __shared__ f16 lar[32*128];
  __shared__ float t16[32*16];
  const int tid = threadIdx.x;
  const int row0 = blockIdx.x * 32;
  {
    const float4* s1 = (const float4*)(q1 + (size_t)row0*128);
    const float4* s2 = (const float4*)(last + (size_t)row0*128);
    f16x2* d1 = (f16x2*)q1r; f16x2* d2 = (f16x2*)lar;
    for (int i = tid; i < 32*32; i += 256) {
      float4 v = s1[i];
      d1[2*i] = pkrtz(v.x,v.y); d1[2*i+1] = pkrtz(v.z,v.w);
      float4 u = s2[i];
      d2[2*i] = pkrtz(u.x,u.y); d2[2*i+1] = pkrtz(u.z,u.w);
    }
  }
  __syncthreads();
  for (int idx = tid; idx < 32*16; idx += 256) {
    const int r = idx >> 4, kk = idx & 15;
    const f16x8* lrow = (const f16x8*)(lar + r*128);
    const float* arow = lqA + kk*128;
    float s = 0.f;
    #pragma unroll
    for (int cc = 0; cc < 16; ++cc) {
      f16x8 a = lrow[cc];
      float4 wa = *(const float4*)(arow + cc*8);
      float4 wb = *(const float4*)(arow + cc*8 + 4);
      s = fdot2f(pk2(a[0],a[1]), pkrtz(wa.x,wa.y), s);
      s = fdot2f(pk2(a[2],a[3]), pkrtz(wa.z,wa.w), s);
      s = fdot2f(pk2(a[4],a[5]), pkrtz(wb.x,wb.y), s);
      s = fdot2f(pk2(a[6],a[7]), pkrtz(wb.z,wb.w), s);
    }
    t16[idx] = s;
  }
  __syncthreads();
  const int c = tid & 127, rg = tid >> 7, rb = rg*16;
  float acc[16];
  #pragma unroll
  for (int r = 0; r < 16; ++r) acc[r] = 0.f;
  const float* wfr = Wqf + c*128;
  const float* wlr = Wql + c*128;
  for (int c0 = 0; c0 < 128; c0 += 16) {
    float4 f0 = *(const float4*)(wfr + c0);
    float4 f1 = *(const float4*)(wfr + c0 + 4);
    float4 f2 = *(const float4*)(wfr + c0 + 8);
    float4 f3 = *(const float4*)(wfr + c0 + 12);
    f16x2 wf[8] = { pkrtz(f0.x,f0.y), pkrtz(f0.z,f0.w), pkrtz(f1.x,f1.y), pkrtz(f1.z,f1.w),
                    pkrtz(f2.x,f2.y), pkrtz(f2.z,f2.w), pkrtz(f3.x,f3.y), pkrtz(f3.z,f3.w) };
    float4 g0 = *(const float4*)(wlr + c0);
    float4 g1 = *(const float4*)(wlr + c0 + 4);
    float4 g2 = *(const float4*)(wlr + c0 + 8);
    float4 g3 = *(const float4*)(wlr + c0 + 12);
    f16x2 wl[8] = { pkrtz(g0.x,g0.y), pkrtz(g0.z,g0.w), pkrtz(g1.x,g1.y), pkrtz(g1.z,g1.w),
                    pkrtz(g2.x,g2.y), pkrtz(g2.z,g2.w), pkrtz(g3.x,g3.y), pkrtz(g3.z,g3.w) };
    #pragma unroll
    for (int r = 0; r < 16; ++r) {
      const f16x8* qp = (const f16x8*)(q1r + (rb+r)*128 + c0);
      const f16x8* lp = (const f16x8*)(lar + (rb+r)*128 + c0);
      f16x8 a0 = qp[0], a1 = qp[1], b0 = lp[0], b1 = lp[1];
      float s = acc[r];
      s = fdot2f(pk2(a0[0],a0[1]), wf[0], s);
      s = fdot2f(pk2(a0[2],a0[3]), wf[1], s);
      s = fdot2f(pk2(a0[4],a0[5]), wf[2], s);
      s = fdot2f(pk2(a0[6],a0[7]), wf[3], s);
      s = fdot2f(pk2(a1[0],a1[1]), wf[4], s);
      s = fdot2f(pk2(a1[2],a1[3]), wf[5], s);
      s = fdot2f(pk2(a1[4],a1[5]), wf[6], s);
      s = fdot2f(pk2(a1[6],a1[7]), wf[7], s);
      s = fdot2f(pk2(b0[0],b0[1]), wl[0], s);
      s = fdot2f(pk2(b0[2],b0[3]), wl[1], s);
      s = fdot2f(pk2(b0[4],b0[5]), wl[2], s);
      s = fdot2f(pk2(b0[6],b0[7]), wl[3], s);
      s = fdot2f(pk2(b1[0],b1[1]), wl[4], s);
      s = fdot2f(pk2(b1[2],b1[3]), wl[5], s);
      s = fdot2f(pk2(b1[4],b1[5]), wl[6], s);
      s = fdot2f(pk2(b1[6],b1[7]), wl[7], s);
      acc[r] = s;
    }
  }
  const float* lb = lqB + c*16;
  float lbv[16];
  #pragma unroll
  for (int i = 0; i < 16; i += 4) {
    float4 t = *(const float4*)(lb + i);
    lbv[i] = t.x; lbv[i+1] = t.y; lbv[i+2] = t.z; lbv[i+3] = t.w;
  }
  #pragma unroll
  for (int r = 0; r < 16; ++r) {
    float dl = 0.f;
    #pragma unroll
    for (int kk = 0; kk < 16; ++kk) dl += t16[(rb+r)*16 + kk] * lbv[kk];
    acc[r] += dl * LORA_SCALE;
  }
  const int h = c >> 4, d = c & 15;
  #pragma unroll
  for (int r = 0; r < 16; ++r) {
    const int grow = row0 + rb + r;
    const int b = grow / 200, m = grow % 200;
    qF[(((size_t)b*8 + h)*200 + m)*16 + d] = (f16)acc[r];
  }
}

// ---------------- k3: per-(b,h) attention ----------------
// grid (8, 64), 256 thr (4 waves, 50 rows each). LDS 72000 B dynamic.
__global__ __launch_bounds__(256) void k3_attn(const f16* __restrict__ Kp,
    const f16* __restrict__ Vt, const f16* __restrict__ qF,
    const float* __restrict__ mask, f16* __restrict__ ocF)
{
  extern __shared__ char smem[];
  f16* Kl = (f16*)smem;             // 32000 B: plane lo [1000][8] | plane hi [1000][8]
  f16* Vl = (f16*)(smem + 32000);   // 32000 B: [16][1000]
  f16* pb = (f16*)(smem + 64000);   //  8000 B: per-wave P [4][1000]
  const int tid = threadIdx.x;
  const int lane = tid & 63, w = tid >> 6;
  const int h = blockIdx.x, b = blockIdx.y;
  const int bh = b*8 + h;
  {
    const f16x8* sK = (const f16x8*)(Kp + (size_t)bh*16000);
    const f16x8* sV = (const f16x8*)(Vt + (size_t)bh*16000);
    f16x8* dK = (f16x8*)Kl;
    f16x8* dV = (f16x8*)Vl;
    for (int i = tid; i < 2000; i += 256) { dK[i] = sK[i]; dV[i] = sV[i]; }
  }
  __syncthreads();
  const f16x8* Klo = (const f16x8*)Kl;
  const f16x8* Khi = (const f16x8*)(Kl + 8000);
  const float* maskb = mask + (size_t)b*200000;
  const f16x2* q2 = (const f16x2*)(qF + (size_t)bh*3200);
  f16* pw = pb + w*1000;
  const int d = lane & 15, g = lane >> 4;
  const f16x2* vrow = (const f16x2*)(Vl + d*1000);
  const f16x2* prow = (const f16x2*)pw;
  for (int m = w; m < 200; m += 4) {
    f16x2 qv[8];
    #pragma unroll
    for (int i = 0; i < 8; ++i) qv[i] = q2[m*8 + i];
    float s[16];
    #pragma unroll
    for (int j = 0; j < 16; ++j) {
      const int n = j*64 + lane;
      if (n < 1000) {
        f16x8 k0 = Klo[n], k1 = Khi[n];
        float t = 0.f;
        t = fdot2f(pk2(k0[0],k0[1]), qv[0], t);
        t = fdot2f(pk2(k0[2],k0[3]), qv[1], t);
        t = fdot2f(pk2(k0[4],k0[5]), qv[2], t);
        t = fdot2f(pk2(k0[6],k0[7]), qv[3], t);
        t = fdot2f(pk2(k1[0],k1[1]), qv[4], t);
        t = fdot2f(pk2(k1[2],k1[3]), qv[5], t);
        t = fdot2f(pk2(k1[4],k1[5]), qv[6], t);
        t = fdot2f(pk2(k1[6],k1[7]), qv[7], t);
        s[j] = t*0.25f + maskb[(size_t)m*1000 + n];
      } else s[j] = -1e30f;
    }
    float M = -1e30f;
    #pragma unroll
    for (int j = 0; j < 16; ++j) M = fmaxf(M, s[j]);
    M = wave_max(M);
    float lsum = 0.f;
    #pragma unroll
    for (int j = 0; j < 16; ++j) {
      const int n = j*64 + lane;
      if (n < 1000) {
        float p = exp2f((s[j]-M)*1.44269504f);
        pw[n] = (f16)p;
        lsum += p;
      }
    }
    float S = wave_sum(lsum);
    float inv = 1.0f / S;
    float acc = 0.f;
    #pragma unroll 5
    for (int k = 0; k < 125; ++k) {
      const int pp = g + 4*k;       // pair index; n = {2pp, 2pp+1}
      acc = fdot2f(prow[pp], vrow[pp], acc);
    }
    acc += __shfl_xor(acc, 16, 64);
    acc += __shfl_xor(acc, 32, 64);
    if (lane < 16) ocF[((size_t)b*200 + m)*128 + h*16 + d] = (f16)(acc*inv);
  }
}

// ---------------- k4: mh = oc@Wc^T + bc + LoRA ----------------
__global__ __launch_bounds__(256) void k4_comb(const f16* __restrict__ ocF,
    const float* __restrict__ Wc, const float* __restrict__ bc,
    const float* __restrict__ lcA, const float* __restrict__ lcB,
    f16* __restrict__ mhF)
{
  __shared__ f16 ocr[32*128];
  __shared__ float t16[32*16];
  const int tid = threadIdx.x;
  const int row0 = blockIdx.x * 32;
  {
    const f16x8* s1 = (const f16x8*)(ocF + (size_t)row0*128);
    f16x8* d1 = (f16x8*)ocr;
    for (int i = tid; i < 512; i += 256) d1[i] = s1[i];
  }
  __syncthreads();
  for (int idx = tid; idx < 32*16; idx += 256) {
    const int r = idx >> 4, kk = idx & 15;
    const f16x8* lrow = (const f16x8*)(ocr + r*128);
    const float* arow = lcA + kk*128;
    float s = 0.f;
    #pragma unroll
    for (int cc = 0; cc < 16; ++cc) {
      f16x8 a = lrow[cc];
      float4 wa = *(const float4*)(arow + cc*8);
      float4 wb = *(const float4*)(arow + cc*8 + 4);
      s = fdot2f(pk2(a[0],a[1]), pkrtz(wa.x,wa.y), s);
      s = fdot2f(pk2(a[2],a[3]), pkrtz(wa.z,wa.w), s);
      s = fdot2f(pk2(a[4],a[5]), pkrtz(wb.x,wb.y), s);
      s = fdot2f(pk2(a[6],a[7]), pkrtz(wb.z,wb.w), s);
    }
    t16[idx] = s;
  }
  __syncthreads();
  const int c = tid & 127, rg = tid >> 7, rb = rg*16;
  float acc[16];
  const float bias = bc[c];
  #pragma unroll
  for (int r = 0; r < 16; ++r) acc[r] = bias;
  const float* wrow = Wc + c*128;
  for (int c0 = 0; c0 < 128; c0 += 16) {
    float4 w0 = *(const float4*)(wrow + c0);
    float4 w1 = *(const float4*)(wrow + c0 + 4);
    float4 w2 = *(const float4*)(wrow + c0 + 8);
    float4 w3 = *(const float4*)(wrow + c0 + 12);
    f16x2 wv[8] = { pkrtz(w0.x,w0.y), pkrtz(w0.z,w0.w), pkrtz(w1.x,w1.y), pkrtz(w1.z,w1.w),
                    pkrtz(w2.x,w2.y), pkrtz(w2.z,w2.w), pkrtz(w3.x,w3.y), pkrtz(w3.z,w3.w) };
    #pragma unroll
    for (int r = 0; r < 16; ++r) {
      const f16x8* op = (const f16x8*)(ocr + (rb+r)*128 + c0);
      f16x8 a0 = op[0], a1 = op[1];
      float s = acc[r];
      s = fdot2f(pk2(a0[0],a0[1]), wv[0], s);
      s = fdot2f(pk2(a0[2],a0[3]), wv[1], s);
      s = fdot2f(pk2(a0[4],a0[5]), wv[2], s);
      s = fdot2f(pk2(a0[6],a0[7]), wv[3], s);
      s = fdot2f(pk2(a1[0],a1[1]), wv[4], s);
      s = fdot2f(pk2(a1[2],a1[3]), wv[5], s);
      s = fdot2f(pk2(a1[4],a1[5]), wv[6], s);
      s = fdot2f(pk2(a1[6],a1[7]), wv[7], s);
      acc[r] = s;
    }
  }
  const float* lb = lcB + c*16;
  float lbv[16];
  #pragma unroll
  for (int i = 0; i < 16; i += 4) {
    float4 t = *(const float4*)(lb + i);
    lbv[i] = t.x; lbv[i+1] = t.y; lbv[i+2] = t.z; lbv[i+3] = t.w;
  }
  #pragma unroll
  for (int r = 0; r < 16; ++r) {
    float dl = 0.f;
    #pragma unroll
    for (int kk = 0; kk < 16; ++kk) dl += t16[(rb+r)*16 + kk] * lbv[kk];
    acc[r] += dl * LORA_SCALE;
  }
  #pragma unroll
  for (int r = 0; r < 16; ++r) {
    mhF[(size_t)(row0 + rb + r)*128 + c] = (f16)acc[r];
  }
}

// ---------------- k5: probs = softmax(10*tanh(mh@nodes^T / sqrt(128)) + mask) ----------------
// grid (25, 64), 512 thr (8 waves, 1 row each). Node tiles staged in LDS with XOR swizzle.
__global__ __launch_bounds__(512) void k5_final(const f16* __restrict__ mhF,
    const f16* __restrict__ nodesF, const float* __restrict__ mask,
    float* __restrict__ out)
{
  __shared__ f16 mhl[8*128];
  __shared__ f16x8 ntile[1024];   // [64 rows][16 vecs], vec index XOR-swizzled by row
  const int tid = threadIdx.x;
  const int lane = tid & 63, w = tid >> 6;
  const int b = blockIdx.y, m0 = blockIdx.x * 8;
  {
    const f16x8* sm = (const f16x8*)(mhF + ((size_t)b*200 + m0)*128);
    f16x8* dm = (f16x8*)mhl;
    if (tid < 128) dm[tid] = sm[tid];
  }
  __syncthreads();
  f16x8 mv[16];
  {
    const f16x8* mr = (const f16x8*)(mhl + w*128);
    #pragma unroll
    for (int i = 0; i < 16; ++i) mv[i] = mr[i];
  }
  float s[16];
  for (int t = 0; t < 16; ++t) {
    const int nrows = (t < 15) ? 64 : 40;
    __syncthreads();
    const f16x8* sn = (const f16x8*)(nodesF + ((size_t)b*1000 + t*64)*128);
    for (int i = tid; i < nrows*16; i += 512) {
      const int r = i >> 4, cc = i & 15;
      ntile[r*16 + (cc ^ (r & 7))] = sn[i];
    }
    __syncthreads();
    if (lane < nrows) {
      float acc = 0.f;
      #pragma unroll
      for (int cc = 0; cc < 16; ++cc) {
        f16x8 nv = ntile[lane*16 + (cc ^ (lane & 7))];
        acc = dot8f(mv[cc], nv, acc);
      }
      s[t] = acc;
    } else s[t] = 0.f;
  }
  const int m = m0 + w;
  const float* maskb = mask + ((size_t)b*200 + m)*1000;
  const float C1 = 0.08838834764831845f;  // 1/sqrt(128)
  float sc[16];
  #pragma unroll
  for (int t = 0; t < 16; ++t) {
    const int n = t*64 + lane;
    if (n < 1000) {
      float x = s[t] * C1;
      float e = exp2f(x * 2.8853900817779268f);  // 2*log2(e)*x
      float th = 1.f - 2.f/(e + 1.f);
      sc[t] = 10.f*th + maskb[n];
    } else sc[t] = -1e30f;
  }
  float M = -1e30f;
  #pragma unroll
  for (int t = 0; t < 16; ++t) M = fmaxf(M, sc[t]);
  M = wave_max(M);
  float lsum = 0.f;
  #pragma unroll
  for (int t = 0; t < 16; ++t) { sc[t] = exp2f((sc[t]-M)*1.44269504f); lsum += sc[t]; }
  float S = wave_sum(lsum);
  const float inv = 1.f/S;
  float* outb = out + ((size_t)b*200 + m)*1000;
  #pragma unroll
  for (int t = 0; t < 16; ++t) {
    const int n = t*64 + lane;
    if (n < 1000) outb[n] = sc[t]*inv;
  }
}

extern "C" void kernel_launch(void* const* d_in, const int* in_sizes, int n_in,
                              void* d_out, int out_size, void* d_ws, size_t ws_size,
                              hipStream_t stream)
{
  (void)in_sizes; (void)n_in; (void)out_size; (void)ws_size;
  const float* nodes = (const float*)d_in[0];
  const float* q1    = (const float*)d_in[1];
  const float* last  = (const float*)d_in[2];
  const float* mask  = (const float*)d_in[3];
  const float* Wqf   = (const float*)d_in[4];
  const float* Wql   = (const float*)d_in[5];
  const float* Wk    = (const float*)d_in[6];
  const float* Wv    = (const float*)d_in[7];
  const float* Wc    = (const float*)d_in[8];
  const float* bc    = (const float*)d_in[9];
  const float* lqA   = (const float*)d_in[10];
  const float* lqB   = (const float*)d_in[11];
  const float* lcA   = (const float*)d_in[12];
  const float* lcB   = (const float*)d_in[13];
  float* out = (float*)d_out;
  char* ws = (char*)d_ws;
  // ws layout (bytes):
  f16* nodesF = (f16*)(ws);               // 16,384,000
  f16* Kp     = (f16*)(ws + 16384000);    // 16,384,000
  f16* Vt     = (f16*)(ws + 32768000);    // 16,384,000
  f16* qF     = (f16*)(ws + 49152000);    //  3,276,800
  f16* ocF    = (f16*)(ws + 52428800);    //  3,276,800
  f16* mhF    = (f16*)(ws + 55705600);    //  3,276,800  (end 58,982,400)

  k1_proj<<<dim3(25, 64), 256, 0, stream>>>(nodes, Wk, Wv, nodesF, Kp, Vt);
  k2_q<<<dim3(400), 256, 0, stream>>>(q1, last, Wqf, Wql, lqA, lqB, qF);
  k3_attn<<<dim3(8, 64), 256, 72000, stream>>>(Kp, Vt, qF, mask, ocF);
  k4_comb<<<dim3(400), 256, 0, stream>>>(ocF, Wc, bc, lcA, lcB, mhF);
  k5_final<<<dim3(25, 64), 512, 0, stream>>>(mhF, nodesF, mask, out);
}

// Round 3
// 316.085 us; speedup vs baseline: 1.4221x; 1.4221x over previous
//
#include <hip/hip_runtime.h>
#include <hip/hip_bf16.h>

// TSP decoder forward: B=64, POMO=200, N=1000, EMB=128, H=8, D=16.
// k1 proj K/V + nodes->f16 | k2 q (+LoRA) | k3 MFMA flash attention |
// k4 combine (+LoRA) | k5 mh@nodes^T + 10*tanh + mask + softmax.

typedef _Float16 f16;
typedef _Float16 f16x2 __attribute__((ext_vector_type(2)));
typedef _Float16 f16x4 __attribute__((ext_vector_type(4)));
typedef _Float16 f16x8 __attribute__((ext_vector_type(8)));
typedef __fp16  h4   __attribute__((ext_vector_type(4)));
typedef float   f32x4 __attribute__((ext_vector_type(4)));

#define LORA_SCALE 1.0f

__device__ __forceinline__ f16x2 pk2(f16 a, f16 b){ f16x2 r; r[0]=a; r[1]=b; return r; }

#if __has_builtin(__builtin_amdgcn_fdot2)
__device__ __forceinline__ float fdot2f(f16x2 a, f16x2 b, float c){ return __builtin_amdgcn_fdot2(a, b, c, false); }
#else
__device__ __forceinline__ float fdot2f(f16x2 a, f16x2 b, float c){ return c + (float)a[0]*(float)b[0] + (float)a[1]*(float)b[1]; }
#endif

#if __has_builtin(__builtin_amdgcn_cvt_pkrtz)
__device__ __forceinline__ f16x2 pkrtz(float a, float b){
  return __builtin_bit_cast(f16x2, __builtin_amdgcn_cvt_pkrtz(a, b));
}
#else
__device__ __forceinline__ f16x2 pkrtz(float a, float b){ return pk2((f16)a, (f16)b); }
#endif

// D = A(16x16) * B(16x16) + C via v_mfma_f32_16x16x16_f16.
// A: lane holds row (l&15), k = 4*(l>>4)+j. B: lane holds col (l&15), k = 4*(l>>4)+j.
// D: lane holds col (l&15), row = 4*(l>>4)+reg.
__device__ __forceinline__ f32x4 mfma16(f16x4 a, f16x4 b, f32x4 c){
  return __builtin_amdgcn_mfma_f32_16x16x16f16(
      __builtin_bit_cast(h4, a), __builtin_bit_cast(h4, b), c, 0, 0, 0);
}

__device__ __forceinline__ float dot8f(f16x8 a, f16x8 b, float c){
  c = fdot2f(pk2(a[0],a[1]), pk2(b[0],b[1]), c);
  c = fdot2f(pk2(a[2],a[3]), pk2(b[2],b[3]), c);
  c = fdot2f(pk2(a[4],a[5]), pk2(b[4],b[5]), c);
  c = fdot2f(pk2(a[6],a[7]), pk2(b[6],b[7]), c);
  return c;
}

__device__ __forceinline__ float wave_max(float v){
  #pragma unroll
  for (int off = 32; off; off >>= 1) v = fmaxf(v, __shfl_xor(v, off, 64));
  return v;
}
__device__ __forceinline__ float wave_sum(float v){
  #pragma unroll
  for (int off = 32; off; off >>= 1) v += __shfl_xor(v, off, 64);
  return v;
}

// ---------------- k1: K/V projection + nodes -> f16 ----------------
// grid (25, 64), 256 thr. Tile = 40 node rows.
// Kp layout: [bh][n(1000)][16]   (row-major for MFMA A-fragment reads)
// Vt layout: [bh][d(16)][n(1000)] (transposed for PV A-fragment reads)
#define K1_TILE 40
__global__ __launch_bounds__(256) void k1_proj(const float* __restrict__ nodes,
    const float* __restrict__ Wk, const float* __restrict__ Wv,
    f16* __restrict__ nodesF, f16* __restrict__ Kp, f16* __restrict__ Vt)
{
  __shared__ f16 lds[K1_TILE*128];
  const int tid = threadIdx.x;
  const int b = blockIdx.y;
  const int n0 = blockIdx.x * K1_TILE;
  {
    const float4* src = (const float4*)(nodes + ((size_t)b*1000 + n0)*128);
    f16x2* l2 = (f16x2*)lds;
    f16x2* nd = (f16x2*)(nodesF + ((size_t)b*1000 + n0)*128);
    for (int i = tid; i < K1_TILE*32; i += 256) {
      float4 v = src[i];
      f16x2 lo = pkrtz(v.x, v.y), hi = pkrtz(v.z, v.w);
      l2[2*i] = lo; l2[2*i+1] = hi;
      nd[2*i] = lo; nd[2*i+1] = hi;
    }
  }
  __syncthreads();
  const int col = tid;
  const bool isv = col >= 128;
  const int c = col & 127;
  const float* wrow = (isv ? Wv : Wk) + c*128;
  float acc[K1_TILE];
  #pragma unroll
  for (int r = 0; r < K1_TILE; ++r) acc[r] = 0.f;
  for (int c0 = 0; c0 < 128; c0 += 16) {
    float4 w0 = *(const float4*)(wrow + c0);
    float4 w1 = *(const float4*)(wrow + c0 + 4);
    float4 w2 = *(const float4*)(wrow + c0 + 8);
    float4 w3 = *(const float4*)(wrow + c0 + 12);
    f16x2 wv[8] = { pkrtz(w0.x,w0.y), pkrtz(w0.z,w0.w), pkrtz(w1.x,w1.y), pkrtz(w1.z,w1.w),
                    pkrtz(w2.x,w2.y), pkrtz(w2.z,w2.w), pkrtz(w3.x,w3.y), pkrtz(w3.z,w3.w) };
    #pragma unroll
    for (int r = 0; r < K1_TILE; ++r) {
      const f16x8* lr = (const f16x8*)(lds + r*128 + c0);
      f16x8 a0 = lr[0], a1 = lr[1];
      float s = acc[r];
      s = fdot2f(pk2(a0[0],a0[1]), wv[0], s);
      s = fdot2f(pk2(a0[2],a0[3]), wv[1], s);
      s = fdot2f(pk2(a0[4],a0[5]), wv[2], s);
      s = fdot2f(pk2(a0[6],a0[7]), wv[3], s);
      s = fdot2f(pk2(a1[0],a1[1]), wv[4], s);
      s = fdot2f(pk2(a1[2],a1[3]), wv[5], s);
      s = fdot2f(pk2(a1[4],a1[5]), wv[6], s);
      s = fdot2f(pk2(a1[6],a1[7]), wv[7], s);
      acc[r] = s;
    }
  }
  const int bh = b*8 + (c >> 4);
  const int d = c & 15;
  if (!isv) {
    f16* dst = Kp + (size_t)bh*16000 + d;
    #pragma unroll
    for (int r = 0; r < K1_TILE; ++r) dst[(size_t)(n0+r)*16] = (f16)acc[r];
  } else {
    f16* dst = Vt + ((size_t)bh*16 + d)*1000;
    #pragma unroll
    for (int r = 0; r < K1_TILE; ++r) dst[n0 + r] = (f16)acc[r];
  }
}

// ---------------- k2: q = q1@Wqf^T + last@Wql^T + LoRA ----------------
// grid 400, 256 thr, 32 rows/block. qF layout: [bh][m(200)][16]
__global__ __launch_bounds__(256) void k2_q(const float* __restrict__ q1,
    const float* __restrict__ last, const float* __restrict__ Wqf,
    const float* __restrict__ Wql, const float* __restrict__ lqA,
    const float* __restrict__ lqB, f16* __restrict__ qF)
{
  __shared__ f16 q1r[32*128];
  __shared__ f16 lar[32*128];
  __shared__ float t16[32*16];
  const int tid = threadIdx.x;
  const int row0 = blockIdx.x * 32;
  {
    const float4* s1 = (const float4*)(q1 + (size_t)row0*128);
    const float4* s2 = (const float4*)(last + (size_t)row0*128);
    f16x2* d1 = (f16x2*)q1r; f16x2* d2 = (f16x2*)lar;
    for (int i = tid; i < 32*32; i += 256) {
      float4 v = s1[i];
      d1[2*i] = pkrtz(v.x,v.y); d1[2*i+1] = pkrtz(v.z,v.w);
      float4 u = s2[i];
      d2[2*i] = pkrtz(u.x,u.y); d2[2*i+1] = pkrtz(u.z,u.w);
    }
  }
  __syncthreads();
  for (int idx = tid; idx < 32*16; idx += 256) {
    const int r = idx >> 4, kk = idx & 15;
    const f16x8* lrow = (const f16x8*)(lar + r*128);
    const float* arow = lqA + kk*128;
    float s = 0.f;
    #pragma unroll
    for (int cc = 0; cc < 16; ++cc) {
      f16x8 a = lrow[cc];
      float4 wa = *(const float4*)(arow + cc*8);
      float4 wb = *(const float4*)(arow + cc*8 + 4);
      s = fdot2f(pk2(a[0],a[1]), pkrtz(wa.x,wa.y), s);
      s = fdot2f(pk2(a[2],a[3]), pkrtz(wa.z,wa.w), s);
      s = fdot2f(pk2(a[4],a[5]), pkrtz(wb.x,wb.y), s);
      s = fdot2f(pk2(a[6],a[7]), pkrtz(wb.z,wb.w), s);
    }
    t16[idx] = s;
  }
  __syncthreads();
  const int c = tid & 127, rg = tid >> 7, rb = rg*16;
  float acc[16];
  #pragma unroll
  for (int r = 0; r < 16; ++r) acc[r] = 0.f;
  const float* wfr = Wqf + c*128;
  const float* wlr = Wql + c*128;
  for (int c0 = 0; c0 < 128; c0 += 16) {
    float4 f0 = *(const float4*)(wfr + c0);
    float4 f1 = *(const float4*)(wfr + c0 + 4);
    float4 f2 = *(const float4*)(wfr + c0 + 8);
    float4 f3 = *(const float4*)(wfr + c0 + 12);
    f16x2 wf[8] = { pkrtz(f0.x,f0.y), pkrtz(f0.z,f0.w), pkrtz(f1.x,f1.y), pkrtz(f1.z,f1.w),
                    pkrtz(f2.x,f2.y), pkrtz(f2.z,f2.w), pkrtz(f3.x,f3.y), pkrtz(f3.z,f3.w) };
    float4 g0 = *(const float4*)(wlr + c0);
    float4 g1 = *(const float4*)(wlr + c0 + 4);
    float4 g2 = *(const float4*)(wlr + c0 + 8);
    float4 g3 = *(const float4*)(wlr + c0 + 12);
    f16x2 wl[8] = { pkrtz(g0.x,g0.y), pkrtz(g0.z,g0.w), pkrtz(g1.x,g1.y), pkrtz(g1.z,g1.w),
                    pkrtz(g2.x,g2.y), pkrtz(g2.z,g2.w), pkrtz(g3.x,g3.y), pkrtz(g3.z,g3.w) };
    #pragma unroll
    for (int r = 0; r < 16; ++r) {
      const f16x8* qp = (const f16x8*)(q1r + (rb+r)*128 + c0);
      const f16x8* lp = (const f16x8*)(lar + (rb+r)*128 + c0);
      f16x8 a0 = qp[0], a1 = qp[1], b0 = lp[0], b1 = lp[1];
      float s = acc[r];
      s = fdot2f(pk2(a0[0],a0[1]), wf[0], s);
      s = fdot2f(pk2(a0[2],a0[3]), wf[1], s);
      s = fdot2f(pk2(a0[4],a0[5]), wf[2], s);
      s = fdot2f(pk2(a0[6],a0[7]), wf[3], s);
      s = fdot2f(pk2(a1[0],a1[1]), wf[4], s);
      s = fdot2f(pk2(a1[2],a1[3]), wf[5], s);
      s = fdot2f(pk2(a1[4],a1[5]), wf[6], s);
      s = fdot2f(pk2(a1[6],a1[7]), wf[7], s);
      s = fdot2f(pk2(b0[0],b0[1]), wl[0], s);
      s = fdot2f(pk2(b0[2],b0[3]), wl[1], s);
      s = fdot2f(pk2(b0[4],b0[5]), wl[2], s);
      s = fdot2f(pk2(b0[6],b0[7]), wl[3], s);
      s = fdot2f(pk2(b1[0],b1[1]), wl[4], s);
      s = fdot2f(pk2(b1[2],b1[3]), wl[5], s);
      s = fdot2f(pk2(b1[4],b1[5]), wl[6], s);
      s = fdot2f(pk2(b1[6],b1[7]), wl[7], s);
      acc[r] = s;
    }
  }
  const float* lb = lqB + c*16;
  float lbv[16];
  #pragma unroll
  for (int i = 0; i < 16; i += 4) {
    float4 t = *(const float4*)(lb + i);
    lbv[i] = t.x; lbv[i+1] = t.y; lbv[i+2] = t.z; lbv[i+3] = t.w;
  }
  #pragma unroll
  for (int r = 0; r < 16; ++r) {
    float dl = 0.f;
    #pragma unroll
    for (int kk = 0; kk < 16; ++kk) dl += t16[(rb+r)*16 + kk] * lbv[kk];
    acc[r] += dl * LORA_SCALE;
  }
  const int h = c >> 4, d = c & 15;
  #pragma unroll
  for (int r = 0; r < 16; ++r) {
    const int grow = row0 + rb + r;
    const int b = grow / 200, m = grow % 200;
    qF[(((size_t)b*8 + h)*200 + m)*16 + d] = (f16)acc[r];
  }
}

// ---------------- k3: per-(b,h) MFMA flash attention ----------------
// grid (8,64), 512 thr (8 waves). Swapped-operand 16x16x16 MFMA:
//   S^T tile = mfma(A=K-frag, B=Q-frag): lane holds S[m=col][n=t*16+4g+r]
//   O^T      = mfma(A=V^T-frag, B=P-frag): lane holds O[m=col][d=4g+r]
// P/softmax state is lane-local per row m=col; only row max/sum need 2 shfl_xor.
#define KSTR 20    // K_lds row stride (f16): 8B-aligned frags, odd/4 bank step
#define VSTR 1004  // V_lds row stride (f16)
__global__ __launch_bounds__(512) void k3_attn(const f16* __restrict__ Kp,
    const f16* __restrict__ Vt, const f16* __restrict__ qF,
    const float* __restrict__ mask, f16* __restrict__ ocF)
{
  extern __shared__ char smem[];
  f16* Kl = (f16*)smem;                     // [1008][KSTR] : 40320 B
  f16* Vl = (f16*)(smem + 1008*KSTR*2);     // [16][VSTR]   : 32128 B
  const int tid = threadIdx.x;
  const int lane = tid & 63, w = tid >> 6;
  const int h = blockIdx.x, b = blockIdx.y;
  const int bh = b*8 + h;
  // stage K rows (pad rows 1000..1007 with zeros; cols 16..19 never read)
  for (int n = tid; n < 1008; n += 512) {
    f16x4 z = {};
    f16x4 v0 = z, v1 = z, v2 = z, v3 = z;
    if (n < 1000) {
      const f16x4* src = (const f16x4*)(Kp + (size_t)bh*16000 + n*16);
      v0 = src[0]; v1 = src[1]; v2 = src[2]; v3 = src[3];
    }
    f16* dst = Kl + n*KSTR;
    *(f16x4*)(dst)    = v0;
    *(f16x4*)(dst+4)  = v1;
    *(f16x4*)(dst+8)  = v2;
    *(f16x4*)(dst+12) = v3;
  }
  // stage V^T rows [16][1000], zero-fill cols 1000..1003
  for (int i = tid; i < 2000; i += 512) {
    const int d = i / 125, c8 = i - d*125;
    const f16x4* src = (const f16x4*)(Vt + (size_t)bh*16000 + d*1000 + c8*8);
    f16* dst = Vl + d*VSTR + c8*8;
    *(f16x4*)(dst)   = src[0];
    *(f16x4*)(dst+4) = src[1];
  }
  if (tid < 64) { const int d = tid >> 2, e = 1000 + (tid & 3); Vl[d*VSTR + e] = (f16)0; }
  __syncthreads();

  const int col = lane & 15, g = lane >> 4, g4 = g*4;
  for (int mt = w; mt < 13; mt += 8) {
    const int m0 = mt*16;
    const int mq = min(m0 + col, 199);                 // clamp tail tile rows
    const f16x4 qf = *(const f16x4*)(qF + (size_t)bh*3200 + mq*16 + g4);
    const float* mp = mask + ((size_t)b*200 + mq)*1000;
    f32x4 O = {0.f, 0.f, 0.f, 0.f};
    float mrun = -1e30f, lrun = 0.f;
    for (int t = 0; t < 63; ++t) {
      const int n0 = t*16 + g4;
      const f16x4 kf = *(const f16x4*)(Kl + (t*16+col)*KSTR + g4);
      const f32x4 zero = {0.f, 0.f, 0.f, 0.f};
      f32x4 s4 = mfma16(kf, qf, zero);
      float s0, s1, s2, s3;
      if (n0 + 3 < 1000) {
        const float4 mk = *(const float4*)(mp + n0);
        s0 = s4[0]*0.25f + mk.x; s1 = s4[1]*0.25f + mk.y;
        s2 = s4[2]*0.25f + mk.z; s3 = s4[3]*0.25f + mk.w;
      } else {                                          // t==62, g>=2 (n>=1000)
        s0 = s1 = s2 = s3 = -1e30f;
      }
      float tm = fmaxf(fmaxf(s0, s1), fmaxf(s2, s3));
      tm = fmaxf(tm, __shfl_xor(tm, 16, 64));
      tm = fmaxf(tm, __shfl_xor(tm, 32, 64));
      const float newM = fmaxf(mrun, tm);
      const float sc = exp2f((mrun - newM)*1.44269504f);
      mrun = newM;
      const float p0 = exp2f((s0 - newM)*1.44269504f);
      const float p1 = exp2f((s1 - newM)*1.44269504f);
      const float p2 = exp2f((s2 - newM)*1.44269504f);
      const float p3 = exp2f((s3 - newM)*1.44269504f);
      lrun = lrun*sc + (p0 + p1) + (p2 + p3);
      O *= sc;
      const f16x2 plo = pkrtz(p0, p1), phi = pkrtz(p2, p3);
      const f16x4 pf = __builtin_shufflevector(plo, phi, 0, 1, 2, 3);
      const int nv = (n0 <= 1000) ? n0 : 1000;          // t==62,g==3: read zeros (pf==0)
      const f16x4 vf = *(const f16x4*)(Vl + col*VSTR + nv);
      O = mfma16(vf, pf, O);
    }
    lrun += __shfl_xor(lrun, 16, 64);
    lrun += __shfl_xor(lrun, 32, 64);
    const float inv = 1.f / lrun;
    if (m0 + col < 200) {
      const f16x2 o01 = pkrtz(O[0]*inv, O[1]*inv);
      const f16x2 o23 = pkrtz(O[2]*inv, O[3]*inv);
      const f16x4 ov = __builtin_shufflevector(o01, o23, 0, 1, 2, 3);
      *(f16x4*)(ocF + ((size_t)b*200 + m0 + col)*128 + h*16 + g4) = ov;
    }
  }
}

// ---------------- k4: mh = oc@Wc^T + bc + LoRA ----------------
__global__ __launch_bounds__(256) void k4_comb(const f16* __restrict__ ocF,
    const float* __restrict__ Wc, const float* __restrict__ bc,
    const float* __restrict__ lcA, const float* __restrict__ lcB,
    f16* __restrict__ mhF)
{
  __shared__ f16 ocr[32*128];
  __shared__ float t16[32*16];
  const int tid = threadIdx.x;
  const int row0 = blockIdx.x * 32;
  {
    const f16x8* s1 = (const f16x8*)(ocF + (size_t)row0*128);
    f16x8* d1 = (f16x8*)ocr;
    for (int i = tid; i < 512; i += 256) d1[i] = s1[i];
  }
  __syncthreads();
  for (int idx = tid; idx < 32*16; idx += 256) {
    const int r = idx >> 4, kk = idx & 15;
    const f16x8* lrow = (const f16x8*)(ocr + r*128);
    const float* arow = lcA + kk*128;
    float s = 0.f;
    #pragma unroll
    for (int cc = 0; cc < 16; ++cc) {
      f16x8 a = lrow[cc];
      float4 wa = *(const float4*)(arow + cc*8);
      float4 wb = *(const float4*)(arow + cc*8 + 4);
      s = fdot2f(pk2(a[0],a[1]), pkrtz(wa.x,wa.y), s);
      s = fdot2f(pk2(a[2],a[3]), pkrtz(wa.z,wa.w), s);
      s = fdot2f(pk2(a[4],a[5]), pkrtz(wb.x,wb.y), s);
      s = fdot2f(pk2(a[6],a[7]), pkrtz(wb.z,wb.w), s);
    }
    t16[idx] = s;
  }
  __syncthreads();
  const int c = tid & 127, rg = tid >> 7, rb = rg*16;
  float acc[16];
  const float bias = bc[c];
  #pragma unroll
  for (int r = 0; r < 16; ++r) acc[r] = bias;
  const float* wrow = Wc + c*128;
  for (int c0 = 0; c0 < 128; c0 += 16) {
    float4 w0 = *(const float4*)(wrow + c0);
    float4 w1 = *(const float4*)(wrow + c0 + 4);
    float4 w2 = *(const float4*)(wrow + c0 + 8);
    float4 w3 = *(const float4*)(wrow + c0 + 12);
    f16x2 wv[8] = { pkrtz(w0.x,w0.y), pkrtz(w0.z,w0.w), pkrtz(w1.x,w1.y), pkrtz(w1.z,w1.w),
                    pkrtz(w2.x,w2.y), pkrtz(w2.z,w2.w), pkrtz(w3.x,w3.y), pkrtz(w3.z,w3.w) };
    #pragma unroll
    for (int r = 0; r < 16; ++r) {
      const f16x8* op = (const f16x8*)(ocr + (rb+r)*128 + c0);
      f16x8 a0 = op[0], a1 = op[1];
      float s = acc[r];
      s = fdot2f(pk2(a0[0],a0[1]), wv[0], s);
      s = fdot2f(pk2(a0[2],a0[3]), wv[1], s);
      s = fdot2f(pk2(a0[4],a0[5]), wv[2], s);
      s = fdot2f(pk2(a0[6],a0[7]), wv[3], s);
      s = fdot2f(pk2(a1[0],a1[1]), wv[4], s);
      s = fdot2f(pk2(a1[2],a1[3]), wv[5], s);
      s = fdot2f(pk2(a1[4],a1[5]), wv[6], s);
      s = fdot2f(pk2(a1[6],a1[7]), wv[7], s);
      acc[r] = s;
    }
  }
  const float* lb = lcB + c*16;
  float lbv[16];
  #pragma unroll
  for (int i = 0; i < 16; i += 4) {
    float4 t = *(const float4*)(lb + i);
    lbv[i] = t.x; lbv[i+1] = t.y; lbv[i+2] = t.z; lbv[i+3] = t.w;
  }
  #pragma unroll
  for (int r = 0; r < 16; ++r) {
    float dl = 0.f;
    #pragma unroll
    for (int kk = 0; kk < 16; ++kk) dl += t16[(rb+r)*16 + kk] * lbv[kk];
    acc[r] += dl * LORA_SCALE;
  }
  #pragma unroll
  for (int r = 0; r < 16; ++r) {
    mhF[(size_t)(row0 + rb + r)*128 + c] = (f16)acc[r];
  }
}

// ---------------- k5: probs = softmax(10*tanh(mh@nodes^T / sqrt(128)) + mask) ----------------
// grid (25, 64), 512 thr (8 waves, 1 row each). Node tiles staged in LDS with XOR swizzle.
__global__ __launch_bounds__(512) void k5_final(const f16* __restrict__ mhF,
    const f16* __restrict__ nodesF, const float* __restrict__ mask,
    float* __restrict__ out)
{
  __shared__ f16 mhl[8*128];
  __shared__ f16x8 ntile[1024];   // [64 rows][16 vecs], vec index XOR-swizzled by row
  const int tid = threadIdx.x;
  const int lane = tid & 63, w = tid >> 6;
  const int b = blockIdx.y, m0 = blockIdx.x * 8;
  {
    const f16x8* sm = (const f16x8*)(mhF + ((size_t)b*200 + m0)*128);
    f16x8* dm = (f16x8*)mhl;
    if (tid < 128) dm[tid] = sm[tid];
  }
  __syncthreads();
  f16x8 mv[16];
  {
    const f16x8* mr = (const f16x8*)(mhl + w*128);
    #pragma unroll
    for (int i = 0; i < 16; ++i) mv[i] = mr[i];
  }
  float s[16];
  for (int t = 0; t < 16; ++t) {
    const int nrows = (t < 15) ? 64 : 40;
    __syncthreads();
    const f16x8* sn = (const f16x8*)(nodesF + ((size_t)b*1000 + t*64)*128);
    for (int i = tid; i < nrows*16; i += 512) {
      const int r = i >> 4, cc = i & 15;
      ntile[r*16 + (cc ^ (r & 7))] = sn[i];
    }
    __syncthreads();
    if (lane < nrows) {
      float acc = 0.f;
      #pragma unroll
      for (int cc = 0; cc < 16; ++cc) {
        f16x8 nv = ntile[lane*16 + (cc ^ (lane & 7))];
        acc = dot8f(mv[cc], nv, acc);
      }
      s[t] = acc;
    } else s[t] = 0.f;
  }
  const int m = m0 + w;
  const float* maskb = mask + ((size_t)b*200 + m)*1000;
  const float C1 = 0.08838834764831845f;  // 1/sqrt(128)
  float sc[16];
  #pragma unroll
  for (int t = 0; t < 16; ++t) {
    const int n = t*64 + lane;
    if (n < 1000) {
      float x = s[t] * C1;
      float e = exp2f(x * 2.8853900817779268f);  // 2*log2(e)*x
      float th = 1.f - 2.f/(e + 1.f);
      sc[t] = 10.f*th + maskb[n];
    } else sc[t] = -1e30f;
  }
  float M = -1e30f;
  #pragma unroll
  for (int t = 0; t < 16; ++t) M = fmaxf(M, sc[t]);
  M = wave_max(M);
  float lsum = 0.f;
  #pragma unroll
  for (int t = 0; t < 16; ++t) { sc[t] = exp2f((sc[t]-M)*1.44269504f); lsum += sc[t]; }
  float S = wave_sum(lsum);
  const float inv = 1.f/S;
  float* outb = out + ((size_t)b*200 + m)*1000;
  #pragma unroll
  for (int t = 0; t < 16; ++t) {
    const int n = t*64 + lane;
    if (n < 1000) outb[n] = sc[t]*inv;
  }
}

extern "C" void kernel_launch(void* const* d_in, const int* in_sizes, int n_in,
                              void* d_out, int out_size, void* d_ws, size_t ws_size,
                              hipStream_t stream)
{
  (void)in_sizes; (void)n_in; (void)out_size; (void)ws_size;
  const float* nodes = (const float*)d_in[0];
  const float* q1    = (const float*)d_in[1];
  const float* last  = (const float*)d_in[2];
  const float* mask  = (const float*)d_in[3];
  const float* Wqf   = (const float*)d_in[4];
  const float* Wql   = (const float*)d_in[5];
  const float* Wk    = (const float*)d_in[6];
  const float* Wv    = (const float*)d_in[7];
  const float* Wc    = (const float*)d_in[8];
  const float* bc    = (const float*)d_in[9];
  const float* lqA   = (const float*)d_in[10];
  const float* lqB   = (const float*)d_in[11];
  const float* lcA   = (const float*)d_in[12];
  const float* lcB   = (const float*)d_in[13];
  float* out = (float*)d_out;
  char* ws = (char*)d_ws;
  // ws layout (bytes):
  f16* nodesF = (f16*)(ws);               // 16,384,000
  f16* Kp     = (f16*)(ws + 16384000);    // 16,384,000
  f16* Vt     = (f16*)(ws + 32768000);    // 16,384,000
  f16* qF     = (f16*)(ws + 49152000);    //  3,276,800
  f16* ocF    = (f16*)(ws + 52428800);    //  3,276,800
  f16* mhF    = (f16*)(ws + 55705600);    //  3,276,800  (end 58,982,400)

  k1_proj<<<dim3(25, 64), 256, 0, stream>>>(nodes, Wk, Wv, nodesF, Kp, Vt);
  k2_q<<<dim3(400), 256, 0, stream>>>(q1, last, Wqf, Wql, lqA, lqB, qF);
  k3_attn<<<dim3(8, 64), 512, 72448, stream>>>(Kp, Vt, qF, mask, ocF);
  k4_comb<<<dim3(400), 256, 0, stream>>>(ocF, Wc, bc, lcA, lcB, mhF);
  k5_final<<<dim3(25, 64), 512, 0, stream>>>(mhF, nodesF, mask, out);
}

// Round 4
// 297.378 us; speedup vs baseline: 1.5116x; 1.0629x over previous
//
#include <hip/hip_runtime.h>
#include <hip/hip_bf16.h>

// TSP decoder forward: B=64, POMO=200, N=1000, EMB=128, H=8, D=16.
// k0 W->f16 | k1 MFMA K/V proj + nodes->f16 | k2 q (+LoRA) |
// k3 MFMA flash attention | k4 combine (+LoRA) | k5 MFMA mh@nodes^T + tanh-softmax.

typedef _Float16 f16;
typedef _Float16 f16x2 __attribute__((ext_vector_type(2)));
typedef _Float16 f16x4 __attribute__((ext_vector_type(4)));
typedef _Float16 f16x8 __attribute__((ext_vector_type(8)));
typedef __fp16  h4   __attribute__((ext_vector_type(4)));
typedef float   f32x4 __attribute__((ext_vector_type(4)));

#define LORA_SCALE 1.0f

__device__ __forceinline__ f16x2 pk2(f16 a, f16 b){ f16x2 r; r[0]=a; r[1]=b; return r; }

#if __has_builtin(__builtin_amdgcn_fdot2)
__device__ __forceinline__ float fdot2f(f16x2 a, f16x2 b, float c){ return __builtin_amdgcn_fdot2(a, b, c, false); }
#else
__device__ __forceinline__ float fdot2f(f16x2 a, f16x2 b, float c){ return c + (float)a[0]*(float)b[0] + (float)a[1]*(float)b[1]; }
#endif

#if __has_builtin(__builtin_amdgcn_cvt_pkrtz)
__device__ __forceinline__ f16x2 pkrtz(float a, float b){
  return __builtin_bit_cast(f16x2, __builtin_amdgcn_cvt_pkrtz(a, b));
}
#else
__device__ __forceinline__ f16x2 pkrtz(float a, float b){ return pk2((f16)a, (f16)b); }
#endif

// D[i][j] = sum_k A[i][k]*B[k][j] + C  via v_mfma_f32_16x16x16_f16.
// A: lane holds row i=(l&15), k=4*(l>>4)+j. B: lane holds col j=(l&15), k=4*(l>>4)+j.
// D: lane holds col j=(l&15), row i=4*(l>>4)+reg.   (validated end-to-end in k3)
__device__ __forceinline__ f32x4 mfma16(f16x4 a, f16x4 b, f32x4 c){
  return __builtin_amdgcn_mfma_f32_16x16x16f16(
      __builtin_bit_cast(h4, a), __builtin_bit_cast(h4, b), c, 0, 0, 0);
}

__device__ __forceinline__ float dot8f(f16x8 a, f16x8 b, float c){
  c = fdot2f(pk2(a[0],a[1]), pk2(b[0],b[1]), c);
  c = fdot2f(pk2(a[2],a[3]), pk2(b[2],b[3]), c);
  c = fdot2f(pk2(a[4],a[5]), pk2(b[4],b[5]), c);
  c = fdot2f(pk2(a[6],a[7]), pk2(b[6],b[7]), c);
  return c;
}

// ---------------- k0: Wk|Wv -> f16 [256][128] ----------------
__global__ __launch_bounds__(256) void k0_wconv(const float* __restrict__ Wk,
    const float* __restrict__ Wv, f16* __restrict__ WkvF)
{
  const int i = blockIdx.x*256 + threadIdx.x;           // 0..8191, one f32x4 each
  const float4 v = (i < 4096) ? ((const float4*)Wk)[i] : ((const float4*)Wv)[i-4096];
  f16x2 lo = pkrtz(v.x,v.y), hi = pkrtz(v.z,v.w);
  f16x4 o = __builtin_shufflevector(lo, hi, 0, 1, 2, 3);
  *(f16x4*)(WkvF + i*4) = o;
}

// ---------------- k1: MFMA K/V projection + nodes -> f16 ----------------
// grid (16, 64), 256 thr (4 waves), 64 node rows per block.
// Kp: [bh][n(1000)][16] ; Vt: [bh][d(16)][n(1000)]
#define NSTR 132
__global__ __launch_bounds__(256) void k1_proj(const float* __restrict__ nodes,
    const f16* __restrict__ WkvF,
    f16* __restrict__ nodesF, f16* __restrict__ Kp, f16* __restrict__ Vt)
{
  __shared__ f16 lds[64*NSTR];
  const int tid = threadIdx.x, lane = tid & 63, w = tid >> 6;
  const int b = blockIdx.y;
  const int n0 = blockIdx.x * 64;
  const int rows = min(64, 1000 - n0);                  // 64 or 40
  for (int i = tid; i < rows*32; i += 256) {            // 32 f32x4 per row
    const int r = i >> 5, cq = i & 31;
    float4 v = ((const float4*)(nodes + ((size_t)b*1000 + n0 + r)*128))[cq];
    f16x2 lo = pkrtz(v.x,v.y), hi = pkrtz(v.z,v.w);
    f16x4 o = __builtin_shufflevector(lo, hi, 0, 1, 2, 3);
    *(f16x4*)(lds + r*NSTR + cq*4) = o;
    *(f16x4*)(nodesF + ((size_t)b*1000 + n0 + r)*128 + cq*4) = o;
  }
  __syncthreads();
  const int col = lane & 15, g = lane >> 4, g4 = g*4;
  const int mloc = w*16 + col;                          // wave-local node row (as frag row/col)
  f16x4 nf[8];
  #pragma unroll
  for (int kk = 0; kk < 8; ++kk)
    nf[kk] = *(const f16x4*)(lds + min(mloc, rows-1)*NSTR + kk*16 + g4);
  for (int ct = 0; ct < 16; ++ct) {
    f16x4 wf[8];
    const f16* wbase = WkvF + (ct*16 + col)*128;
    #pragma unroll
    for (int kk = 0; kk < 8; ++kk) wf[kk] = *(const f16x4*)(wbase + kk*16 + g4);
    f32x4 acc = {0.f, 0.f, 0.f, 0.f};
    if (ct < 8) {                                       // K-head ct: D[c][m]
      #pragma unroll
      for (int kk = 0; kk < 8; ++kk) acc = mfma16(wf[kk], nf[kk], acc);
      if (mloc < rows) {
        const int nn = n0 + mloc;
        f16x4 ov = __builtin_shufflevector(pk2((f16)acc[0],(f16)acc[1]),
                                           pk2((f16)acc[2],(f16)acc[3]), 0,1,2,3);
        *(f16x4*)(Kp + ((size_t)(b*8+ct)*1000 + nn)*16 + g4) = ov;
      }
    } else {                                            // V-head ct-8: D[m][c]
      #pragma unroll
      for (int kk = 0; kk < 8; ++kk) acc = mfma16(nf[kk], wf[kk], acc);
      if (w*16 + g4 + 3 < rows) {
        const int nbase = n0 + w*16 + g4;
        f16x4 ov = __builtin_shufflevector(pk2((f16)acc[0],(f16)acc[1]),
                                           pk2((f16)acc[2],(f16)acc[3]), 0,1,2,3);
        *(f16x4*)(Vt + ((size_t)(b*8+(ct-8))*16 + col)*1000 + nbase) = ov;
      }
    }
  }
}

// ---------------- k2: q = q1@Wqf^T + last@Wql^T + LoRA ----------------
// grid 400, 256 thr, 32 rows/block. qF layout: [bh][m(200)][16]
__global__ __launch_bounds__(256) void k2_q(const float* __restrict__ q1,
    const float* __restrict__ last, const float* __restrict__ Wqf,
    const float* __restrict__ Wql, const float* __restrict__ lqA,
    const float* __restrict__ lqB, f16* __restrict__ qF)
{
  __shared__ f16 q1r[32*128];
  __shared__ f16 lar[32*128];
  __shared__ float t16[32*16];
  const int tid = threadIdx.x;
  const int row0 = blockIdx.x * 32;
  {
    const float4* s1 = (const float4*)(q1 + (size_t)row0*128);
    const float4* s2 = (const float4*)(last + (size_t)row0*128);
    f16x2* d1 = (f16x2*)q1r; f16x2* d2 = (f16x2*)lar;
    for (int i = tid; i < 32*32; i += 256) {
      float4 v = s1[i];
      d1[2*i] = pkrtz(v.x,v.y); d1[2*i+1] = pkrtz(v.z,v.w);
      float4 u = s2[i];
      d2[2*i] = pkrtz(u.x,u.y); d2[2*i+1] = pkrtz(u.z,u.w);
    }
  }
  __syncthreads();
  for (int idx = tid; idx < 32*16; idx += 256) {
    const int r = idx >> 4, kk = idx & 15;
    const f16x8* lrow = (const f16x8*)(lar + r*128);
    const float* arow = lqA + kk*128;
    float s = 0.f;
    #pragma unroll
    for (int cc = 0; cc < 16; ++cc) {
      f16x8 a = lrow[cc];
      float4 wa = *(const float4*)(arow + cc*8);
      float4 wb = *(const float4*)(arow + cc*8 + 4);
      s = fdot2f(pk2(a[0],a[1]), pkrtz(wa.x,wa.y), s);
      s = fdot2f(pk2(a[2],a[3]), pkrtz(wa.z,wa.w), s);
      s = fdot2f(pk2(a[4],a[5]), pkrtz(wb.x,wb.y), s);
      s = fdot2f(pk2(a[6],a[7]), pkrtz(wb.z,wb.w), s);
    }
    t16[idx] = s;
  }
  __syncthreads();
  const int c = tid & 127, rg = tid >> 7, rb = rg*16;
  float acc[16];
  #pragma unroll
  for (int r = 0; r < 16; ++r) acc[r] = 0.f;
  const float* wfr = Wqf + c*128;
  const float* wlr = Wql + c*128;
  for (int c0 = 0; c0 < 128; c0 += 16) {
    float4 f0 = *(const float4*)(wfr + c0);
    float4 f1 = *(const float4*)(wfr + c0 + 4);
    float4 f2 = *(const float4*)(wfr + c0 + 8);
    float4 f3 = *(const float4*)(wfr + c0 + 12);
    f16x2 wf[8] = { pkrtz(f0.x,f0.y), pkrtz(f0.z,f0.w), pkrtz(f1.x,f1.y), pkrtz(f1.z,f1.w),
                    pkrtz(f2.x,f2.y), pkrtz(f2.z,f2.w), pkrtz(f3.x,f3.y), pkrtz(f3.z,f3.w) };
    float4 g0 = *(const float4*)(wlr + c0);
    float4 g1 = *(const float4*)(wlr + c0 + 4);
    float4 g2 = *(const float4*)(wlr + c0 + 8);
    float4 g3 = *(const float4*)(wlr + c0 + 12);
    f16x2 wl[8] = { pkrtz(g0.x,g0.y), pkrtz(g0.z,g0.w), pkrtz(g1.x,g1.y), pkrtz(g1.z,g1.w),
                    pkrtz(g2.x,g2.y), pkrtz(g2.z,g2.w), pkrtz(g3.x,g3.y), pkrtz(g3.z,g3.w) };
    #pragma unroll
    for (int r = 0; r < 16; ++r) {
      const f16x8* qp = (const f16x8*)(q1r + (rb+r)*128 + c0);
      const f16x8* lp = (const f16x8*)(lar + (rb+r)*128 + c0);
      f16x8 a0 = qp[0], a1 = qp[1], b0 = lp[0], b1 = lp[1];
      float s = acc[r];
      s = fdot2f(pk2(a0[0],a0[1]), wf[0], s);
      s = fdot2f(pk2(a0[2],a0[3]), wf[1], s);
      s = fdot2f(pk2(a0[4],a0[5]), wf[2], s);
      s = fdot2f(pk2(a0[6],a0[7]), wf[3], s);
      s = fdot2f(pk2(a1[0],a1[1]), wf[4], s);
      s = fdot2f(pk2(a1[2],a1[3]), wf[5], s);
      s = fdot2f(pk2(a1[4],a1[5]), wf[6], s);
      s = fdot2f(pk2(a1[6],a1[7]), wf[7], s);
      s = fdot2f(pk2(b0[0],b0[1]), wl[0], s);
      s = fdot2f(pk2(b0[2],b0[3]), wl[1], s);
      s = fdot2f(pk2(b0[4],b0[5]), wl[2], s);
      s = fdot2f(pk2(b0[6],b0[7]), wl[3], s);
      s = fdot2f(pk2(b1[0],b1[1]), wl[4], s);
      s = fdot2f(pk2(b1[2],b1[3]), wl[5], s);
      s = fdot2f(pk2(b1[4],b1[5]), wl[6], s);
      s = fdot2f(pk2(b1[6],b1[7]), wl[7], s);
      acc[r] = s;
    }
  }
  const float* lb = lqB + c*16;
  float lbv[16];
  #pragma unroll
  for (int i = 0; i < 16; i += 4) {
    float4 t = *(const float4*)(lb + i);
    lbv[i] = t.x; lbv[i+1] = t.y; lbv[i+2] = t.z; lbv[i+3] = t.w;
  }
  #pragma unroll
  for (int r = 0; r < 16; ++r) {
    float dl = 0.f;
    #pragma unroll
    for (int kk = 0; kk < 16; ++kk) dl += t16[(rb+r)*16 + kk] * lbv[kk];
    acc[r] += dl * LORA_SCALE;
  }
  const int h = c >> 4, d = c & 15;
  #pragma unroll
  for (int r = 0; r < 16; ++r) {
    const int grow = row0 + rb + r;
    const int b = grow / 200, m = grow % 200;
    qF[(((size_t)b*8 + h)*200 + m)*16 + d] = (f16)acc[r];
  }
}

// ---------------- k3: per-(b,h) MFMA flash attention ----------------
// grid (8,64), 512 thr (8 waves). Swapped-operand 16x16x16 MFMA.
#define KSTR 20
#define VSTR 1004
__global__ __launch_bounds__(512) void k3_attn(const f16* __restrict__ Kp,
    const f16* __restrict__ Vt, const f16* __restrict__ qF,
    const float* __restrict__ mask, f16* __restrict__ ocF)
{
  extern __shared__ char smem[];
  f16* Kl = (f16*)smem;                     // [1008][KSTR] : 40320 B
  f16* Vl = (f16*)(smem + 1008*KSTR*2);     // [16][VSTR]   : 32128 B
  const int tid = threadIdx.x;
  const int lane = tid & 63, w = tid >> 6;
  const int h = blockIdx.x, b = blockIdx.y;
  const int bh = b*8 + h;
  for (int n = tid; n < 1008; n += 512) {
    f16x4 z = {};
    f16x4 v0 = z, v1 = z, v2 = z, v3 = z;
    if (n < 1000) {
      const f16x4* src = (const f16x4*)(Kp + (size_t)bh*16000 + n*16);
      v0 = src[0]; v1 = src[1]; v2 = src[2]; v3 = src[3];
    }
    f16* dst = Kl + n*KSTR;
    *(f16x4*)(dst)    = v0;
    *(f16x4*)(dst+4)  = v1;
    *(f16x4*)(dst+8)  = v2;
    *(f16x4*)(dst+12) = v3;
  }
  for (int i = tid; i < 2000; i += 512) {
    const int d = i / 125, c8 = i - d*125;
    const f16x4* src = (const f16x4*)(Vt + (size_t)bh*16000 + d*1000 + c8*8);
    f16* dst = Vl + d*VSTR + c8*8;
    *(f16x4*)(dst)   = src[0];
    *(f16x4*)(dst+4) = src[1];
  }
  if (tid < 64) { const int d = tid >> 2, e = 1000 + (tid & 3); Vl[d*VSTR + e] = (f16)0; }
  __syncthreads();

  const int col = lane & 15, g = lane >> 4, g4 = g*4;
  for (int mt = w; mt < 13; mt += 8) {
    const int m0 = mt*16;
    const int mq = min(m0 + col, 199);
    const f16x4 qf = *(const f16x4*)(qF + (size_t)bh*3200 + mq*16 + g4);
    const float* mp = mask + ((size_t)b*200 + mq)*1000;
    f32x4 O = {0.f, 0.f, 0.f, 0.f};
    float mrun = -1e30f, lrun = 0.f;
    for (int t = 0; t < 63; ++t) {
      const int n0 = t*16 + g4;
      const f16x4 kf = *(const f16x4*)(Kl + (t*16+col)*KSTR + g4);
      const f32x4 zero = {0.f, 0.f, 0.f, 0.f};
      f32x4 s4 = mfma16(kf, qf, zero);
      float s0, s1, s2, s3;
      if (n0 + 3 < 1000) {
        const float4 mk = *(const float4*)(mp + n0);
        s0 = s4[0]*0.25f + mk.x; s1 = s4[1]*0.25f + mk.y;
        s2 = s4[2]*0.25f + mk.z; s3 = s4[3]*0.25f + mk.w;
      } else {
        s0 = s1 = s2 = s3 = -1e30f;
      }
      float tm = fmaxf(fmaxf(s0, s1), fmaxf(s2, s3));
      tm = fmaxf(tm, __shfl_xor(tm, 16, 64));
      tm = fmaxf(tm, __shfl_xor(tm, 32, 64));
      const float newM = fmaxf(mrun, tm);
      const float sc = exp2f((mrun - newM)*1.44269504f);
      mrun = newM;
      const float p0 = exp2f((s0 - newM)*1.44269504f);
      const float p1 = exp2f((s1 - newM)*1.44269504f);
      const float p2 = exp2f((s2 - newM)*1.44269504f);
      const float p3 = exp2f((s3 - newM)*1.44269504f);
      lrun = lrun*sc + (p0 + p1) + (p2 + p3);
      O *= sc;
      const f16x2 plo = pkrtz(p0, p1), phi = pkrtz(p2, p3);
      const f16x4 pf = __builtin_shufflevector(plo, phi, 0, 1, 2, 3);
      const int nv = (n0 <= 1000) ? n0 : 1000;
      const f16x4 vf = *(const f16x4*)(Vl + col*VSTR + nv);
      O = mfma16(vf, pf, O);
    }
    lrun += __shfl_xor(lrun, 16, 64);
    lrun += __shfl_xor(lrun, 32, 64);
    const float inv = 1.f / lrun;
    if (m0 + col < 200) {
      const f16x2 o01 = pkrtz(O[0]*inv, O[1]*inv);
      const f16x2 o23 = pkrtz(O[2]*inv, O[3]*inv);
      const f16x4 ov = __builtin_shufflevector(o01, o23, 0, 1, 2, 3);
      *(f16x4*)(ocF + ((size_t)b*200 + m0 + col)*128 + h*16 + g4) = ov;
    }
  }
}

// ---------------- k4: mh = oc@Wc^T + bc + LoRA ----------------
__global__ __launch_bounds__(256) void k4_comb(const f16* __restrict__ ocF,
    const float* __restrict__ Wc, const float* __restrict__ bc,
    const float* __restrict__ lcA, const float* __restrict__ lcB,
    f16* __restrict__ mhF)
{
  __shared__ f16 ocr[32*128];
  __shared__ float t16[32*16];
  const int tid = threadIdx.x;
  const int row0 = blockIdx.x * 32;
  {
    const f16x8* s1 = (const f16x8*)(ocF + (size_t)row0*128);
    f16x8* d1 = (f16x8*)ocr;
    for (int i = tid; i < 512; i += 256) d1[i] = s1[i];
  }
  __syncthreads();
  for (int idx = tid; idx < 32*16; idx += 256) {
    const int r = idx >> 4, kk = idx & 15;
    const f16x8* lrow = (const f16x8*)(ocr + r*128);
    const float* arow = lcA + kk*128;
    float s = 0.f;
    #pragma unroll
    for (int cc = 0; cc < 16; ++cc) {
      f16x8 a = lrow[cc];
      float4 wa = *(const float4*)(arow + cc*8);
      float4 wb = *(const float4*)(arow + cc*8 + 4);
      s = fdot2f(pk2(a[0],a[1]), pkrtz(wa.x,wa.y), s);
      s = fdot2f(pk2(a[2],a[3]), pkrtz(wa.z,wa.w), s);
      s = fdot2f(pk2(a[4],a[5]), pkrtz(wb.x,wb.y), s);
      s = fdot2f(pk2(a[6],a[7]), pkrtz(wb.z,wb.w), s);
    }
    t16[idx] = s;
  }
  __syncthreads();
  const int c = tid & 127, rg = tid >> 7, rb = rg*16;
  float acc[16];
  const float bias = bc[c];
  #pragma unroll
  for (int r = 0; r < 16; ++r) acc[r] = bias;
  const float* wrow = Wc + c*128;
  for (int c0 = 0; c0 < 128; c0 += 16) {
    float4 w0 = *(const float4*)(wrow + c0);
    float4 w1 = *(const float4*)(wrow + c0 + 4);
    float4 w2 = *(const float4*)(wrow + c0 + 8);
    float4 w3 = *(const float4*)(wrow + c0 + 12);
    f16x2 wv[8] = { pkrtz(w0.x,w0.y), pkrtz(w0.z,w0.w), pkrtz(w1.x,w1.y), pkrtz(w1.z,w1.w),
                    pkrtz(w2.x,w2.y), pkrtz(w2.z,w2.w), pkrtz(w3.x,w3.y), pkrtz(w3.z,w3.w) };
    #pragma unroll
    for (int r = 0; r < 16; ++r) {
      const f16x8* op = (const f16x8*)(ocr + (rb+r)*128 + c0);
      f16x8 a0 = op[0], a1 = op[1];
      float s = acc[r];
      s = fdot2f(pk2(a0[0],a0[1]), wv[0], s);
      s = fdot2f(pk2(a0[2],a0[3]), wv[1], s);
      s = fdot2f(pk2(a0[4],a0[5]), wv[2], s);
      s = fdot2f(pk2(a0[6],a0[7]), wv[3], s);
      s = fdot2f(pk2(a1[0],a1[1]), wv[4], s);
      s = fdot2f(pk2(a1[2],a1[3]), wv[5], s);
      s = fdot2f(pk2(a1[4],a1[5]), wv[6], s);
      s = fdot2f(pk2(a1[6],a1[7]), wv[7], s);
      acc[r] = s;
    }
  }
  const float* lb = lcB + c*16;
  float lbv[16];
  #pragma unroll
  for (int i = 0; i < 16; i += 4) {
    float4 t = *(const float4*)(lb + i);
    lbv[i] = t.x; lbv[i+1] = t.y; lbv[i+2] = t.z; lbv[i+3] = t.w;
  }
  #pragma unroll
  for (int r = 0; r < 16; ++r) {
    float dl = 0.f;
    #pragma unroll
    for (int kk = 0; kk < 16; ++kk) dl += t16[(rb+r)*16 + kk] * lbv[kk];
    acc[r] += dl * LORA_SCALE;
  }
  #pragma unroll
  for (int r = 0; r < 16; ++r) {
    mhF[(size_t)(row0 + rb + r)*128 + c] = (f16)acc[r];
  }
}

// ---------------- k5: MFMA probs = softmax(10*tanh(mh@nodes^T/sqrt(128)) + mask) ----------------
// grid (64, 13), 512 thr (8 waves). Block = (b, 16 m-rows); wave covers n-tiles w+8i.
// D lane layout: col = m-offset (l&15), rows = n0+4g+{0..3} -> mask/exp/store all lane-local.
__global__ __launch_bounds__(512) void k5_final(const f16* __restrict__ mhF,
    const f16* __restrict__ nodesF, const float* __restrict__ mask,
    float* __restrict__ out)
{
  __shared__ float sums[8][16];
  const int tid = threadIdx.x, lane = tid & 63, w = tid >> 6;
  const int b = blockIdx.x, mt = blockIdx.y;
  const int col = lane & 15, g = lane >> 4, g4 = g*4;
  const int m = mt*16 + col;
  const int mq = min(m, 199);
  f16x4 bf[8];
  const f16* mb = mhF + (size_t)(b*200 + mq)*128;
  #pragma unroll
  for (int kk = 0; kk < 8; ++kk) bf[kk] = *(const f16x4*)(mb + kk*16 + g4);
  const float* mrow = mask + (size_t)(b*200 + mq)*1000;
  const f16* nb = nodesF + (size_t)b*128000;
  float p[8][4];
  float lsum = 0.f;
  #pragma unroll
  for (int i = 0; i < 8; ++i) {
    const int t = w + i*8;
    if (t < 63) {
      const int nr = min(t*16 + col, 999);
      const f16* na = nb + nr*128;
      f32x4 acc = {0.f, 0.f, 0.f, 0.f};
      #pragma unroll
      for (int kk = 0; kk < 8; ++kk) {
        f16x4 af = *(const f16x4*)(na + kk*16 + g4);
        acc = mfma16(af, bf[kk], acc);
      }
      const int n0 = t*16 + g4;
      float mkv[4] = {0.f, 0.f, 0.f, 0.f};
      if (n0 + 3 < 1000) {
        float4 mk = *(const float4*)(mrow + n0);
        mkv[0] = mk.x; mkv[1] = mk.y; mkv[2] = mk.z; mkv[3] = mk.w;
      }
      #pragma unroll
      for (int r = 0; r < 4; ++r) {
        float x = acc[r] * 0.08838834764831845f;            // /sqrt(128)
        float e = exp2f(x * 2.8853900817779268f);           // e^{2x}
        float th = 1.f - 2.f/(e + 1.f);                     // tanh(x)
        float scv = 10.f*th + mkv[r];
        float pv = exp2f(scv * 1.44269504f);                // no-max softmax: sc <= 10
        pv = (n0 + r < 1000) ? pv : 0.f;
        p[i][r] = pv;
        lsum += pv;
      }
    } else {
      p[i][0] = p[i][1] = p[i][2] = p[i][3] = 0.f;
    }
  }
  lsum += __shfl_xor(lsum, 16, 64);
  lsum += __shfl_xor(lsum, 32, 64);
  if (lane < 16) sums[w][lane] = lsum;
  __syncthreads();
  float S = 0.f;
  #pragma unroll
  for (int ww = 0; ww < 8; ++ww) S += sums[ww][col];
  const float inv = 1.f / S;
  if (m < 200) {
    float* ob = out + (size_t)(b*200 + m)*1000;
    #pragma unroll
    for (int i = 0; i < 8; ++i) {
      const int t = w + i*8;
      if (t < 63) {
        const int n0 = t*16 + g4;
        if (n0 + 3 < 1000) {
          float4 o;
          o.x = p[i][0]*inv; o.y = p[i][1]*inv; o.z = p[i][2]*inv; o.w = p[i][3]*inv;
          *(float4*)(ob + n0) = o;
        } else {
          #pragma unroll
          for (int r = 0; r < 4; ++r) if (n0 + r < 1000) ob[n0+r] = p[i][r]*inv;
        }
      }
    }
  }
}

extern "C" void kernel_launch(void* const* d_in, const int* in_sizes, int n_in,
                              void* d_out, int out_size, void* d_ws, size_t ws_size,
                              hipStream_t stream)
{
  (void)in_sizes; (void)n_in; (void)out_size; (void)ws_size;
  const float* nodes = (const float*)d_in[0];
  const float* q1    = (const float*)d_in[1];
  const float* last  = (const float*)d_in[2];
  const float* mask  = (const float*)d_in[3];
  const float* Wqf   = (const float*)d_in[4];
  const float* Wql   = (const float*)d_in[5];
  const float* Wk    = (const float*)d_in[6];
  const float* Wv    = (const float*)d_in[7];
  const float* Wc    = (const float*)d_in[8];
  const float* bc    = (const float*)d_in[9];
  const float* lqA   = (const float*)d_in[10];
  const float* lqB   = (const float*)d_in[11];
  const float* lcA   = (const float*)d_in[12];
  const float* lcB   = (const float*)d_in[13];
  float* out = (float*)d_out;
  char* ws = (char*)d_ws;
  // ws layout (bytes):
  f16* nodesF = (f16*)(ws);               // 16,384,000
  f16* Kp     = (f16*)(ws + 16384000);    // 16,384,000
  f16* Vt     = (f16*)(ws + 32768000);    // 16,384,000
  f16* qF     = (f16*)(ws + 49152000);    //  3,276,800
  f16* ocF    = (f16*)(ws + 52428800);    //  3,276,800
  f16* mhF    = (f16*)(ws + 55705600);    //  3,276,800
  f16* WkvF   = (f16*)(ws + 58982400);    //     65,536  (end 59,047,936)

  k0_wconv<<<dim3(32), 256, 0, stream>>>(Wk, Wv, WkvF);
  k1_proj<<<dim3(16, 64), 256, 0, stream>>>(nodes, WkvF, nodesF, Kp, Vt);
  k2_q<<<dim3(400), 256, 0, stream>>>(q1, last, Wqf, Wql, lqA, lqB, qF);
  k3_attn<<<dim3(8, 64), 512, 72448, stream>>>(Kp, Vt, qF, mask, ocF);
  k4_comb<<<dim3(400), 256, 0, stream>>>(ocF, Wc, bc, lcA, lcB, mhF);
  k5_final<<<dim3(64, 13), 512, 0, stream>>>(mhF, nodesF, mask, out);
}

// Round 5
// 286.428 us; speedup vs baseline: 1.5693x; 1.0382x over previous
//
#include <hip/hip_runtime.h>
#include <hip/hip_bf16.h>

// TSP decoder forward: B=64, POMO=200, N=1000, EMB=128, H=8, D=16.
// k0 W->f16 | k1 MFMA K/V proj + nodes->f16 | k2 q (+LoRA) |
// k3 MFMA flash attention (two-pass fixed-max) | k4 combine (+LoRA) |
// k5 MFMA mh@nodes^T + tanh-softmax.

typedef _Float16 f16;
typedef _Float16 f16x2 __attribute__((ext_vector_type(2)));
typedef _Float16 f16x4 __attribute__((ext_vector_type(4)));
typedef _Float16 f16x8 __attribute__((ext_vector_type(8)));
typedef __fp16  h4   __attribute__((ext_vector_type(4)));
typedef float   f32x4 __attribute__((ext_vector_type(4)));

#define LORA_SCALE 1.0f

__device__ __forceinline__ f16x2 pk2(f16 a, f16 b){ f16x2 r; r[0]=a; r[1]=b; return r; }

#if __has_builtin(__builtin_amdgcn_fdot2)
__device__ __forceinline__ float fdot2f(f16x2 a, f16x2 b, float c){ return __builtin_amdgcn_fdot2(a, b, c, false); }
#else
__device__ __forceinline__ float fdot2f(f16x2 a, f16x2 b, float c){ return c + (float)a[0]*(float)b[0] + (float)a[1]*(float)b[1]; }
#endif

#if __has_builtin(__builtin_amdgcn_cvt_pkrtz)
__device__ __forceinline__ f16x2 pkrtz(float a, float b){
  return __builtin_bit_cast(f16x2, __builtin_amdgcn_cvt_pkrtz(a, b));
}
#else
__device__ __forceinline__ f16x2 pkrtz(float a, float b){ return pk2((f16)a, (f16)b); }
#endif

// D[i][j] = sum_k A[i][k]*B[k][j] + C  via v_mfma_f32_16x16x16_f16.
// A: lane holds row i=(l&15), k=4*(l>>4)+j. B: lane holds col j=(l&15), k=4*(l>>4)+j.
// D: lane holds col j=(l&15), row i=4*(l>>4)+reg.   (validated end-to-end in k3/k5)
__device__ __forceinline__ f32x4 mfma16(f16x4 a, f16x4 b, f32x4 c){
  return __builtin_amdgcn_mfma_f32_16x16x16f16(
      __builtin_bit_cast(h4, a), __builtin_bit_cast(h4, b), c, 0, 0, 0);
}

__device__ __forceinline__ float dot8f(f16x8 a, f16x8 b, float c){
  c = fdot2f(pk2(a[0],a[1]), pk2(b[0],b[1]), c);
  c = fdot2f(pk2(a[2],a[3]), pk2(b[2],b[3]), c);
  c = fdot2f(pk2(a[4],a[5]), pk2(b[4],b[5]), c);
  c = fdot2f(pk2(a[6],a[7]), pk2(b[6],b[7]), c);
  return c;
}

// ---------------- k0: Wk|Wv -> f16 [256][128] ----------------
__global__ __launch_bounds__(256) void k0_wconv(const float* __restrict__ Wk,
    const float* __restrict__ Wv, f16* __restrict__ WkvF)
{
  const int i = blockIdx.x*256 + threadIdx.x;           // 0..8191, one f32x4 each
  const float4 v = (i < 4096) ? ((const float4*)Wk)[i] : ((const float4*)Wv)[i-4096];
  f16x2 lo = pkrtz(v.x,v.y), hi = pkrtz(v.z,v.w);
  f16x4 o = __builtin_shufflevector(lo, hi, 0, 1, 2, 3);
  *(f16x4*)(WkvF + i*4) = o;
}

// ---------------- k1: MFMA K/V projection + nodes -> f16 ----------------
// grid (16, 64), 256 thr (4 waves), 64 node rows per block.
// Kp: [bh][n(1000)][16] ; Vt: [bh][d(16)][n(1000)]
#define NSTR 132
__global__ __launch_bounds__(256) void k1_proj(const float* __restrict__ nodes,
    const f16* __restrict__ WkvF,
    f16* __restrict__ nodesF, f16* __restrict__ Kp, f16* __restrict__ Vt)
{
  __shared__ f16 lds[64*NSTR];
  const int tid = threadIdx.x, lane = tid & 63, w = tid >> 6;
  const int b = blockIdx.y;
  const int n0 = blockIdx.x * 64;
  const int rows = min(64, 1000 - n0);                  // 64 or 40
  for (int i = tid; i < rows*32; i += 256) {            // 32 f32x4 per row
    const int r = i >> 5, cq = i & 31;
    float4 v = ((const float4*)(nodes + ((size_t)b*1000 + n0 + r)*128))[cq];
    f16x2 lo = pkrtz(v.x,v.y), hi = pkrtz(v.z,v.w);
    f16x4 o = __builtin_shufflevector(lo, hi, 0, 1, 2, 3);
    *(f16x4*)(lds + r*NSTR + cq*4) = o;
    *(f16x4*)(nodesF + ((size_t)b*1000 + n0 + r)*128 + cq*4) = o;
  }
  __syncthreads();
  const int col = lane & 15, g = lane >> 4, g4 = g*4;
  const int mloc = w*16 + col;                          // wave-local node row (as frag row/col)
  f16x4 nf[8];
  #pragma unroll
  for (int kk = 0; kk < 8; ++kk)
    nf[kk] = *(const f16x4*)(lds + min(mloc, rows-1)*NSTR + kk*16 + g4);
  for (int ct = 0; ct < 16; ++ct) {
    f16x4 wf[8];
    const f16* wbase = WkvF + (ct*16 + col)*128;
    #pragma unroll
    for (int kk = 0; kk < 8; ++kk) wf[kk] = *(const f16x4*)(wbase + kk*16 + g4);
    f32x4 acc = {0.f, 0.f, 0.f, 0.f};
    if (ct < 8) {                                       // K-head ct: D[c][m]
      #pragma unroll
      for (int kk = 0; kk < 8; ++kk) acc = mfma16(wf[kk], nf[kk], acc);
      if (mloc < rows) {
        const int nn = n0 + mloc;
        f16x4 ov = __builtin_shufflevector(pk2((f16)acc[0],(f16)acc[1]),
                                           pk2((f16)acc[2],(f16)acc[3]), 0,1,2,3);
        *(f16x4*)(Kp + ((size_t)(b*8+ct)*1000 + nn)*16 + g4) = ov;
      }
    } else {                                            // V-head ct-8: D[m][c]
      #pragma unroll
      for (int kk = 0; kk < 8; ++kk) acc = mfma16(nf[kk], wf[kk], acc);
      if (w*16 + g4 + 3 < rows) {
        const int nbase = n0 + w*16 + g4;
        f16x4 ov = __builtin_shufflevector(pk2((f16)acc[0],(f16)acc[1]),
                                           pk2((f16)acc[2],(f16)acc[3]), 0,1,2,3);
        *(f16x4*)(Vt + ((size_t)(b*8+(ct-8))*16 + col)*1000 + nbase) = ov;
      }
    }
  }
}

// ---------------- k2: q = q1@Wqf^T + last@Wql^T + LoRA ----------------
// grid 400, 256 thr, 32 rows/block. qF layout: [bh][m(200)][16]
__global__ __launch_bounds__(256) void k2_q(const float* __restrict__ q1,
    const float* __restrict__ last, const float* __restrict__ Wqf,
    const float* __restrict__ Wql, const float* __restrict__ lqA,
    const float* __restrict__ lqB, f16* __restrict__ qF)
{
  __shared__ f16 q1r[32*128];
  __shared__ f16 lar[32*128];
  __shared__ float t16[32*16];
  const int tid = threadIdx.x;
  const int row0 = blockIdx.x * 32;
  {
    const float4* s1 = (const float4*)(q1 + (size_t)row0*128);
    const float4* s2 = (const float4*)(last + (size_t)row0*128);
    f16x2* d1 = (f16x2*)q1r; f16x2* d2 = (f16x2*)lar;
    for (int i = tid; i < 32*32; i += 256) {
      float4 v = s1[i];
      d1[2*i] = pkrtz(v.x,v.y); d1[2*i+1] = pkrtz(v.z,v.w);
      float4 u = s2[i];
      d2[2*i] = pkrtz(u.x,u.y); d2[2*i+1] = pkrtz(u.z,u.w);
    }
  }
  __syncthreads();
  for (int idx = tid; idx < 32*16; idx += 256) {
    const int r = idx >> 4, kk = idx & 15;
    const f16x8* lrow = (const f16x8*)(lar + r*128);
    const float* arow = lqA + kk*128;
    float s = 0.f;
    #pragma unroll
    for (int cc = 0; cc < 16; ++cc) {
      f16x8 a = lrow[cc];
      float4 wa = *(const float4*)(arow + cc*8);
      float4 wb = *(const float4*)(arow + cc*8 + 4);
      s = fdot2f(pk2(a[0],a[1]), pkrtz(wa.x,wa.y), s);
      s = fdot2f(pk2(a[2],a[3]), pkrtz(wa.z,wa.w), s);
      s = fdot2f(pk2(a[4],a[5]), pkrtz(wb.x,wb.y), s);
      s = fdot2f(pk2(a[6],a[7]), pkrtz(wb.z,wb.w), s);
    }
    t16[idx] = s;
  }
  __syncthreads();
  const int c = tid & 127, rg = tid >> 7, rb = rg*16;
  float acc[16];
  #pragma unroll
  for (int r = 0; r < 16; ++r) acc[r] = 0.f;
  const float* wfr = Wqf + c*128;
  const float* wlr = Wql + c*128;
  for (int c0 = 0; c0 < 128; c0 += 16) {
    float4 f0 = *(const float4*)(wfr + c0);
    float4 f1 = *(const float4*)(wfr + c0 + 4);
    float4 f2 = *(const float4*)(wfr + c0 + 8);
    float4 f3 = *(const float4*)(wfr + c0 + 12);
    f16x2 wf[8] = { pkrtz(f0.x,f0.y), pkrtz(f0.z,f0.w), pkrtz(f1.x,f1.y), pkrtz(f1.z,f1.w),
                    pkrtz(f2.x,f2.y), pkrtz(f2.z,f2.w), pkrtz(f3.x,f3.y), pkrtz(f3.z,f3.w) };
    float4 g0 = *(const float4*)(wlr + c0);
    float4 g1 = *(const float4*)(wlr + c0 + 4);
    float4 g2 = *(const float4*)(wlr + c0 + 8);
    float4 g3 = *(const float4*)(wlr + c0 + 12);
    f16x2 wl[8] = { pkrtz(g0.x,g0.y), pkrtz(g0.z,g0.w), pkrtz(g1.x,g1.y), pkrtz(g1.z,g1.w),
                    pkrtz(g2.x,g2.y), pkrtz(g2.z,g2.w), pkrtz(g3.x,g3.y), pkrtz(g3.z,g3.w) };
    #pragma unroll
    for (int r = 0; r < 16; ++r) {
      const f16x8* qp = (const f16x8*)(q1r + (rb+r)*128 + c0);
      const f16x8* lp = (const f16x8*)(lar + (rb+r)*128 + c0);
      f16x8 a0 = qp[0], a1 = qp[1], b0 = lp[0], b1 = lp[1];
      float s = acc[r];
      s = fdot2f(pk2(a0[0],a0[1]), wf[0], s);
      s = fdot2f(pk2(a0[2],a0[3]), wf[1], s);
      s = fdot2f(pk2(a0[4],a0[5]), wf[2], s);
      s = fdot2f(pk2(a0[6],a0[7]), wf[3], s);
      s = fdot2f(pk2(a1[0],a1[1]), wf[4], s);
      s = fdot2f(pk2(a1[2],a1[3]), wf[5], s);
      s = fdot2f(pk2(a1[4],a1[5]), wf[6], s);
      s = fdot2f(pk2(a1[6],a1[7]), wf[7], s);
      s = fdot2f(pk2(b0[0],b0[1]), wl[0], s);
      s = fdot2f(pk2(b0[2],b0[3]), wl[1], s);
      s = fdot2f(pk2(b0[4],b0[5]), wl[2], s);
      s = fdot2f(pk2(b0[6],b0[7]), wl[3], s);
      s = fdot2f(pk2(b1[0],b1[1]), wl[4], s);
      s = fdot2f(pk2(b1[2],b1[3]), wl[5], s);
      s = fdot2f(pk2(b1[4],b1[5]), wl[6], s);
      s = fdot2f(pk2(b1[6],b1[7]), wl[7], s);
      acc[r] = s;
    }
  }
  const float* lb = lqB + c*16;
  float lbv[16];
  #pragma unroll
  for (int i = 0; i < 16; i += 4) {
    float4 t = *(const float4*)(lb + i);
    lbv[i] = t.x; lbv[i+1] = t.y; lbv[i+2] = t.z; lbv[i+3] = t.w;
  }
  #pragma unroll
  for (int r = 0; r < 16; ++r) {
    float dl = 0.f;
    #pragma unroll
    for (int kk = 0; kk < 16; ++kk) dl += t16[(rb+r)*16 + kk] * lbv[kk];
    acc[r] += dl * LORA_SCALE;
  }
  const int h = c >> 4, d = c & 15;
  #pragma unroll
  for (int r = 0; r < 16; ++r) {
    const int grow = row0 + rb + r;
    const int b = grow / 200, m = grow % 200;
    qF[(((size_t)b*8 + h)*200 + m)*16 + d] = (f16)acc[r];
  }
}

// ---------------- k3: per-(b,h) MFMA flash attention, two-pass fixed-max ----------------
// grid (64,8) [b=x so all 8 heads of b share an XCD L2 for the mask panel], 512 thr.
// Pass1: row max via 63 QK MFMAs, lane-local fmax only (mask<=0 => unmasked max is an
//        upper bound; p<=1 so f16-safe). One 2-shfl reduce at end.
// Pass2: recompute QK, p=exp2(s*c + (mask-M)*l2e), accumulate PV directly. No rescale,
//        no per-iter cross-lane ops. Tail n-tile (t=62) peeled.
#define KSTR 20
#define VSTR 1004
__global__ __launch_bounds__(512) void k3_attn(const f16* __restrict__ Kp,
    const f16* __restrict__ Vt, const f16* __restrict__ qF,
    const float* __restrict__ mask, f16* __restrict__ ocF)
{
  extern __shared__ char smem[];
  f16* Kl = (f16*)smem;                     // [1008][KSTR] : 40320 B
  f16* Vl = (f16*)(smem + 1008*KSTR*2);     // [16][VSTR]   : 32128 B
  const int tid = threadIdx.x;
  const int lane = tid & 63, w = tid >> 6;
  const int b = blockIdx.x, h = blockIdx.y;
  const int bh = b*8 + h;
  for (int n = tid; n < 1008; n += 512) {
    f16x4 z = {};
    f16x4 v0 = z, v1 = z, v2 = z, v3 = z;
    if (n < 1000) {
      const f16x4* src = (const f16x4*)(Kp + (size_t)bh*16000 + n*16);
      v0 = src[0]; v1 = src[1]; v2 = src[2]; v3 = src[3];
    }
    f16* dst = Kl + n*KSTR;
    *(f16x4*)(dst)    = v0;
    *(f16x4*)(dst+4)  = v1;
    *(f16x4*)(dst+8)  = v2;
    *(f16x4*)(dst+12) = v3;
  }
  for (int i = tid; i < 2000; i += 512) {
    const int d = i / 125, c8 = i - d*125;
    const f16x4* src = (const f16x4*)(Vt + (size_t)bh*16000 + d*1000 + c8*8);
    f16* dst = Vl + d*VSTR + c8*8;
    *(f16x4*)(dst)   = src[0];
    *(f16x4*)(dst+4) = src[1];
  }
  if (tid < 64) { const int d = tid >> 2, e = 1000 + (tid & 3); Vl[d*VSTR + e] = (f16)0; }
  __syncthreads();

  const int col = lane & 15, g = lane >> 4, g4 = g*4;
  const f32x4 zero = {0.f, 0.f, 0.f, 0.f};
  for (int mt = w; mt < 13; mt += 8) {
    const int m0 = mt*16;
    const int mq = min(m0 + col, 199);
    const f16x4 qf = *(const f16x4*)(qF + (size_t)bh*3200 + mq*16 + g4);
    const float* mp = mask + ((size_t)b*200 + mq)*1000;

    // ---- pass 1: raw-score row max (no mask, no cross-lane until end) ----
    float mx = -1e30f;
    #pragma unroll 4
    for (int t = 0; t < 62; ++t) {
      const f16x4 kf = *(const f16x4*)(Kl + (t*16+col)*KSTR + g4);
      f32x4 s4 = mfma16(kf, qf, zero);
      mx = fmaxf(mx, fmaxf(fmaxf(s4[0], s4[1]), fmaxf(s4[2], s4[3])));
    }
    { // t = 62: n = 992+g4+r, valid only for g<2
      const f16x4 kf = *(const f16x4*)(Kl + (62*16+col)*KSTR + g4);
      f32x4 s4 = mfma16(kf, qf, zero);
      if (g < 2) mx = fmaxf(mx, fmaxf(fmaxf(s4[0], s4[1]), fmaxf(s4[2], s4[3])));
    }
    mx = fmaxf(mx, __shfl_xor(mx, 16, 64));
    mx = fmaxf(mx, __shfl_xor(mx, 32, 64));
    const float M = mx * 0.25f;                       // scaled-domain upper bound
    const float mb = -M * 1.44269504f;                // bias for exp2

    // ---- pass 2: p = exp2(s*0.25*l2e + (mask - M)*l2e); PV accumulate ----
    f32x4 O = zero;
    float l0 = 0.f, l1 = 0.f, l2 = 0.f, l3 = 0.f;
    #pragma unroll 2
    for (int t = 0; t < 62; ++t) {
      const int n0 = t*16 + g4;
      const f16x4 kf = *(const f16x4*)(Kl + (t*16+col)*KSTR + g4);
      f32x4 s4 = mfma16(kf, qf, zero);
      const float4 mk = *(const float4*)(mp + n0);
      const float p0 = exp2f(fmaf(s4[0], 0.360673760f, fmaf(mk.x, 1.44269504f, mb)));
      const float p1 = exp2f(fmaf(s4[1], 0.360673760f, fmaf(mk.y, 1.44269504f, mb)));
      const float p2 = exp2f(fmaf(s4[2], 0.360673760f, fmaf(mk.z, 1.44269504f, mb)));
      const float p3 = exp2f(fmaf(s4[3], 0.360673760f, fmaf(mk.w, 1.44269504f, mb)));
      l0 += p0; l1 += p1; l2 += p2; l3 += p3;
      const f16x4 pf = __builtin_shufflevector(pkrtz(p0, p1), pkrtz(p2, p3), 0, 1, 2, 3);
      const f16x4 vf = *(const f16x4*)(Vl + col*VSTR + n0);
      O = mfma16(vf, pf, O);
    }
    { // t = 62 tail: only g<2 lanes carry real scores
      const int n0 = 62*16 + g4;
      const f16x4 kf = *(const f16x4*)(Kl + (62*16+col)*KSTR + g4);
      f32x4 s4 = mfma16(kf, qf, zero);
      float p0 = 0.f, p1 = 0.f, p2 = 0.f, p3 = 0.f;
      if (g < 2) {
        const float4 mk = *(const float4*)(mp + n0);
        p0 = exp2f(fmaf(s4[0], 0.360673760f, fmaf(mk.x, 1.44269504f, mb)));
        p1 = exp2f(fmaf(s4[1], 0.360673760f, fmaf(mk.y, 1.44269504f, mb)));
        p2 = exp2f(fmaf(s4[2], 0.360673760f, fmaf(mk.z, 1.44269504f, mb)));
        p3 = exp2f(fmaf(s4[3], 0.360673760f, fmaf(mk.w, 1.44269504f, mb)));
        l0 += p0; l1 += p1; l2 += p2; l3 += p3;
      }
      const f16x4 pf = __builtin_shufflevector(pkrtz(p0, p1), pkrtz(p2, p3), 0, 1, 2, 3);
      const f16x4 vf = *(const f16x4*)(Vl + col*VSTR + ((g < 2) ? n0 : 0));
      O = mfma16(vf, pf, O);
    }
    float lrun = (l0 + l1) + (l2 + l3);
    lrun += __shfl_xor(lrun, 16, 64);
    lrun += __shfl_xor(lrun, 32, 64);
    const float inv = 1.f / lrun;
    if (m0 + col < 200) {
      const f16x2 o01 = pkrtz(O[0]*inv, O[1]*inv);
      const f16x2 o23 = pkrtz(O[2]*inv, O[3]*inv);
      const f16x4 ov = __builtin_shufflevector(o01, o23, 0, 1, 2, 3);
      *(f16x4*)(ocF + ((size_t)b*200 + m0 + col)*128 + h*16 + g4) = ov;
    }
  }
}

// ---------------- k4: mh = oc@Wc^T + bc + LoRA ----------------
__global__ __launch_bounds__(256) void k4_comb(const f16* __restrict__ ocF,
    const float* __restrict__ Wc, const float* __restrict__ bc,
    const float* __restrict__ lcA, const float* __restrict__ lcB,
    f16* __restrict__ mhF)
{
  __shared__ f16 ocr[32*128];
  __shared__ float t16[32*16];
  const int tid = threadIdx.x;
  const int row0 = blockIdx.x * 32;
  {
    const f16x8* s1 = (const f16x8*)(ocF + (size_t)row0*128);
    f16x8* d1 = (f16x8*)ocr;
    for (int i = tid; i < 512; i += 256) d1[i] = s1[i];
  }
  __syncthreads();
  for (int idx = tid; idx < 32*16; idx += 256) {
    const int r = idx >> 4, kk = idx & 15;
    const f16x8* lrow = (const f16x8*)(ocr + r*128);
    const float* arow = lcA + kk*128;
    float s = 0.f;
    #pragma unroll
    for (int cc = 0; cc < 16; ++cc) {
      f16x8 a = lrow[cc];
      float4 wa = *(const float4*)(arow + cc*8);
      float4 wb = *(const float4*)(arow + cc*8 + 4);
      s = fdot2f(pk2(a[0],a[1]), pkrtz(wa.x,wa.y), s);
      s = fdot2f(pk2(a[2],a[3]), pkrtz(wa.z,wa.w), s);
      s = fdot2f(pk2(a[4],a[5]), pkrtz(wb.x,wb.y), s);
      s = fdot2f(pk2(a[6],a[7]), pkrtz(wb.z,wb.w), s);
    }
    t16[idx] = s;
  }
  __syncthreads();
  const int c = tid & 127, rg = tid >> 7, rb = rg*16;
  float acc[16];
  const float bias = bc[c];
  #pragma unroll
  for (int r = 0; r < 16; ++r) acc[r] = bias;
  const float* wrow = Wc + c*128;
  for (int c0 = 0; c0 < 128; c0 += 16) {
    float4 w0 = *(const float4*)(wrow + c0);
    float4 w1 = *(const float4*)(wrow + c0 + 4);
    float4 w2 = *(const float4*)(wrow + c0 + 8);
    float4 w3 = *(const float4*)(wrow + c0 + 12);
    f16x2 wv[8] = { pkrtz(w0.x,w0.y), pkrtz(w0.z,w0.w), pkrtz(w1.x,w1.y), pkrtz(w1.z,w1.w),
                    pkrtz(w2.x,w2.y), pkrtz(w2.z,w2.w), pkrtz(w3.x,w3.y), pkrtz(w3.z,w3.w) };
    #pragma unroll
    for (int r = 0; r < 16; ++r) {
      const f16x8* op = (const f16x8*)(ocr + (rb+r)*128 + c0);
      f16x8 a0 = op[0], a1 = op[1];
      float s = acc[r];
      s = fdot2f(pk2(a0[0],a0[1]), wv[0], s);
      s = fdot2f(pk2(a0[2],a0[3]), wv[1], s);
      s = fdot2f(pk2(a0[4],a0[5]), wv[2], s);
      s = fdot2f(pk2(a0[6],a0[7]), wv[3], s);
      s = fdot2f(pk2(a1[0],a1[1]), wv[4], s);
      s = fdot2f(pk2(a1[2],a1[3]), wv[5], s);
      s = fdot2f(pk2(a1[4],a1[5]), wv[6], s);
      s = fdot2f(pk2(a1[6],a1[7]), wv[7], s);
      acc[r] = s;
    }
  }
  const float* lb = lcB + c*16;
  float lbv[16];
  #pragma unroll
  for (int i = 0; i < 16; i += 4) {
    float4 t = *(const float4*)(lb + i);
    lbv[i] = t.x; lbv[i+1] = t.y; lbv[i+2] = t.z; lbv[i+3] = t.w;
  }
  #pragma unroll
  for (int r = 0; r < 16; ++r) {
    float dl = 0.f;
    #pragma unroll
    for (int kk = 0; kk < 16; ++kk) dl += t16[(rb+r)*16 + kk] * lbv[kk];
    acc[r] += dl * LORA_SCALE;
  }
  #pragma unroll
  for (int r = 0; r < 16; ++r) {
    mhF[(size_t)(row0 + rb + r)*128 + c] = (f16)acc[r];
  }
}

// ---------------- k5: MFMA probs = softmax(10*tanh(mh@nodes^T/sqrt(128)) + mask) ----------------
// grid (64, 13), 512 thr (8 waves). Block = (b, 16 m-rows); wave covers n-tiles w+8i.
__global__ __launch_bounds__(512) void k5_final(const f16* __restrict__ mhF,
    const f16* __restrict__ nodesF, const float* __restrict__ mask,
    float* __restrict__ out)
{
  __shared__ float sums[8][16];
  const int tid = threadIdx.x, lane = tid & 63, w = tid >> 6;
  const int b = blockIdx.x, mt = blockIdx.y;
  const int col = lane & 15, g = lane >> 4, g4 = g*4;
  const int m = mt*16 + col;
  const int mq = min(m, 199);
  f16x4 bf[8];
  const f16* mb = mhF + (size_t)(b*200 + mq)*128;
  #pragma unroll
  for (int kk = 0; kk < 8; ++kk) bf[kk] = *(const f16x4*)(mb + kk*16 + g4);
  const float* mrow = mask + (size_t)(b*200 + mq)*1000;
  const f16* nb = nodesF + (size_t)b*128000;
  float p[8][4];
  float lsum = 0.f;
  #pragma unroll
  for (int i = 0; i < 8; ++i) {
    const int t = w + i*8;
    if (t < 63) {
      const int nr = min(t*16 + col, 999);
      const f16* na = nb + nr*128;
      f32x4 acc = {0.f, 0.f, 0.f, 0.f};
      #pragma unroll
      for (int kk = 0; kk < 8; ++kk) {
        f16x4 af = *(const f16x4*)(na + kk*16 + g4);
        acc = mfma16(af, bf[kk], acc);
      }
      const int n0 = t*16 + g4;
      float mkv[4] = {0.f, 0.f, 0.f, 0.f};
      if (n0 + 3 < 1000) {
        float4 mk = *(const float4*)(mrow + n0);
        mkv[0] = mk.x; mkv[1] = mk.y; mkv[2] = mk.z; mkv[3] = mk.w;
      }
      #pragma unroll
      for (int r = 0; r < 4; ++r) {
        float x = acc[r] * 0.08838834764831845f;            // /sqrt(128)
        float e = exp2f(x * 2.8853900817779268f);           // e^{2x}
        float th = 1.f - 2.f/(e + 1.f);                     // tanh(x)
        float scv = 10.f*th + mkv[r];
        float pv = exp2f(scv * 1.44269504f);                // no-max softmax: sc <= 10
        pv = (n0 + r < 1000) ? pv : 0.f;
        p[i][r] = pv;
        lsum += pv;
      }
    } else {
      p[i][0] = p[i][1] = p[i][2] = p[i][3] = 0.f;
    }
  }
  lsum += __shfl_xor(lsum, 16, 64);
  lsum += __shfl_xor(lsum, 32, 64);
  if (lane < 16) sums[w][lane] = lsum;
  __syncthreads();
  float S = 0.f;
  #pragma unroll
  for (int ww = 0; ww < 8; ++ww) S += sums[ww][col];
  const float inv = 1.f / S;
  if (m < 200) {
    float* ob = out + (size_t)(b*200 + m)*1000;
    #pragma unroll
    for (int i = 0; i < 8; ++i) {
      const int t = w + i*8;
      if (t < 63) {
        const int n0 = t*16 + g4;
        if (n0 + 3 < 1000) {
          float4 o;
          o.x = p[i][0]*inv; o.y = p[i][1]*inv; o.z = p[i][2]*inv; o.w = p[i][3]*inv;
          *(float4*)(ob + n0) = o;
        } else {
          #pragma unroll
          for (int r = 0; r < 4; ++r) if (n0 + r < 1000) ob[n0+r] = p[i][r]*inv;
        }
      }
    }
  }
}

extern "C" void kernel_launch(void* const* d_in, const int* in_sizes, int n_in,
                              void* d_out, int out_size, void* d_ws, size_t ws_size,
                              hipStream_t stream)
{
  (void)in_sizes; (void)n_in; (void)out_size; (void)ws_size;
  const float* nodes = (const float*)d_in[0];
  const float* q1    = (const float*)d_in[1];
  const float* last  = (const float*)d_in[2];
  const float* mask  = (const float*)d_in[3];
  const float* Wqf   = (const float*)d_in[4];
  const float* Wql   = (const float*)d_in[5];
  const float* Wk    = (const float*)d_in[6];
  const float* Wv    = (const float*)d_in[7];
  const float* Wc    = (const float*)d_in[8];
  const float* bc    = (const float*)d_in[9];
  const float* lqA   = (const float*)d_in[10];
  const float* lqB   = (const float*)d_in[11];
  const float* lcA   = (const float*)d_in[12];
  const float* lcB   = (const float*)d_in[13];
  float* out = (float*)d_out;
  char* ws = (char*)d_ws;
  // ws layout (bytes):
  f16* nodesF = (f16*)(ws);               // 16,384,000
  f16* Kp     = (f16*)(ws + 16384000);    // 16,384,000
  f16* Vt     = (f16*)(ws + 32768000);    // 16,384,000
  f16* qF     = (f16*)(ws + 49152000);    //  3,276,800
  f16* ocF    = (f16*)(ws + 52428800);    //  3,276,800
  f16* mhF    = (f16*)(ws + 55705600);    //  3,276,800
  f16* WkvF   = (f16*)(ws + 58982400);    //     65,536  (end 59,047,936)

  k0_wconv<<<dim3(32), 256, 0, stream>>>(Wk, Wv, WkvF);
  k1_proj<<<dim3(16, 64), 256, 0, stream>>>(nodes, WkvF, nodesF, Kp, Vt);
  k2_q<<<dim3(400), 256, 0, stream>>>(q1, last, Wqf, Wql, lqA, lqB, qF);
  k3_attn<<<dim3(64, 8), 512, 72448, stream>>>(Kp, Vt, qF, mask, ocF);
  k4_comb<<<dim3(400), 256, 0, stream>>>(ocF, Wc, bc, lcA, lcB, mhF);
  k5_final<<<dim3(64, 13), 512, 0, stream>>>(mhF, nodesF, mask, out);
}

// Round 6
// 281.158 us; speedup vs baseline: 1.5988x; 1.0187x over previous
//
#include <hip/hip_runtime.h>
#include <hip/hip_bf16.h>

// TSP decoder forward: B=64, POMO=200, N=1000, EMB=128, H=8, D=16.
// k0 W->f16 | k1 MFMA K/V proj + nodes->f16 | k2 q (+LoRA) |
// k3 MFMA flash attention (two-pass fixed-max, 1 m-tile/wave, dual chains) |
// k4 combine (+LoRA) | k5 MFMA mh@nodes^T + tanh-softmax.

typedef _Float16 f16;
typedef _Float16 f16x2 __attribute__((ext_vector_type(2)));
typedef _Float16 f16x4 __attribute__((ext_vector_type(4)));
typedef _Float16 f16x8 __attribute__((ext_vector_type(8)));
typedef __fp16  h4   __attribute__((ext_vector_type(4)));
typedef float   f32x4 __attribute__((ext_vector_type(4)));

#define LORA_SCALE 1.0f

__device__ __forceinline__ f16x2 pk2(f16 a, f16 b){ f16x2 r; r[0]=a; r[1]=b; return r; }

#if __has_builtin(__builtin_amdgcn_fdot2)
__device__ __forceinline__ float fdot2f(f16x2 a, f16x2 b, float c){ return __builtin_amdgcn_fdot2(a, b, c, false); }
#else
__device__ __forceinline__ float fdot2f(f16x2 a, f16x2 b, float c){ return c + (float)a[0]*(float)b[0] + (float)a[1]*(float)b[1]; }
#endif

#if __has_builtin(__builtin_amdgcn_cvt_pkrtz)
__device__ __forceinline__ f16x2 pkrtz(float a, float b){
  return __builtin_bit_cast(f16x2, __builtin_amdgcn_cvt_pkrtz(a, b));
}
#else
__device__ __forceinline__ f16x2 pkrtz(float a, float b){ return pk2((f16)a, (f16)b); }
#endif

// D[i][j] = sum_k A[i][k]*B[k][j] + C  via v_mfma_f32_16x16x16_f16.
// A: lane holds row i=(l&15), k=4*(l>>4)+j. B: lane holds col j=(l&15), k=4*(l>>4)+j.
// D: lane holds col j=(l&15), row i=4*(l>>4)+reg.   (validated end-to-end in k3/k5)
__device__ __forceinline__ f32x4 mfma16(f16x4 a, f16x4 b, f32x4 c){
  return __builtin_amdgcn_mfma_f32_16x16x16f16(
      __builtin_bit_cast(h4, a), __builtin_bit_cast(h4, b), c, 0, 0, 0);
}

__device__ __forceinline__ float dot8f(f16x8 a, f16x8 b, float c){
  c = fdot2f(pk2(a[0],a[1]), pk2(b[0],b[1]), c);
  c = fdot2f(pk2(a[2],a[3]), pk2(b[2],b[3]), c);
  c = fdot2f(pk2(a[4],a[5]), pk2(b[4],b[5]), c);
  c = fdot2f(pk2(a[6],a[7]), pk2(b[6],b[7]), c);
  return c;
}

// ---------------- k0: Wk|Wv -> f16 [256][128] ----------------
__global__ __launch_bounds__(256) void k0_wconv(const float* __restrict__ Wk,
    const float* __restrict__ Wv, f16* __restrict__ WkvF)
{
  const int i = blockIdx.x*256 + threadIdx.x;           // 0..8191, one f32x4 each
  const float4 v = (i < 4096) ? ((const float4*)Wk)[i] : ((const float4*)Wv)[i-4096];
  f16x2 lo = pkrtz(v.x,v.y), hi = pkrtz(v.z,v.w);
  f16x4 o = __builtin_shufflevector(lo, hi, 0, 1, 2, 3);
  *(f16x4*)(WkvF + i*4) = o;
}

// ---------------- k1: MFMA K/V projection + nodes -> f16 ----------------
// grid (16, 64), 256 thr (4 waves), 64 node rows per block.
// Kp: [bh][n(1000)][16] ; Vt: [bh][d(16)][n(1000)]
#define NSTR 132
__global__ __launch_bounds__(256) void k1_proj(const float* __restrict__ nodes,
    const f16* __restrict__ WkvF,
    f16* __restrict__ nodesF, f16* __restrict__ Kp, f16* __restrict__ Vt)
{
  __shared__ f16 lds[64*NSTR];
  const int tid = threadIdx.x, lane = tid & 63, w = tid >> 6;
  const int b = blockIdx.y;
  const int n0 = blockIdx.x * 64;
  const int rows = min(64, 1000 - n0);                  // 64 or 40
  for (int i = tid; i < rows*32; i += 256) {            // 32 f32x4 per row
    const int r = i >> 5, cq = i & 31;
    float4 v = ((const float4*)(nodes + ((size_t)b*1000 + n0 + r)*128))[cq];
    f16x2 lo = pkrtz(v.x,v.y), hi = pkrtz(v.z,v.w);
    f16x4 o = __builtin_shufflevector(lo, hi, 0, 1, 2, 3);
    *(f16x4*)(lds + r*NSTR + cq*4) = o;
    *(f16x4*)(nodesF + ((size_t)b*1000 + n0 + r)*128 + cq*4) = o;
  }
  __syncthreads();
  const int col = lane & 15, g = lane >> 4, g4 = g*4;
  const int mloc = w*16 + col;                          // wave-local node row (as frag row/col)
  f16x4 nf[8];
  #pragma unroll
  for (int kk = 0; kk < 8; ++kk)
    nf[kk] = *(const f16x4*)(lds + min(mloc, rows-1)*NSTR + kk*16 + g4);
  for (int ct = 0; ct < 16; ++ct) {
    f16x4 wf[8];
    const f16* wbase = WkvF + (ct*16 + col)*128;
    #pragma unroll
    for (int kk = 0; kk < 8; ++kk) wf[kk] = *(const f16x4*)(wbase + kk*16 + g4);
    f32x4 acc = {0.f, 0.f, 0.f, 0.f};
    if (ct < 8) {                                       // K-head ct: D[c][m]
      #pragma unroll
      for (int kk = 0; kk < 8; ++kk) acc = mfma16(wf[kk], nf[kk], acc);
      if (mloc < rows) {
        const int nn = n0 + mloc;
        f16x4 ov = __builtin_shufflevector(pk2((f16)acc[0],(f16)acc[1]),
                                           pk2((f16)acc[2],(f16)acc[3]), 0,1,2,3);
        *(f16x4*)(Kp + ((size_t)(b*8+ct)*1000 + nn)*16 + g4) = ov;
      }
    } else {                                            // V-head ct-8: D[m][c]
      #pragma unroll
      for (int kk = 0; kk < 8; ++kk) acc = mfma16(nf[kk], wf[kk], acc);
      if (w*16 + g4 + 3 < rows) {
        const int nbase = n0 + w*16 + g4;
        f16x4 ov = __builtin_shufflevector(pk2((f16)acc[0],(f16)acc[1]),
                                           pk2((f16)acc[2],(f16)acc[3]), 0,1,2,3);
        *(f16x4*)(Vt + ((size_t)(b*8+(ct-8))*16 + col)*1000 + nbase) = ov;
      }
    }
  }
}

// ---------------- k2: q = q1@Wqf^T + last@Wql^T + LoRA ----------------
// grid 400, 256 thr, 32 rows/block. qF layout: [bh][m(200)][16]
__global__ __launch_bounds__(256) void k2_q(const float* __restrict__ q1,
    const float* __restrict__ last, const float* __restrict__ Wqf,
    const float* __restrict__ Wql, const float* __restrict__ lqA,
    const float* __restrict__ lqB, f16* __restrict__ qF)
{
  __shared__ f16 q1r[32*128];
  __shared__ f16 lar[32*128];
  __shared__ float t16[32*16];
  const int tid = threadIdx.x;
  const int row0 = blockIdx.x * 32;
  {
    const float4* s1 = (const float4*)(q1 + (size_t)row0*128);
    const float4* s2 = (const float4*)(last + (size_t)row0*128);
    f16x2* d1 = (f16x2*)q1r; f16x2* d2 = (f16x2*)lar;
    for (int i = tid; i < 32*32; i += 256) {
      float4 v = s1[i];
      d1[2*i] = pkrtz(v.x,v.y); d1[2*i+1] = pkrtz(v.z,v.w);
      float4 u = s2[i];
      d2[2*i] = pkrtz(u.x,u.y); d2[2*i+1] = pkrtz(u.z,u.w);
    }
  }
  __syncthreads();
  for (int idx = tid; idx < 32*16; idx += 256) {
    const int r = idx >> 4, kk = idx & 15;
    const f16x8* lrow = (const f16x8*)(lar + r*128);
    const float* arow = lqA + kk*128;
    float s = 0.f;
    #pragma unroll
    for (int cc = 0; cc < 16; ++cc) {
      f16x8 a = lrow[cc];
      float4 wa = *(const float4*)(arow + cc*8);
      float4 wb = *(const float4*)(arow + cc*8 + 4);
      s = fdot2f(pk2(a[0],a[1]), pkrtz(wa.x,wa.y), s);
      s = fdot2f(pk2(a[2],a[3]), pkrtz(wa.z,wa.w), s);
      s = fdot2f(pk2(a[4],a[5]), pkrtz(wb.x,wb.y), s);
      s = fdot2f(pk2(a[6],a[7]), pkrtz(wb.z,wb.w), s);
    }
    t16[idx] = s;
  }
  __syncthreads();
  const int c = tid & 127, rg = tid >> 7, rb = rg*16;
  float acc[16];
  #pragma unroll
  for (int r = 0; r < 16; ++r) acc[r] = 0.f;
  const float* wfr = Wqf + c*128;
  const float* wlr = Wql + c*128;
  for (int c0 = 0; c0 < 128; c0 += 16) {
    float4 f0 = *(const float4*)(wfr + c0);
    float4 f1 = *(const float4*)(wfr + c0 + 4);
    float4 f2 = *(const float4*)(wfr + c0 + 8);
    float4 f3 = *(const float4*)(wfr + c0 + 12);
    f16x2 wf[8] = { pkrtz(f0.x,f0.y), pkrtz(f0.z,f0.w), pkrtz(f1.x,f1.y), pkrtz(f1.z,f1.w),
                    pkrtz(f2.x,f2.y), pkrtz(f2.z,f2.w), pkrtz(f3.x,f3.y), pkrtz(f3.z,f3.w) };
    float4 g0 = *(const float4*)(wlr + c0);
    float4 g1 = *(const float4*)(wlr + c0 + 4);
    float4 g2 = *(const float4*)(wlr + c0 + 8);
    float4 g3 = *(const float4*)(wlr + c0 + 12);
    f16x2 wl[8] = { pkrtz(g0.x,g0.y), pkrtz(g0.z,g0.w), pkrtz(g1.x,g1.y), pkrtz(g1.z,g1.w),
                    pkrtz(g2.x,g2.y), pkrtz(g2.z,g2.w), pkrtz(g3.x,g3.y), pkrtz(g3.z,g3.w) };
    #pragma unroll
    for (int r = 0; r < 16; ++r) {
      const f16x8* qp = (const f16x8*)(q1r + (rb+r)*128 + c0);
      const f16x8* lp = (const f16x8*)(lar + (rb+r)*128 + c0);
      f16x8 a0 = qp[0], a1 = qp[1], b0 = lp[0], b1 = lp[1];
      float s = acc[r];
      s = fdot2f(pk2(a0[0],a0[1]), wf[0], s);
      s = fdot2f(pk2(a0[2],a0[3]), wf[1], s);
      s = fdot2f(pk2(a0[4],a0[5]), wf[2], s);
      s = fdot2f(pk2(a0[6],a0[7]), wf[3], s);
      s = fdot2f(pk2(a1[0],a1[1]), wf[4], s);
      s = fdot2f(pk2(a1[2],a1[3]), wf[5], s);
      s = fdot2f(pk2(a1[4],a1[5]), wf[6], s);
      s = fdot2f(pk2(a1[6],a1[7]), wf[7], s);
      s = fdot2f(pk2(b0[0],b0[1]), wl[0], s);
      s = fdot2f(pk2(b0[2],b0[3]), wl[1], s);
      s = fdot2f(pk2(b0[4],b0[5]), wl[2], s);
      s = fdot2f(pk2(b0[6],b0[7]), wl[3], s);
      s = fdot2f(pk2(b1[0],b1[1]), wl[4], s);
      s = fdot2f(pk2(b1[2],b1[3]), wl[5], s);
      s = fdot2f(pk2(b1[4],b1[5]), wl[6], s);
      s = fdot2f(pk2(b1[6],b1[7]), wl[7], s);
      acc[r] = s;
    }
  }
  const float* lb = lqB + c*16;
  float lbv[16];
  #pragma unroll
  for (int i = 0; i < 16; i += 4) {
    float4 t = *(const float4*)(lb + i);
    lbv[i] = t.x; lbv[i+1] = t.y; lbv[i+2] = t.z; lbv[i+3] = t.w;
  }
  #pragma unroll
  for (int r = 0; r < 16; ++r) {
    float dl = 0.f;
    #pragma unroll
    for (int kk = 0; kk < 16; ++kk) dl += t16[(rb+r)*16 + kk] * lbv[kk];
    acc[r] += dl * LORA_SCALE;
  }
  const int h = c >> 4, d = c & 15;
  #pragma unroll
  for (int r = 0; r < 16; ++r) {
    const int grow = row0 + rb + r;
    const int b = grow / 200, m = grow % 200;
    qF[(((size_t)b*8 + h)*200 + m)*16 + d] = (f16)acc[r];
  }
}

// ---------------- k3: per-(b,h) MFMA flash attention, two-pass fixed-max ----------------
// grid (64,8,2): z splits the 13 m-tiles {0..6}/{7..12}; 512 thr (8 waves),
// ONE m-tile per wave (balanced, halves serial path). Dual O-chains for MFMA ILP.
// Pass1: unmasked row max (mask<=0 => upper bound; p<=1 f16-safe), lane-local.
// Pass2: recompute QK, p=exp2(s*c + (mask-M)*l2e), direct PV accumulate.
#define KSTR 20
#define VSTR 1004
__global__ __launch_bounds__(512) void k3_attn(const f16* __restrict__ Kp,
    const f16* __restrict__ Vt, const f16* __restrict__ qF,
    const float* __restrict__ mask, f16* __restrict__ ocF)
{
  extern __shared__ char smem[];
  f16* Kl = (f16*)smem;                     // [1008][KSTR] : 40320 B
  f16* Vl = (f16*)(smem + 1008*KSTR*2);     // [16][VSTR]   : 32128 B
  const int tid = threadIdx.x;
  const int lane = tid & 63, w = tid >> 6;
  const int b = blockIdx.x, h = blockIdx.y, z = blockIdx.z;
  const int bh = b*8 + h;
  for (int n = tid; n < 1008; n += 512) {
    f16x4 zf = {};
    f16x4 v0 = zf, v1 = zf, v2 = zf, v3 = zf;
    if (n < 1000) {
      const f16x4* src = (const f16x4*)(Kp + (size_t)bh*16000 + n*16);
      v0 = src[0]; v1 = src[1]; v2 = src[2]; v3 = src[3];
    }
    f16* dst = Kl + n*KSTR;
    *(f16x4*)(dst)    = v0;
    *(f16x4*)(dst+4)  = v1;
    *(f16x4*)(dst+8)  = v2;
    *(f16x4*)(dst+12) = v3;
  }
  for (int i = tid; i < 2000; i += 512) {
    const int d = i / 125, c8 = i - d*125;
    const f16x4* src = (const f16x4*)(Vt + (size_t)bh*16000 + d*1000 + c8*8);
    f16* dst = Vl + d*VSTR + c8*8;
    *(f16x4*)(dst)   = src[0];
    *(f16x4*)(dst+4) = src[1];
  }
  if (tid < 64) { const int d = tid >> 2, e = 1000 + (tid & 3); Vl[d*VSTR + e] = (f16)0; }
  __syncthreads();

  const int mt = z*7 + w;                                // z=0: w<7 -> 0..6; z=1: w<6 -> 7..12
  if (w >= 7 - z) return;
  const int col = lane & 15, g = lane >> 4, g4 = g*4;
  const f32x4 zero = {0.f, 0.f, 0.f, 0.f};
  const int m0 = mt*16;
  const int mq = min(m0 + col, 199);
  const f16x4 qf = *(const f16x4*)(qF + (size_t)bh*3200 + mq*16 + g4);
  const float* mp = mask + ((size_t)b*200 + mq)*1000;

  // ---- pass 1: raw-score row max, dual accumulators, no cross-lane until end ----
  float mxa = -1e30f, mxb = -1e30f;
  #pragma unroll 2
  for (int t2 = 0; t2 < 31; ++t2) {
    const int t = t2*2;
    const f16x4 kf0 = *(const f16x4*)(Kl + (t*16+col)*KSTR + g4);
    const f16x4 kf1 = *(const f16x4*)(Kl + ((t+1)*16+col)*KSTR + g4);
    f32x4 sa = mfma16(kf0, qf, zero);
    f32x4 sb = mfma16(kf1, qf, zero);
    mxa = fmaxf(mxa, fmaxf(fmaxf(sa[0], sa[1]), fmaxf(sa[2], sa[3])));
    mxb = fmaxf(mxb, fmaxf(fmaxf(sb[0], sb[1]), fmaxf(sb[2], sb[3])));
  }
  { // t = 62: n = 992+g4+r, valid only for g<2
    const f16x4 kf = *(const f16x4*)(Kl + (62*16+col)*KSTR + g4);
    f32x4 s4 = mfma16(kf, qf, zero);
    if (g < 2) mxa = fmaxf(mxa, fmaxf(fmaxf(s4[0], s4[1]), fmaxf(s4[2], s4[3])));
  }
  float mx = fmaxf(mxa, mxb);
  mx = fmaxf(mx, __shfl_xor(mx, 16, 64));
  mx = fmaxf(mx, __shfl_xor(mx, 32, 64));
  const float mb = -(mx * 0.25f) * 1.44269504f;          // exp2 bias

  // ---- pass 2: dual O/l chains; p = exp2(s*0.25*l2e + (mask - M)*l2e) ----
  f32x4 Oa = zero, Ob = zero;
  float l0 = 0.f, l1 = 0.f, l2 = 0.f, l3 = 0.f;
  #pragma unroll 2
  for (int t2 = 0; t2 < 31; ++t2) {
    const int t = t2*2;
    {
      const int n0 = t*16 + g4;
      const f16x4 kf = *(const f16x4*)(Kl + (t*16+col)*KSTR + g4);
      f32x4 s4 = mfma16(kf, qf, zero);
      const float4 mk = *(const float4*)(mp + n0);
      const float p0 = exp2f(fmaf(s4[0], 0.360673760f, fmaf(mk.x, 1.44269504f, mb)));
      const float p1 = exp2f(fmaf(s4[1], 0.360673760f, fmaf(mk.y, 1.44269504f, mb)));
      const float p2 = exp2f(fmaf(s4[2], 0.360673760f, fmaf(mk.z, 1.44269504f, mb)));
      const float p3 = exp2f(fmaf(s4[3], 0.360673760f, fmaf(mk.w, 1.44269504f, mb)));
      l0 += p0; l1 += p1; l2 += p2; l3 += p3;
      const f16x4 pf = __builtin_shufflevector(pkrtz(p0, p1), pkrtz(p2, p3), 0, 1, 2, 3);
      const f16x4 vf = *(const f16x4*)(Vl + col*VSTR + n0);
      Oa = mfma16(vf, pf, Oa);
    }
    {
      const int n0 = (t+1)*16 + g4;
      const f16x4 kf = *(const f16x4*)(Kl + ((t+1)*16+col)*KSTR + g4);
      f32x4 s4 = mfma16(kf, qf, zero);
      const float4 mk = *(const float4*)(mp + n0);
      const float p0 = exp2f(fmaf(s4[0], 0.360673760f, fmaf(mk.x, 1.44269504f, mb)));
      const float p1 = exp2f(fmaf(s4[1], 0.360673760f, fmaf(mk.y, 1.44269504f, mb)));
      const float p2 = exp2f(fmaf(s4[2], 0.360673760f, fmaf(mk.z, 1.44269504f, mb)));
      const float p3 = exp2f(fmaf(s4[3], 0.360673760f, fmaf(mk.w, 1.44269504f, mb)));
      l0 += p0; l1 += p1; l2 += p2; l3 += p3;
      const f16x4 pf = __builtin_shufflevector(pkrtz(p0, p1), pkrtz(p2, p3), 0, 1, 2, 3);
      const f16x4 vf = *(const f16x4*)(Vl + col*VSTR + n0);
      Ob = mfma16(vf, pf, Ob);
    }
  }
  { // t = 62 tail: only g<2 lanes carry real scores
    const int n0 = 62*16 + g4;
    const f16x4 kf = *(const f16x4*)(Kl + (62*16+col)*KSTR + g4);
    f32x4 s4 = mfma16(kf, qf, zero);
    float p0 = 0.f, p1 = 0.f, p2 = 0.f, p3 = 0.f;
    if (g < 2) {
      const float4 mk = *(const float4*)(mp + n0);
      p0 = exp2f(fmaf(s4[0], 0.360673760f, fmaf(mk.x, 1.44269504f, mb)));
      p1 = exp2f(fmaf(s4[1], 0.360673760f, fmaf(mk.y, 1.44269504f, mb)));
      p2 = exp2f(fmaf(s4[2], 0.360673760f, fmaf(mk.z, 1.44269504f, mb)));
      p3 = exp2f(fmaf(s4[3], 0.360673760f, fmaf(mk.w, 1.44269504f, mb)));
      l0 += p0; l1 += p1; l2 += p2; l3 += p3;
    }
    const f16x4 pf = __builtin_shufflevector(pkrtz(p0, p1), pkrtz(p2, p3), 0, 1, 2, 3);
    const f16x4 vf = *(const f16x4*)(Vl + col*VSTR + ((g < 2) ? n0 : 0));
    Oa = mfma16(vf, pf, Oa);
  }
  f32x4 O = Oa + Ob;
  float lrun = (l0 + l1) + (l2 + l3);
  lrun += __shfl_xor(lrun, 16, 64);
  lrun += __shfl_xor(lrun, 32, 64);
  const float inv = 1.f / lrun;
  if (m0 + col < 200) {
    const f16x2 o01 = pkrtz(O[0]*inv, O[1]*inv);
    const f16x2 o23 = pkrtz(O[2]*inv, O[3]*inv);
    const f16x4 ov = __builtin_shufflevector(o01, o23, 0, 1, 2, 3);
    *(f16x4*)(ocF + ((size_t)b*200 + m0 + col)*128 + h*16 + g4) = ov;
  }
}

// ---------------- k4: mh = oc@Wc^T + bc + LoRA ----------------
__global__ __launch_bounds__(256) void k4_comb(const f16* __restrict__ ocF,
    const float* __restrict__ Wc, const float* __restrict__ bc,
    const float* __restrict__ lcA, const float* __restrict__ lcB,
    f16* __restrict__ mhF)
{
  __shared__ f16 ocr[32*128];
  __shared__ float t16[32*16];
  const int tid = threadIdx.x;
  const int row0 = blockIdx.x * 32;
  {
    const f16x8* s1 = (const f16x8*)(ocF + (size_t)row0*128);
    f16x8* d1 = (f16x8*)ocr;
    for (int i = tid; i < 512; i += 256) d1[i] = s1[i];
  }
  __syncthreads();
  for (int idx = tid; idx < 32*16; idx += 256) {
    const int r = idx >> 4, kk = idx & 15;
    const f16x8* lrow = (const f16x8*)(ocr + r*128);
    const float* arow = lcA + kk*128;
    float s = 0.f;
    #pragma unroll
    for (int cc = 0; cc < 16; ++cc) {
      f16x8 a = lrow[cc];
      float4 wa = *(const float4*)(arow + cc*8);
      float4 wb = *(const float4*)(arow + cc*8 + 4);
      s = fdot2f(pk2(a[0],a[1]), pkrtz(wa.x,wa.y), s);
      s = fdot2f(pk2(a[2],a[3]), pkrtz(wa.z,wa.w), s);
      s = fdot2f(pk2(a[4],a[5]), pkrtz(wb.x,wb.y), s);
      s = fdot2f(pk2(a[6],a[7]), pkrtz(wb.z,wb.w), s);
    }
    t16[idx] = s;
  }
  __syncthreads();
  const int c = tid & 127, rg = tid >> 7, rb = rg*16;
  float acc[16];
  const float bias = bc[c];
  #pragma unroll
  for (int r = 0; r < 16; ++r) acc[r] = bias;
  const float* wrow = Wc + c*128;
  for (int c0 = 0; c0 < 128; c0 += 16) {
    float4 w0 = *(const float4*)(wrow + c0);
    float4 w1 = *(const float4*)(wrow + c0 + 4);
    float4 w2 = *(const float4*)(wrow + c0 + 8);
    float4 w3 = *(const float4*)(wrow + c0 + 12);
    f16x2 wv[8] = { pkrtz(w0.x,w0.y), pkrtz(w0.z,w0.w), pkrtz(w1.x,w1.y), pkrtz(w1.z,w1.w),
                    pkrtz(w2.x,w2.y), pkrtz(w2.z,w2.w), pkrtz(w3.x,w3.y), pkrtz(w3.z,w3.w) };
    #pragma unroll
    for (int r = 0; r < 16; ++r) {
      const f16x8* op = (const f16x8*)(ocr + (rb+r)*128 + c0);
      f16x8 a0 = op[0], a1 = op[1];
      float s = acc[r];
      s = fdot2f(pk2(a0[0],a0[1]), wv[0], s);
      s = fdot2f(pk2(a0[2],a0[3]), wv[1], s);
      s = fdot2f(pk2(a0[4],a0[5]), wv[2], s);
      s = fdot2f(pk2(a0[6],a0[7]), wv[3], s);
      s = fdot2f(pk2(a1[0],a1[1]), wv[4], s);
      s = fdot2f(pk2(a1[2],a1[3]), wv[5], s);
      s = fdot2f(pk2(a1[4],a1[5]), wv[6], s);
      s = fdot2f(pk2(a1[6],a1[7]), wv[7], s);
      acc[r] = s;
    }
  }
  const float* lb = lcB + c*16;
  float lbv[16];
  #pragma unroll
  for (int i = 0; i < 16; i += 4) {
    float4 t = *(const float4*)(lb + i);
    lbv[i] = t.x; lbv[i+1] = t.y; lbv[i+2] = t.z; lbv[i+3] = t.w;
  }
  #pragma unroll
  for (int r = 0; r < 16; ++r) {
    float dl = 0.f;
    #pragma unroll
    for (int kk = 0; kk < 16; ++kk) dl += t16[(rb+r)*16 + kk] * lbv[kk];
    acc[r] += dl * LORA_SCALE;
  }
  #pragma unroll
  for (int r = 0; r < 16; ++r) {
    mhF[(size_t)(row0 + rb + r)*128 + c] = (f16)acc[r];
  }
}

// ---------------- k5: MFMA probs = softmax(10*tanh(mh@nodes^T/sqrt(128)) + mask) ----------------
// grid (64, 13), 512 thr (8 waves). Block = (b, 16 m-rows); wave covers n-tiles w+8i.
__global__ __launch_bounds__(512) void k5_final(const f16* __restrict__ mhF,
    const f16* __restrict__ nodesF, const float* __restrict__ mask,
    float* __restrict__ out)
{
  __shared__ float sums[8][16];
  const int tid = threadIdx.x, lane = tid & 63, w = tid >> 6;
  const int b = blockIdx.x, mt = blockIdx.y;
  const int col = lane & 15, g = lane >> 4, g4 = g*4;
  const int m = mt*16 + col;
  const int mq = min(m, 199);
  f16x4 bf[8];
  const f16* mb = mhF + (size_t)(b*200 + mq)*128;
  #pragma unroll
  for (int kk = 0; kk < 8; ++kk) bf[kk] = *(const f16x4*)(mb + kk*16 + g4);
  const float* mrow = mask + (size_t)(b*200 + mq)*1000;
  const f16* nb = nodesF + (size_t)b*128000;
  float p[8][4];
  float lsum = 0.f;
  #pragma unroll
  for (int i = 0; i < 8; ++i) {
    const int t = w + i*8;
    if (t < 63) {
      const int nr = min(t*16 + col, 999);
      const f16* na = nb + nr*128;
      f32x4 acc = {0.f, 0.f, 0.f, 0.f};
      #pragma unroll
      for (int kk = 0; kk < 8; ++kk) {
        f16x4 af = *(const f16x4*)(na + kk*16 + g4);
        acc = mfma16(af, bf[kk], acc);
      }
      const int n0 = t*16 + g4;
      float mkv[4] = {0.f, 0.f, 0.f, 0.f};
      if (n0 + 3 < 1000) {
        float4 mk = *(const float4*)(mrow + n0);
        mkv[0] = mk.x; mkv[1] = mk.y; mkv[2] = mk.z; mkv[3] = mk.w;
      }
      #pragma unroll
      for (int r = 0; r < 4; ++r) {
        float x = acc[r] * 0.08838834764831845f;            // /sqrt(128)
        float e = exp2f(x * 2.8853900817779268f);           // e^{2x}
        float th = 1.f - 2.f/(e + 1.f);                     // tanh(x)
        float scv = 10.f*th + mkv[r];
        float pv = exp2f(scv * 1.44269504f);                // no-max softmax: sc <= 10
        pv = (n0 + r < 1000) ? pv : 0.f;
        p[i][r] = pv;
        lsum += pv;
      }
    } else {
      p[i][0] = p[i][1] = p[i][2] = p[i][3] = 0.f;
    }
  }
  lsum += __shfl_xor(lsum, 16, 64);
  lsum += __shfl_xor(lsum, 32, 64);
  if (lane < 16) sums[w][lane] = lsum;
  __syncthreads();
  float S = 0.f;
  #pragma unroll
  for (int ww = 0; ww < 8; ++ww) S += sums[ww][col];
  const float inv = 1.f / S;
  if (m < 200) {
    float* ob = out + (size_t)(b*200 + m)*1000;
    #pragma unroll
    for (int i = 0; i < 8; ++i) {
      const int t = w + i*8;
      if (t < 63) {
        const int n0 = t*16 + g4;
        if (n0 + 3 < 1000) {
          float4 o;
          o.x = p[i][0]*inv; o.y = p[i][1]*inv; o.z = p[i][2]*inv; o.w = p[i][3]*inv;
          *(float4*)(ob + n0) = o;
        } else {
          #pragma unroll
          for (int r = 0; r < 4; ++r) if (n0 + r < 1000) ob[n0+r] = p[i][r]*inv;
        }
      }
    }
  }
}

extern "C" void kernel_launch(void* const* d_in, const int* in_sizes, int n_in,
                              void* d_out, int out_size, void* d_ws, size_t ws_size,
                              hipStream_t stream)
{
  (void)in_sizes; (void)n_in; (void)out_size; (void)ws_size;
  const float* nodes = (const float*)d_in[0];
  const float* q1    = (const float*)d_in[1];
  const float* last  = (const float*)d_in[2];
  const float* mask  = (const float*)d_in[3];
  const float* Wqf   = (const float*)d_in[4];
  const float* Wql   = (const float*)d_in[5];
  const float* Wk    = (const float*)d_in[6];
  const float* Wv    = (const float*)d_in[7];
  const float* Wc    = (const float*)d_in[8];
  const float* bc    = (const float*)d_in[9];
  const float* lqA   = (const float*)d_in[10];
  const float* lqB   = (const float*)d_in[11];
  const float* lcA   = (const float*)d_in[12];
  const float* lcB   = (const float*)d_in[13];
  float* out = (float*)d_out;
  char* ws = (char*)d_ws;
  // ws layout (bytes):
  f16* nodesF = (f16*)(ws);               // 16,384,000
  f16* Kp     = (f16*)(ws + 16384000);    // 16,384,000
  f16* Vt     = (f16*)(ws + 32768000);    // 16,384,000
  f16* qF     = (f16*)(ws + 49152000);    //  3,276,800
  f16* ocF    = (f16*)(ws + 52428800);    //  3,276,800
  f16* mhF    = (f16*)(ws + 55705600);    //  3,276,800
  f16* WkvF   = (f16*)(ws + 58982400);    //     65,536  (end 59,047,936)

  k0_wconv<<<dim3(32), 256, 0, stream>>>(Wk, Wv, WkvF);
  k1_proj<<<dim3(16, 64), 256, 0, stream>>>(nodes, WkvF, nodesF, Kp, Vt);
  k2_q<<<dim3(400), 256, 0, stream>>>(q1, last, Wqf, Wql, lqA, lqB, qF);
  k3_attn<<<dim3(64, 8, 2), 512, 72448, stream>>>(Kp, Vt, qF, mask, ocF);
  k4_comb<<<dim3(400), 256, 0, stream>>>(ocF, Wc, bc, lcA, lcB, mhF);
  k5_final<<<dim3(64, 13), 512, 0, stream>>>(mhF, nodesF, mask, out);
}

// Round 7
// 265.837 us; speedup vs baseline: 1.6909x; 1.0576x over previous
//
#include <hip/hip_runtime.h>
#include <hip/hip_bf16.h>

// TSP decoder forward: B=64, POMO=200, N=1000, EMB=128, H=8, D=16.
// k0 W->f16 | k1 MFMA K/V proj + nodes->f16 | k1b kmax | k2 q (+LoRA) | k2b qnorm |
// k3 MFMA flash attention (single-pass, Cauchy-Schwarz max bound, dual m-tile/wave) |
// k4 combine (+LoRA) | k5 MFMA mh@nodes^T + tanh-softmax.

typedef _Float16 f16;
typedef _Float16 f16x2 __attribute__((ext_vector_type(2)));
typedef _Float16 f16x4 __attribute__((ext_vector_type(4)));
typedef _Float16 f16x8 __attribute__((ext_vector_type(8)));
typedef __fp16  h4   __attribute__((ext_vector_type(4)));
typedef float   f32x4 __attribute__((ext_vector_type(4)));

#define LORA_SCALE 1.0f

__device__ __forceinline__ f16x2 pk2(f16 a, f16 b){ f16x2 r; r[0]=a; r[1]=b; return r; }

#if __has_builtin(__builtin_amdgcn_fdot2)
__device__ __forceinline__ float fdot2f(f16x2 a, f16x2 b, float c){ return __builtin_amdgcn_fdot2(a, b, c, false); }
#else
__device__ __forceinline__ float fdot2f(f16x2 a, f16x2 b, float c){ return c + (float)a[0]*(float)b[0] + (float)a[1]*(float)b[1]; }
#endif

#if __has_builtin(__builtin_amdgcn_cvt_pkrtz)
__device__ __forceinline__ f16x2 pkrtz(float a, float b){
  return __builtin_bit_cast(f16x2, __builtin_amdgcn_cvt_pkrtz(a, b));
}
#else
__device__ __forceinline__ f16x2 pkrtz(float a, float b){ return pk2((f16)a, (f16)b); }
#endif

// D[i][j] = sum_k A[i][k]*B[k][j] + C  via v_mfma_f32_16x16x16_f16.
// A: lane holds row i=(l&15), k=4*(l>>4)+j. B: lane holds col j=(l&15), k=4*(l>>4)+j.
// D: lane holds col j=(l&15), row i=4*(l>>4)+reg.   (validated end-to-end in k3/k5)
__device__ __forceinline__ f32x4 mfma16(f16x4 a, f16x4 b, f32x4 c){
  return __builtin_amdgcn_mfma_f32_16x16x16f16(
      __builtin_bit_cast(h4, a), __builtin_bit_cast(h4, b), c, 0, 0, 0);
}

__device__ __forceinline__ float sumsq16(const f16* p){
  const f16x8* v = (const f16x8*)p;
  f16x8 a = v[0], b = v[1];
  float s = 0.f;
  s = fdot2f(pk2(a[0],a[1]), pk2(a[0],a[1]), s);
  s = fdot2f(pk2(a[2],a[3]), pk2(a[2],a[3]), s);
  s = fdot2f(pk2(a[4],a[5]), pk2(a[4],a[5]), s);
  s = fdot2f(pk2(a[6],a[7]), pk2(a[6],a[7]), s);
  s = fdot2f(pk2(b[0],b[1]), pk2(b[0],b[1]), s);
  s = fdot2f(pk2(b[2],b[3]), pk2(b[2],b[3]), s);
  s = fdot2f(pk2(b[4],b[5]), pk2(b[4],b[5]), s);
  s = fdot2f(pk2(b[6],b[7]), pk2(b[6],b[7]), s);
  return s;
}

// ---------------- k0: Wk|Wv -> f16 [256][128] ----------------
__global__ __launch_bounds__(256) void k0_wconv(const float* __restrict__ Wk,
    const float* __restrict__ Wv, f16* __restrict__ WkvF)
{
  const int i = blockIdx.x*256 + threadIdx.x;           // 0..8191, one f32x4 each
  const float4 v = (i < 4096) ? ((const float4*)Wk)[i] : ((const float4*)Wv)[i-4096];
  f16x2 lo = pkrtz(v.x,v.y), hi = pkrtz(v.z,v.w);
  f16x4 o = __builtin_shufflevector(lo, hi, 0, 1, 2, 3);
  *(f16x4*)(WkvF + i*4) = o;
}

// ---------------- k1: MFMA K/V projection + nodes -> f16 ----------------
// grid (16, 64), 256 thr (4 waves), 64 node rows per block.
// Kp: [bh][n(1000)][16] ; Vt: [bh][d(16)][n(1000)]
#define NSTR 132
__global__ __launch_bounds__(256) void k1_proj(const float* __restrict__ nodes,
    const f16* __restrict__ WkvF,
    f16* __restrict__ nodesF, f16* __restrict__ Kp, f16* __restrict__ Vt)
{
  __shared__ f16 lds[64*NSTR];
  const int tid = threadIdx.x, lane = tid & 63, w = tid >> 6;
  const int b = blockIdx.y;
  const int n0 = blockIdx.x * 64;
  const int rows = min(64, 1000 - n0);                  // 64 or 40
  for (int i = tid; i < rows*32; i += 256) {            // 32 f32x4 per row
    const int r = i >> 5, cq = i & 31;
    float4 v = ((const float4*)(nodes + ((size_t)b*1000 + n0 + r)*128))[cq];
    f16x2 lo = pkrtz(v.x,v.y), hi = pkrtz(v.z,v.w);
    f16x4 o = __builtin_shufflevector(lo, hi, 0, 1, 2, 3);
    *(f16x4*)(lds + r*NSTR + cq*4) = o;
    *(f16x4*)(nodesF + ((size_t)b*1000 + n0 + r)*128 + cq*4) = o;
  }
  __syncthreads();
  const int col = lane & 15, g = lane >> 4, g4 = g*4;
  const int mloc = w*16 + col;                          // wave-local node row (as frag row/col)
  f16x4 nf[8];
  #pragma unroll
  for (int kk = 0; kk < 8; ++kk)
    nf[kk] = *(const f16x4*)(lds + min(mloc, rows-1)*NSTR + kk*16 + g4);
  for (int ct = 0; ct < 16; ++ct) {
    f16x4 wf[8];
    const f16* wbase = WkvF + (ct*16 + col)*128;
    #pragma unroll
    for (int kk = 0; kk < 8; ++kk) wf[kk] = *(const f16x4*)(wbase + kk*16 + g4);
    f32x4 acc = {0.f, 0.f, 0.f, 0.f};
    if (ct < 8) {                                       // K-head ct: D[c][m]
      #pragma unroll
      for (int kk = 0; kk < 8; ++kk) acc = mfma16(wf[kk], nf[kk], acc);
      if (mloc < rows) {
        const int nn = n0 + mloc;
        f16x4 ov = __builtin_shufflevector(pk2((f16)acc[0],(f16)acc[1]),
                                           pk2((f16)acc[2],(f16)acc[3]), 0,1,2,3);
        *(f16x4*)(Kp + ((size_t)(b*8+ct)*1000 + nn)*16 + g4) = ov;
      }
    } else {                                            // V-head ct-8: D[m][c]
      #pragma unroll
      for (int kk = 0; kk < 8; ++kk) acc = mfma16(nf[kk], wf[kk], acc);
      if (w*16 + g4 + 3 < rows) {
        const int nbase = n0 + w*16 + g4;
        f16x4 ov = __builtin_shufflevector(pk2((f16)acc[0],(f16)acc[1]),
                                           pk2((f16)acc[2],(f16)acc[3]), 0,1,2,3);
        *(f16x4*)(Vt + ((size_t)(b*8+(ct-8))*16 + col)*1000 + nbase) = ov;
      }
    }
  }
}

// ---------------- k1b: kmax[bh] = max_n ||Kp[bh][n]|| ----------------
// grid 512, 256 thr. Reads the f16 K actually used by the MFMA -> rigorous bound.
__global__ __launch_bounds__(256) void k1b_kmax(const f16* __restrict__ Kp,
    float* __restrict__ kmaxA)
{
  __shared__ float wmax[4];
  const int bh = blockIdx.x, tid = threadIdx.x, lane = tid & 63, w = tid >> 6;
  const f16* base = Kp + (size_t)bh*16000;
  float mx = 0.f;
  for (int n = tid; n < 1000; n += 256) mx = fmaxf(mx, sumsq16(base + n*16));
  #pragma unroll
  for (int off = 32; off; off >>= 1) mx = fmaxf(mx, __shfl_xor(mx, off, 64));
  if (lane == 0) wmax[w] = mx;
  __syncthreads();
  if (tid == 0) {
    float m = fmaxf(fmaxf(wmax[0], wmax[1]), fmaxf(wmax[2], wmax[3]));
    kmaxA[bh] = sqrtf(m);
  }
}

// ---------------- k2: q = q1@Wqf^T + last@Wql^T + LoRA ----------------
// grid 400, 256 thr, 32 rows/block. qF layout: [bh][m(200)][16]
__global__ __launch_bounds__(256) void k2_q(const float* __restrict__ q1,
    const float* __restrict__ last, const float* __restrict__ Wqf,
    const float* __restrict__ Wql, const float* __restrict__ lqA,
    const float* __restrict__ lqB, f16* __restrict__ qF)
{
  __shared__ f16 q1r[32*128];
  __shared__ f16 lar[32*128];
  __shared__ float t16[32*16];
  const int tid = threadIdx.x;
  const int row0 = blockIdx.x * 32;
  {
    const float4* s1 = (const float4*)(q1 + (size_t)row0*128);
    const float4* s2 = (const float4*)(last + (size_t)row0*128);
    f16x2* d1 = (f16x2*)q1r; f16x2* d2 = (f16x2*)lar;
    for (int i = tid; i < 32*32; i += 256) {
      float4 v = s1[i];
      d1[2*i] = pkrtz(v.x,v.y); d1[2*i+1] = pkrtz(v.z,v.w);
      float4 u = s2[i];
      d2[2*i] = pkrtz(u.x,u.y); d2[2*i+1] = pkrtz(u.z,u.w);
    }
  }
  __syncthreads();
  for (int idx = tid; idx < 32*16; idx += 256) {
    const int r = idx >> 4, kk = idx & 15;
    const f16x8* lrow = (const f16x8*)(lar + r*128);
    const float* arow = lqA + kk*128;
    float s = 0.f;
    #pragma unroll
    for (int cc = 0; cc < 16; ++cc) {
      f16x8 a = lrow[cc];
      float4 wa = *(const float4*)(arow + cc*8);
      float4 wb = *(const float4*)(arow + cc*8 + 4);
      s = fdot2f(pk2(a[0],a[1]), pkrtz(wa.x,wa.y), s);
      s = fdot2f(pk2(a[2],a[3]), pkrtz(wa.z,wa.w), s);
      s = fdot2f(pk2(a[4],a[5]), pkrtz(wb.x,wb.y), s);
      s = fdot2f(pk2(a[6],a[7]), pkrtz(wb.z,wb.w), s);
    }
    t16[idx] = s;
  }
  __syncthreads();
  const int c = tid & 127, rg = tid >> 7, rb = rg*16;
  float acc[16];
  #pragma unroll
  for (int r = 0; r < 16; ++r) acc[r] = 0.f;
  const float* wfr = Wqf + c*128;
  const float* wlr = Wql + c*128;
  for (int c0 = 0; c0 < 128; c0 += 16) {
    float4 f0 = *(const float4*)(wfr + c0);
    float4 f1 = *(const float4*)(wfr + c0 + 4);
    float4 f2 = *(const float4*)(wfr + c0 + 8);
    float4 f3 = *(const float4*)(wfr + c0 + 12);
    f16x2 wf[8] = { pkrtz(f0.x,f0.y), pkrtz(f0.z,f0.w), pkrtz(f1.x,f1.y), pkrtz(f1.z,f1.w),
                    pkrtz(f2.x,f2.y), pkrtz(f2.z,f2.w), pkrtz(f3.x,f3.y), pkrtz(f3.z,f3.w) };
    float4 g0 = *(const float4*)(wlr + c0);
    float4 g1 = *(const float4*)(wlr + c0 + 4);
    float4 g2 = *(const float4*)(wlr + c0 + 8);
    float4 g3 = *(const float4*)(wlr + c0 + 12);
    f16x2 wl[8] = { pkrtz(g0.x,g0.y), pkrtz(g0.z,g0.w), pkrtz(g1.x,g1.y), pkrtz(g1.z,g1.w),
                    pkrtz(g2.x,g2.y), pkrtz(g2.z,g2.w), pkrtz(g3.x,g3.y), pkrtz(g3.z,g3.w) };
    #pragma unroll
    for (int r = 0; r < 16; ++r) {
      const f16x8* qp = (const f16x8*)(q1r + (rb+r)*128 + c0);
      const f16x8* lp = (const f16x8*)(lar + (rb+r)*128 + c0);
      f16x8 a0 = qp[0], a1 = qp[1], b0 = lp[0], b1 = lp[1];
      float s = acc[r];
      s = fdot2f(pk2(a0[0],a0[1]), wf[0], s);
      s = fdot2f(pk2(a0[2],a0[3]), wf[1], s);
      s = fdot2f(pk2(a0[4],a0[5]), wf[2], s);
      s = fdot2f(pk2(a0[6],a0[7]), wf[3], s);
      s = fdot2f(pk2(a1[0],a1[1]), wf[4], s);
      s = fdot2f(pk2(a1[2],a1[3]), wf[5], s);
      s = fdot2f(pk2(a1[4],a1[5]), wf[6], s);
      s = fdot2f(pk2(a1[6],a1[7]), wf[7], s);
      s = fdot2f(pk2(b0[0],b0[1]), wl[0], s);
      s = fdot2f(pk2(b0[2],b0[3]), wl[1], s);
      s = fdot2f(pk2(b0[4],b0[5]), wl[2], s);
      s = fdot2f(pk2(b0[6],b0[7]), wl[3], s);
      s = fdot2f(pk2(b1[0],b1[1]), wl[4], s);
      s = fdot2f(pk2(b1[2],b1[3]), wl[5], s);
      s = fdot2f(pk2(b1[4],b1[5]), wl[6], s);
      s = fdot2f(pk2(b1[6],b1[7]), wl[7], s);
      acc[r] = s;
    }
  }
  const float* lb = lqB + c*16;
  float lbv[16];
  #pragma unroll
  for (int i = 0; i < 16; i += 4) {
    float4 t = *(const float4*)(lb + i);
    lbv[i] = t.x; lbv[i+1] = t.y; lbv[i+2] = t.z; lbv[i+3] = t.w;
  }
  #pragma unroll
  for (int r = 0; r < 16; ++r) {
    float dl = 0.f;
    #pragma unroll
    for (int kk = 0; kk < 16; ++kk) dl += t16[(rb+r)*16 + kk] * lbv[kk];
    acc[r] += dl * LORA_SCALE;
  }
  const int h = c >> 4, d = c & 15;
  #pragma unroll
  for (int r = 0; r < 16; ++r) {
    const int grow = row0 + rb + r;
    const int b = grow / 200, m = grow % 200;
    qF[(((size_t)b*8 + h)*200 + m)*16 + d] = (f16)acc[r];
  }
}

// ---------------- k2b: qn[bh][m] = ||qF[bh][m]|| ----------------
// grid 400, 256 thr: one thread per (bh,m).
__global__ __launch_bounds__(256) void k2b_qnorm(const f16* __restrict__ qF,
    float* __restrict__ qnA)
{
  const int idx = blockIdx.x*256 + threadIdx.x;         // 0..102399
  qnA[idx] = sqrtf(sumsq16(qF + (size_t)idx*16));
}

// ---------------- k3: per-(b,h) MFMA attention, single-pass with norm bound ----------------
// grid (64,8), 512 thr (8 waves). Wave w handles m-tiles (2w, 2w+1) fused in one loop
// (kf/vf LDS reads shared; two independent O-chains). M bound = ||q_m||*max||k||/4 >=
// row max (Cauchy-Schwarz; mask<=0) -> p<=1 f16-safe, NO max pass, no cross-lane until sum.
#define KSTR 20
#define VSTR 1004
__global__ __launch_bounds__(512) void k3_attn(const f16* __restrict__ Kp,
    const f16* __restrict__ Vt, const f16* __restrict__ qF,
    const float* __restrict__ mask, const float* __restrict__ kmaxA,
    const float* __restrict__ qnA, f16* __restrict__ ocF)
{
  extern __shared__ char smem[];
  f16* Kl = (f16*)smem;                     // [1008][KSTR] : 40320 B
  f16* Vl = (f16*)(smem + 1008*KSTR*2);     // [16][VSTR]   : 32128 B
  const int tid = threadIdx.x;
  const int lane = tid & 63, w = tid >> 6;
  const int b = blockIdx.x, h = blockIdx.y;
  const int bh = b*8 + h;
  for (int n = tid; n < 1008; n += 512) {
    f16x4 zf = {};
    f16x4 v0 = zf, v1 = zf, v2 = zf, v3 = zf;
    if (n < 1000) {
      const f16x4* src = (const f16x4*)(Kp + (size_t)bh*16000 + n*16);
      v0 = src[0]; v1 = src[1]; v2 = src[2]; v3 = src[3];
    }
    f16* dst = Kl + n*KSTR;
    *(f16x4*)(dst)    = v0;
    *(f16x4*)(dst+4)  = v1;
    *(f16x4*)(dst+8)  = v2;
    *(f16x4*)(dst+12) = v3;
  }
  for (int i = tid; i < 2000; i += 512) {
    const int d = i / 125, c8 = i - d*125;
    const f16x4* src = (const f16x4*)(Vt + (size_t)bh*16000 + d*1000 + c8*8);
    f16* dst = Vl + d*VSTR + c8*8;
    *(f16x4*)(dst)   = src[0];
    *(f16x4*)(dst+4) = src[1];
  }
  if (tid < 64) { const int d = tid >> 2, e = 1000 + (tid & 3); Vl[d*VSTR + e] = (f16)0; }
  __syncthreads();

  const int col = lane & 15, g = lane >> 4, g4 = g*4;
  const f32x4 zero = {0.f, 0.f, 0.f, 0.f};
  const int tA = min(2*w, 12), tB = min(2*w + 1, 12);   // waves 6,7 duplicate tile 12 (benign)
  const int mA = tA*16, mB = tB*16;
  const int mqA = min(mA + col, 199), mqB = min(mB + col, 199);
  const f16x4 qfA = *(const f16x4*)(qF + (size_t)bh*3200 + mqA*16 + g4);
  const f16x4 qfB = *(const f16x4*)(qF + (size_t)bh*3200 + mqB*16 + g4);
  const float kmx = kmaxA[bh];
  // mb = -(kmx*qn/4)*log2(e); 0.360673760 = 0.25*1.44269504
  const float mbA = -kmx * qnA[bh*200 + mqA] * 0.360673760f;
  const float mbB = -kmx * qnA[bh*200 + mqB] * 0.360673760f;
  const float* mpA = mask + ((size_t)b*200 + mqA)*1000;
  const float* mpB = mask + ((size_t)b*200 + mqB)*1000;

  f32x4 OA = zero, OB = zero;
  float lA0=0.f, lA1=0.f, lA2=0.f, lA3=0.f;
  float lB0=0.f, lB1=0.f, lB2=0.f, lB3=0.f;
  #pragma unroll 2
  for (int t = 0; t < 62; ++t) {
    const int n0 = t*16 + g4;
    const f16x4 kf = *(const f16x4*)(Kl + (t*16+col)*KSTR + g4);
    f32x4 sA = mfma16(kf, qfA, zero);
    f32x4 sB = mfma16(kf, qfB, zero);
    const float4 mkA = *(const float4*)(mpA + n0);
    const float4 mkB = *(const float4*)(mpB + n0);
    const float pA0 = exp2f(fmaf(sA[0], 0.360673760f, fmaf(mkA.x, 1.44269504f, mbA)));
    const float pA1 = exp2f(fmaf(sA[1], 0.360673760f, fmaf(mkA.y, 1.44269504f, mbA)));
    const float pA2 = exp2f(fmaf(sA[2], 0.360673760f, fmaf(mkA.z, 1.44269504f, mbA)));
    const float pA3 = exp2f(fmaf(sA[3], 0.360673760f, fmaf(mkA.w, 1.44269504f, mbA)));
    const float pB0 = exp2f(fmaf(sB[0], 0.360673760f, fmaf(mkB.x, 1.44269504f, mbB)));
    const float pB1 = exp2f(fmaf(sB[1], 0.360673760f, fmaf(mkB.y, 1.44269504f, mbB)));
    const float pB2 = exp2f(fmaf(sB[2], 0.360673760f, fmaf(mkB.z, 1.44269504f, mbB)));
    const float pB3 = exp2f(fmaf(sB[3], 0.360673760f, fmaf(mkB.w, 1.44269504f, mbB)));
    lA0 += pA0; lA1 += pA1; lA2 += pA2; lA3 += pA3;
    lB0 += pB0; lB1 += pB1; lB2 += pB2; lB3 += pB3;
    const f16x4 pfA = __builtin_shufflevector(pkrtz(pA0,pA1), pkrtz(pA2,pA3), 0,1,2,3);
    const f16x4 pfB = __builtin_shufflevector(pkrtz(pB0,pB1), pkrtz(pB2,pB3), 0,1,2,3);
    const f16x4 vf = *(const f16x4*)(Vl + col*VSTR + n0);
    OA = mfma16(vf, pfA, OA);
    OB = mfma16(vf, pfB, OB);
  }
  { // t = 62 tail: n = 992+g4+r valid only for g<2
    const int n0 = 62*16 + g4;
    const f16x4 kf = *(const f16x4*)(Kl + (62*16+col)*KSTR + g4);
    f32x4 sA = mfma16(kf, qfA, zero);
    f32x4 sB = mfma16(kf, qfB, zero);
    float pA0=0.f,pA1=0.f,pA2=0.f,pA3=0.f, pB0=0.f,pB1=0.f,pB2=0.f,pB3=0.f;
    if (g < 2) {
      const float4 mkA = *(const float4*)(mpA + n0);
      const float4 mkB = *(const float4*)(mpB + n0);
      pA0 = exp2f(fmaf(sA[0], 0.360673760f, fmaf(mkA.x, 1.44269504f, mbA)));
      pA1 = exp2f(fmaf(sA[1], 0.360673760f, fmaf(mkA.y, 1.44269504f, mbA)));
      pA2 = exp2f(fmaf(sA[2], 0.360673760f, fmaf(mkA.z, 1.44269504f, mbA)));
      pA3 = exp2f(fmaf(sA[3], 0.360673760f, fmaf(mkA.w, 1.44269504f, mbA)));
      pB0 = exp2f(fmaf(sB[0], 0.360673760f, fmaf(mkB.x, 1.44269504f, mbB)));
      pB1 = exp2f(fmaf(sB[1], 0.360673760f, fmaf(mkB.y, 1.44269504f, mbB)));
      pB2 = exp2f(fmaf(sB[2], 0.360673760f, fmaf(mkB.z, 1.44269504f, mbB)));
      pB3 = exp2f(fmaf(sB[3], 0.360673760f, fmaf(mkB.w, 1.44269504f, mbB)));
      lA0 += pA0; lA1 += pA1; lA2 += pA2; lA3 += pA3;
      lB0 += pB0; lB1 += pB1; lB2 += pB2; lB3 += pB3;
    }
    const f16x4 pfA = __builtin_shufflevector(pkrtz(pA0,pA1), pkrtz(pA2,pA3), 0,1,2,3);
    const f16x4 pfB = __builtin_shufflevector(pkrtz(pB0,pB1), pkrtz(pB2,pB3), 0,1,2,3);
    const f16x4 vf = *(const f16x4*)(Vl + col*VSTR + ((g < 2) ? n0 : 0));
    OA = mfma16(vf, pfA, OA);
    OB = mfma16(vf, pfB, OB);
  }
  float lA = (lA0 + lA1) + (lA2 + lA3);
  float lB = (lB0 + lB1) + (lB2 + lB3);
  lA += __shfl_xor(lA, 16, 64); lA += __shfl_xor(lA, 32, 64);
  lB += __shfl_xor(lB, 16, 64); lB += __shfl_xor(lB, 32, 64);
  const float invA = 1.f / fmaxf(lA, 1e-35f);
  const float invB = 1.f / fmaxf(lB, 1e-35f);
  if (mA + col < 200) {
    const f16x4 ov = __builtin_shufflevector(pkrtz(OA[0]*invA, OA[1]*invA),
                                             pkrtz(OA[2]*invA, OA[3]*invA), 0,1,2,3);
    *(f16x4*)(ocF + ((size_t)b*200 + mA + col)*128 + h*16 + g4) = ov;
  }
  if (mB + col < 200) {
    const f16x4 ov = __builtin_shufflevector(pkrtz(OB[0]*invB, OB[1]*invB),
                                             pkrtz(OB[2]*invB, OB[3]*invB), 0,1,2,3);
    *(f16x4*)(ocF + ((size_t)b*200 + mB + col)*128 + h*16 + g4) = ov;
  }
}

// ---------------- k4: mh = oc@Wc^T + bc + LoRA ----------------
__global__ __launch_bounds__(256) void k4_comb(const f16* __restrict__ ocF,
    const float* __restrict__ Wc, const float* __restrict__ bc,
    const float* __restrict__ lcA, const float* __restrict__ lcB,
    f16* __restrict__ mhF)
{
  __shared__ f16 ocr[32*128];
  __shared__ float t16[32*16];
  const int tid = threadIdx.x;
  const int row0 = blockIdx.x * 32;
  {
    const f16x8* s1 = (const f16x8*)(ocF + (size_t)row0*128);
    f16x8* d1 = (f16x8*)ocr;
    for (int i = tid; i < 512; i += 256) d1[i] = s1[i];
  }
  __syncthreads();
  for (int idx = tid; idx < 32*16; idx += 256) {
    const int r = idx >> 4, kk = idx & 15;
    const f16x8* lrow = (const f16x8*)(ocr + r*128);
    const float* arow = lcA + kk*128;
    float s = 0.f;
    #pragma unroll
    for (int cc = 0; cc < 16; ++cc) {
      f16x8 a = lrow[cc];
      float4 wa = *(const float4*)(arow + cc*8);
      float4 wb = *(const float4*)(arow + cc*8 + 4);
      s = fdot2f(pk2(a[0],a[1]), pkrtz(wa.x,wa.y), s);
      s = fdot2f(pk2(a[2],a[3]), pkrtz(wa.z,wa.w), s);
      s = fdot2f(pk2(a[4],a[5]), pkrtz(wb.x,wb.y), s);
      s = fdot2f(pk2(a[6],a[7]), pkrtz(wb.z,wb.w), s);
    }
    t16[idx] = s;
  }
  __syncthreads();
  const int c = tid & 127, rg = tid >> 7, rb = rg*16;
  float acc[16];
  const float bias = bc[c];
  #pragma unroll
  for (int r = 0; r < 16; ++r) acc[r] = bias;
  const float* wrow = Wc + c*128;
  for (int c0 = 0; c0 < 128; c0 += 16) {
    float4 w0 = *(const float4*)(wrow + c0);
    float4 w1 = *(const float4*)(wrow + c0 + 4);
    float4 w2 = *(const float4*)(wrow + c0 + 8);
    float4 w3 = *(const float4*)(wrow + c0 + 12);
    f16x2 wv[8] = { pkrtz(w0.x,w0.y), pkrtz(w0.z,w0.w), pkrtz(w1.x,w1.y), pkrtz(w1.z,w1.w),
                    pkrtz(w2.x,w2.y), pkrtz(w2.z,w2.w), pkrtz(w3.x,w3.y), pkrtz(w3.z,w3.w) };
    #pragma unroll
    for (int r = 0; r < 16; ++r) {
      const f16x8* op = (const f16x8*)(ocr + (rb+r)*128 + c0);
      f16x8 a0 = op[0], a1 = op[1];
      float s = acc[r];
      s = fdot2f(pk2(a0[0],a0[1]), wv[0], s);
      s = fdot2f(pk2(a0[2],a0[3]), wv[1], s);
      s = fdot2f(pk2(a0[4],a0[5]), wv[2], s);
      s = fdot2f(pk2(a0[6],a0[7]), wv[3], s);
      s = fdot2f(pk2(a1[0],a1[1]), wv[4], s);
      s = fdot2f(pk2(a1[2],a1[3]), wv[5], s);
      s = fdot2f(pk2(a1[4],a1[5]), wv[6], s);
      s = fdot2f(pk2(a1[6],a1[7]), wv[7], s);
      acc[r] = s;
    }
  }
  const float* lb = lcB + c*16;
  float lbv[16];
  #pragma unroll
  for (int i = 0; i < 16; i += 4) {
    float4 t = *(const float4*)(lb + i);
    lbv[i] = t.x; lbv[i+1] = t.y; lbv[i+2] = t.z; lbv[i+3] = t.w;
  }
  #pragma unroll
  for (int r = 0; r < 16; ++r) {
    float dl = 0.f;
    #pragma unroll
    for (int kk = 0; kk < 16; ++kk) dl += t16[(rb+r)*16 + kk] * lbv[kk];
    acc[r] += dl * LORA_SCALE;
  }
  #pragma unroll
  for (int r = 0; r < 16; ++r) {
    mhF[(size_t)(row0 + rb + r)*128 + c] = (f16)acc[r];
  }
}

// ---------------- k5: MFMA probs = softmax(10*tanh(mh@nodes^T/sqrt(128)) + mask) ----------------
// grid (64, 13), 512 thr (8 waves). Block = (b, 16 m-rows); wave covers n-tiles w+8i.
__global__ __launch_bounds__(512) void k5_final(const f16* __restrict__ mhF,
    const f16* __restrict__ nodesF, const float* __restrict__ mask,
    float* __restrict__ out)
{
  __shared__ float sums[8][16];
  const int tid = threadIdx.x, lane = tid & 63, w = tid >> 6;
  const int b = blockIdx.x, mt = blockIdx.y;
  const int col = lane & 15, g = lane >> 4, g4 = g*4;
  const int m = mt*16 + col;
  const int mq = min(m, 199);
  f16x4 bf[8];
  const f16* mb = mhF + (size_t)(b*200 + mq)*128;
  #pragma unroll
  for (int kk = 0; kk < 8; ++kk) bf[kk] = *(const f16x4*)(mb + kk*16 + g4);
  const float* mrow = mask + (size_t)(b*200 + mq)*1000;
  const f16* nb = nodesF + (size_t)b*128000;
  float p[8][4];
  float lsum = 0.f;
  #pragma unroll
  for (int i = 0; i < 8; ++i) {
    const int t = w + i*8;
    if (t < 63) {
      const int nr = min(t*16 + col, 999);
      const f16* na = nb + nr*128;
      f32x4 acc = {0.f, 0.f, 0.f, 0.f};
      #pragma unroll
      for (int kk = 0; kk < 8; ++kk) {
        f16x4 af = *(const f16x4*)(na + kk*16 + g4);
        acc = mfma16(af, bf[kk], acc);
      }
      const int n0 = t*16 + g4;
      float mkv[4] = {0.f, 0.f, 0.f, 0.f};
      if (n0 + 3 < 1000) {
        float4 mk = *(const float4*)(mrow + n0);
        mkv[0] = mk.x; mkv[1] = mk.y; mkv[2] = mk.z; mkv[3] = mk.w;
      }
      #pragma unroll
      for (int r = 0; r < 4; ++r) {
        float x = acc[r] * 0.08838834764831845f;            // /sqrt(128)
        float e = exp2f(x * 2.8853900817779268f);           // e^{2x}
        float th = 1.f - 2.f/(e + 1.f);                     // tanh(x)
        float scv = 10.f*th + mkv[r];
        float pv = exp2f(scv * 1.44269504f);                // no-max softmax: sc <= 10
        pv = (n0 + r < 1000) ? pv : 0.f;
        p[i][r] = pv;
        lsum += pv;
      }
    } else {
      p[i][0] = p[i][1] = p[i][2] = p[i][3] = 0.f;
    }
  }
  lsum += __shfl_xor(lsum, 16, 64);
  lsum += __shfl_xor(lsum, 32, 64);
  if (lane < 16) sums[w][lane] = lsum;
  __syncthreads();
  float S = 0.f;
  #pragma unroll
  for (int ww = 0; ww < 8; ++ww) S += sums[ww][col];
  const float inv = 1.f / S;
  if (m < 200) {
    float* ob = out + (size_t)(b*200 + m)*1000;
    #pragma unroll
    for (int i = 0; i < 8; ++i) {
      const int t = w + i*8;
      if (t < 63) {
        const int n0 = t*16 + g4;
        if (n0 + 3 < 1000) {
          float4 o;
          o.x = p[i][0]*inv; o.y = p[i][1]*inv; o.z = p[i][2]*inv; o.w = p[i][3]*inv;
          *(float4*)(ob + n0) = o;
        } else {
          #pragma unroll
          for (int r = 0; r < 4; ++r) if (n0 + r < 1000) ob[n0+r] = p[i][r]*inv;
        }
      }
    }
  }
}

extern "C" void kernel_launch(void* const* d_in, const int* in_sizes, int n_in,
                              void* d_out, int out_size, void* d_ws, size_t ws_size,
                              hipStream_t stream)
{
  (void)in_sizes; (void)n_in; (void)out_size; (void)ws_size;
  const float* nodes = (const float*)d_in[0];
  const float* q1    = (const float*)d_in[1];
  const float* last  = (const float*)d_in[2];
  const float* mask  = (const float*)d_in[3];
  const float* Wqf   = (const float*)d_in[4];
  const float* Wql   = (const float*)d_in[5];
  const float* Wk    = (const float*)d_in[6];
  const float* Wv    = (const float*)d_in[7];
  const float* Wc    = (const float*)d_in[8];
  const float* bc    = (const float*)d_in[9];
  const float* lqA   = (const float*)d_in[10];
  const float* lqB   = (const float*)d_in[11];
  const float* lcA   = (const float*)d_in[12];
  const float* lcB   = (const float*)d_in[13];
  float* out = (float*)d_out;
  char* ws = (char*)d_ws;
  // ws layout (bytes):
  f16* nodesF = (f16*)(ws);               // 16,384,000
  f16* Kp     = (f16*)(ws + 16384000);    // 16,384,000
  f16* Vt     = (f16*)(ws + 32768000);    // 16,384,000
  f16* qF     = (f16*)(ws + 49152000);    //  3,276,800
  f16* ocF    = (f16*)(ws + 52428800);    //  3,276,800
  f16* mhF    = (f16*)(ws + 55705600);    //  3,276,800
  f16* WkvF   = (f16*)(ws + 58982400);    //     65,536
  float* kmaxA = (float*)(ws + 59047936); //      2,048
  float* qnA   = (float*)(ws + 59049984); //    409,600  (end 59,459,584)

  k0_wconv<<<dim3(32), 256, 0, stream>>>(Wk, Wv, WkvF);
  k1_proj<<<dim3(16, 64), 256, 0, stream>>>(nodes, WkvF, nodesF, Kp, Vt);
  k1b_kmax<<<dim3(512), 256, 0, stream>>>(Kp, kmaxA);
  k2_q<<<dim3(400), 256, 0, stream>>>(q1, last, Wqf, Wql, lqA, lqB, qF);
  k2b_qnorm<<<dim3(400), 256, 0, stream>>>(qF, qnA);
  k3_attn<<<dim3(64, 8), 512, 72448, stream>>>(Kp, Vt, qF, mask, kmaxA, qnA, ocF);
  k4_comb<<<dim3(400), 256, 0, stream>>>(ocF, Wc, bc, lcA, lcB, mhF);
  k5_final<<<dim3(64, 13), 512, 0, stream>>>(mhF, nodesF, mask, out);
}

// Round 8
// 265.625 us; speedup vs baseline: 1.6922x; 1.0008x over previous
//
#include <hip/hip_runtime.h>
#include <hip/hip_bf16.h>

// TSP decoder forward: B=64, POMO=200, N=1000, EMB=128, H=8, D=16.
// k0 W->f16 | k1 MFMA K/V proj + nodes->f16 | k1b kmax | k2 q (+LoRA) | k2b qnorm |
// k3 MFMA flash attention (single-pass, Cauchy-Schwarz max bound, dual m-tile/wave) |
// k4 combine (+LoRA) | k5 MFMA mh@nodes^T + tanh-softmax (f16-packed p, no spill).

typedef _Float16 f16;
typedef _Float16 f16x2 __attribute__((ext_vector_type(2)));
typedef _Float16 f16x4 __attribute__((ext_vector_type(4)));
typedef _Float16 f16x8 __attribute__((ext_vector_type(8)));
typedef __fp16  h4   __attribute__((ext_vector_type(4)));
typedef float   f32x4 __attribute__((ext_vector_type(4)));

#define LORA_SCALE 1.0f

__device__ __forceinline__ f16x2 pk2(f16 a, f16 b){ f16x2 r; r[0]=a; r[1]=b; return r; }

#if __has_builtin(__builtin_amdgcn_fdot2)
__device__ __forceinline__ float fdot2f(f16x2 a, f16x2 b, float c){ return __builtin_amdgcn_fdot2(a, b, c, false); }
#else
__device__ __forceinline__ float fdot2f(f16x2 a, f16x2 b, float c){ return c + (float)a[0]*(float)b[0] + (float)a[1]*(float)b[1]; }
#endif

#if __has_builtin(__builtin_amdgcn_cvt_pkrtz)
__device__ __forceinline__ f16x2 pkrtz(float a, float b){
  return __builtin_bit_cast(f16x2, __builtin_amdgcn_cvt_pkrtz(a, b));
}
#else
__device__ __forceinline__ f16x2 pkrtz(float a, float b){ return pk2((f16)a, (f16)b); }
#endif

// D[i][j] = sum_k A[i][k]*B[k][j] + C  via v_mfma_f32_16x16x16_f16.
// A: lane holds row i=(l&15), k=4*(l>>4)+j. B: lane holds col j=(l&15), k=4*(l>>4)+j.
// D: lane holds col j=(l&15), row i=4*(l>>4)+reg.   (validated end-to-end in k3/k5)
__device__ __forceinline__ f32x4 mfma16(f16x4 a, f16x4 b, f32x4 c){
  return __builtin_amdgcn_mfma_f32_16x16x16f16(
      __builtin_bit_cast(h4, a), __builtin_bit_cast(h4, b), c, 0, 0, 0);
}

__device__ __forceinline__ float sumsq16(const f16* p){
  const f16x8* v = (const f16x8*)p;
  f16x8 a = v[0], b = v[1];
  float s = 0.f;
  s = fdot2f(pk2(a[0],a[1]), pk2(a[0],a[1]), s);
  s = fdot2f(pk2(a[2],a[3]), pk2(a[2],a[3]), s);
  s = fdot2f(pk2(a[4],a[5]), pk2(a[4],a[5]), s);
  s = fdot2f(pk2(a[6],a[7]), pk2(a[6],a[7]), s);
  s = fdot2f(pk2(b[0],b[1]), pk2(b[0],b[1]), s);
  s = fdot2f(pk2(b[2],b[3]), pk2(b[2],b[3]), s);
  s = fdot2f(pk2(b[4],b[5]), pk2(b[4],b[5]), s);
  s = fdot2f(pk2(b[6],b[7]), pk2(b[6],b[7]), s);
  return s;
}

// ---------------- k0: Wk|Wv -> f16 [256][128] ----------------
__global__ __launch_bounds__(256) void k0_wconv(const float* __restrict__ Wk,
    const float* __restrict__ Wv, f16* __restrict__ WkvF)
{
  const int i = blockIdx.x*256 + threadIdx.x;           // 0..8191, one f32x4 each
  const float4 v = (i < 4096) ? ((const float4*)Wk)[i] : ((const float4*)Wv)[i-4096];
  f16x2 lo = pkrtz(v.x,v.y), hi = pkrtz(v.z,v.w);
  f16x4 o = __builtin_shufflevector(lo, hi, 0, 1, 2, 3);
  *(f16x4*)(WkvF + i*4) = o;
}

// ---------------- k1: MFMA K/V projection + nodes -> f16 ----------------
// grid (16, 64), 256 thr (4 waves), 64 node rows per block.
// Kp: [bh][n(1000)][16] ; Vt: [bh][d(16)][n(1000)]
#define NSTR 132
__global__ __launch_bounds__(256) void k1_proj(const float* __restrict__ nodes,
    const f16* __restrict__ WkvF,
    f16* __restrict__ nodesF, f16* __restrict__ Kp, f16* __restrict__ Vt)
{
  __shared__ f16 lds[64*NSTR];
  const int tid = threadIdx.x, lane = tid & 63, w = tid >> 6;
  const int b = blockIdx.y;
  const int n0 = blockIdx.x * 64;
  const int rows = min(64, 1000 - n0);                  // 64 or 40
  for (int i = tid; i < rows*32; i += 256) {            // 32 f32x4 per row
    const int r = i >> 5, cq = i & 31;
    float4 v = ((const float4*)(nodes + ((size_t)b*1000 + n0 + r)*128))[cq];
    f16x2 lo = pkrtz(v.x,v.y), hi = pkrtz(v.z,v.w);
    f16x4 o = __builtin_shufflevector(lo, hi, 0, 1, 2, 3);
    *(f16x4*)(lds + r*NSTR + cq*4) = o;
    *(f16x4*)(nodesF + ((size_t)b*1000 + n0 + r)*128 + cq*4) = o;
  }
  __syncthreads();
  const int col = lane & 15, g = lane >> 4, g4 = g*4;
  const int mloc = w*16 + col;                          // wave-local node row (as frag row/col)
  f16x4 nf[8];
  #pragma unroll
  for (int kk = 0; kk < 8; ++kk)
    nf[kk] = *(const f16x4*)(lds + min(mloc, rows-1)*NSTR + kk*16 + g4);
  for (int ct = 0; ct < 16; ++ct) {
    f16x4 wf[8];
    const f16* wbase = WkvF + (ct*16 + col)*128;
    #pragma unroll
    for (int kk = 0; kk < 8; ++kk) wf[kk] = *(const f16x4*)(wbase + kk*16 + g4);
    f32x4 acc = {0.f, 0.f, 0.f, 0.f};
    if (ct < 8) {                                       // K-head ct: D[c][m]
      #pragma unroll
      for (int kk = 0; kk < 8; ++kk) acc = mfma16(wf[kk], nf[kk], acc);
      if (mloc < rows) {
        const int nn = n0 + mloc;
        f16x4 ov = __builtin_shufflevector(pk2((f16)acc[0],(f16)acc[1]),
                                           pk2((f16)acc[2],(f16)acc[3]), 0,1,2,3);
        *(f16x4*)(Kp + ((size_t)(b*8+ct)*1000 + nn)*16 + g4) = ov;
      }
    } else {                                            // V-head ct-8: D[m][c]
      #pragma unroll
      for (int kk = 0; kk < 8; ++kk) acc = mfma16(nf[kk], wf[kk], acc);
      if (w*16 + g4 + 3 < rows) {
        const int nbase = n0 + w*16 + g4;
        f16x4 ov = __builtin_shufflevector(pk2((f16)acc[0],(f16)acc[1]),
                                           pk2((f16)acc[2],(f16)acc[3]), 0,1,2,3);
        *(f16x4*)(Vt + ((size_t)(b*8+(ct-8))*16 + col)*1000 + nbase) = ov;
      }
    }
  }
}

// ---------------- k1b: kmax[bh] = max_n ||Kp[bh][n]|| ----------------
__global__ __launch_bounds__(256) void k1b_kmax(const f16* __restrict__ Kp,
    float* __restrict__ kmaxA)
{
  __shared__ float wmax[4];
  const int bh = blockIdx.x, tid = threadIdx.x, lane = tid & 63, w = tid >> 6;
  const f16* base = Kp + (size_t)bh*16000;
  float mx = 0.f;
  for (int n = tid; n < 1000; n += 256) mx = fmaxf(mx, sumsq16(base + n*16));
  #pragma unroll
  for (int off = 32; off; off >>= 1) mx = fmaxf(mx, __shfl_xor(mx, off, 64));
  if (lane == 0) wmax[w] = mx;
  __syncthreads();
  if (tid == 0) {
    float m = fmaxf(fmaxf(wmax[0], wmax[1]), fmaxf(wmax[2], wmax[3]));
    kmaxA[bh] = sqrtf(m);
  }
}

// ---------------- k2: q = q1@Wqf^T + last@Wql^T + LoRA ----------------
// grid 400, 256 thr, 32 rows/block. qF layout: [bh][m(200)][16]
__global__ __launch_bounds__(256) void k2_q(const float* __restrict__ q1,
    const float* __restrict__ last, const float* __restrict__ Wqf,
    const float* __restrict__ Wql, const float* __restrict__ lqA,
    const float* __restrict__ lqB, f16* __restrict__ qF)
{
  __shared__ f16 q1r[32*128];
  __shared__ f16 lar[32*128];
  __shared__ float t16[32*16];
  const int tid = threadIdx.x;
  const int row0 = blockIdx.x * 32;
  {
    const float4* s1 = (const float4*)(q1 + (size_t)row0*128);
    const float4* s2 = (const float4*)(last + (size_t)row0*128);
    f16x2* d1 = (f16x2*)q1r; f16x2* d2 = (f16x2*)lar;
    for (int i = tid; i < 32*32; i += 256) {
      float4 v = s1[i];
      d1[2*i] = pkrtz(v.x,v.y); d1[2*i+1] = pkrtz(v.z,v.w);
      float4 u = s2[i];
      d2[2*i] = pkrtz(u.x,u.y); d2[2*i+1] = pkrtz(u.z,u.w);
    }
  }
  __syncthreads();
  for (int idx = tid; idx < 32*16; idx += 256) {
    const int r = idx >> 4, kk = idx & 15;
    const f16x8* lrow = (const f16x8*)(lar + r*128);
    const float* arow = lqA + kk*128;
    float s = 0.f;
    #pragma unroll
    for (int cc = 0; cc < 16; ++cc) {
      f16x8 a = lrow[cc];
      float4 wa = *(const float4*)(arow + cc*8);
      float4 wb = *(const float4*)(arow + cc*8 + 4);
      s = fdot2f(pk2(a[0],a[1]), pkrtz(wa.x,wa.y), s);
      s = fdot2f(pk2(a[2],a[3]), pkrtz(wa.z,wa.w), s);
      s = fdot2f(pk2(a[4],a[5]), pkrtz(wb.x,wb.y), s);
      s = fdot2f(pk2(a[6],a[7]), pkrtz(wb.z,wb.w), s);
    }
    t16[idx] = s;
  }
  __syncthreads();
  const int c = tid & 127, rg = tid >> 7, rb = rg*16;
  float acc[16];
  #pragma unroll
  for (int r = 0; r < 16; ++r) acc[r] = 0.f;
  const float* wfr = Wqf + c*128;
  const float* wlr = Wql + c*128;
  for (int c0 = 0; c0 < 128; c0 += 16) {
    float4 f0 = *(const float4*)(wfr + c0);
    float4 f1 = *(const float4*)(wfr + c0 + 4);
    float4 f2 = *(const float4*)(wfr + c0 + 8);
    float4 f3 = *(const float4*)(wfr + c0 + 12);
    f16x2 wf[8] = { pkrtz(f0.x,f0.y), pkrtz(f0.z,f0.w), pkrtz(f1.x,f1.y), pkrtz(f1.z,f1.w),
                    pkrtz(f2.x,f2.y), pkrtz(f2.z,f2.w), pkrtz(f3.x,f3.y), pkrtz(f3.z,f3.w) };
    float4 g0 = *(const float4*)(wlr + c0);
    float4 g1 = *(const float4*)(wlr + c0 + 4);
    float4 g2 = *(const float4*)(wlr + c0 + 8);
    float4 g3 = *(const float4*)(wlr + c0 + 12);
    f16x2 wl[8] = { pkrtz(g0.x,g0.y), pkrtz(g0.z,g0.w), pkrtz(g1.x,g1.y), pkrtz(g1.z,g1.w),
                    pkrtz(g2.x,g2.y), pkrtz(g2.z,g2.w), pkrtz(g3.x,g3.y), pkrtz(g3.z,g3.w) };
    #pragma unroll
    for (int r = 0; r < 16; ++r) {
      const f16x8* qp = (const f16x8*)(q1r + (rb+r)*128 + c0);
      const f16x8* lp = (const f16x8*)(lar + (rb+r)*128 + c0);
      f16x8 a0 = qp[0], a1 = qp[1], b0 = lp[0], b1 = lp[1];
      float s = acc[r];
      s = fdot2f(pk2(a0[0],a0[1]), wf[0], s);
      s = fdot2f(pk2(a0[2],a0[3]), wf[1], s);
      s = fdot2f(pk2(a0[4],a0[5]), wf[2], s);
      s = fdot2f(pk2(a0[6],a0[7]), wf[3], s);
      s = fdot2f(pk2(a1[0],a1[1]), wf[4], s);
      s = fdot2f(pk2(a1[2],a1[3]), wf[5], s);
      s = fdot2f(pk2(a1[4],a1[5]), wf[6], s);
      s = fdot2f(pk2(a1[6],a1[7]), wf[7], s);
      s = fdot2f(pk2(b0[0],b0[1]), wl[0], s);
      s = fdot2f(pk2(b0[2],b0[3]), wl[1], s);
      s = fdot2f(pk2(b0[4],b0[5]), wl[2], s);
      s = fdot2f(pk2(b0[6],b0[7]), wl[3], s);
      s = fdot2f(pk2(b1[0],b1[1]), wl[4], s);
      s = fdot2f(pk2(b1[2],b1[3]), wl[5], s);
      s = fdot2f(pk2(b1[4],b1[5]), wl[6], s);
      s = fdot2f(pk2(b1[6],b1[7]), wl[7], s);
      acc[r] = s;
    }
  }
  const float* lb = lqB + c*16;
  float lbv[16];
  #pragma unroll
  for (int i = 0; i < 16; i += 4) {
    float4 t = *(const float4*)(lb + i);
    lbv[i] = t.x; lbv[i+1] = t.y; lbv[i+2] = t.z; lbv[i+3] = t.w;
  }
  #pragma unroll
  for (int r = 0; r < 16; ++r) {
    float dl = 0.f;
    #pragma unroll
    for (int kk = 0; kk < 16; ++kk) dl += t16[(rb+r)*16 + kk] * lbv[kk];
    acc[r] += dl * LORA_SCALE;
  }
  const int h = c >> 4, d = c & 15;
  #pragma unroll
  for (int r = 0; r < 16; ++r) {
    const int grow = row0 + rb + r;
    const int b = grow / 200, m = grow % 200;
    qF[(((size_t)b*8 + h)*200 + m)*16 + d] = (f16)acc[r];
  }
}

// ---------------- k2b: qn[bh][m] = ||qF[bh][m]|| ----------------
__global__ __launch_bounds__(256) void k2b_qnorm(const f16* __restrict__ qF,
    float* __restrict__ qnA)
{
  const int idx = blockIdx.x*256 + threadIdx.x;         // 0..102399
  qnA[idx] = sqrtf(sumsq16(qF + (size_t)idx*16));
}

// ---------------- k3: per-(b,h) MFMA attention, single-pass with norm bound ----------------
// grid (64,8), 512 thr (8 waves). Wave w handles m-tiles (2w, 2w+1) fused in one loop.
#define KSTR 20
#define VSTR 1004
__global__ __launch_bounds__(512) void k3_attn(const f16* __restrict__ Kp,
    const f16* __restrict__ Vt, const f16* __restrict__ qF,
    const float* __restrict__ mask, const float* __restrict__ kmaxA,
    const float* __restrict__ qnA, f16* __restrict__ ocF)
{
  extern __shared__ char smem[];
  f16* Kl = (f16*)smem;                     // [1008][KSTR] : 40320 B
  f16* Vl = (f16*)(smem + 1008*KSTR*2);     // [16][VSTR]   : 32128 B
  const int tid = threadIdx.x;
  const int lane = tid & 63, w = tid >> 6;
  const int b = blockIdx.x, h = blockIdx.y;
  const int bh = b*8 + h;
  for (int n = tid; n < 1008; n += 512) {
    f16x4 zf = {};
    f16x4 v0 = zf, v1 = zf, v2 = zf, v3 = zf;
    if (n < 1000) {
      const f16x4* src = (const f16x4*)(Kp + (size_t)bh*16000 + n*16);
      v0 = src[0]; v1 = src[1]; v2 = src[2]; v3 = src[3];
    }
    f16* dst = Kl + n*KSTR;
    *(f16x4*)(dst)    = v0;
    *(f16x4*)(dst+4)  = v1;
    *(f16x4*)(dst+8)  = v2;
    *(f16x4*)(dst+12) = v3;
  }
  for (int i = tid; i < 2000; i += 512) {
    const int d = i / 125, c8 = i - d*125;
    const f16x4* src = (const f16x4*)(Vt + (size_t)bh*16000 + d*1000 + c8*8);
    f16* dst = Vl + d*VSTR + c8*8;
    *(f16x4*)(dst)   = src[0];
    *(f16x4*)(dst+4) = src[1];
  }
  if (tid < 64) { const int d = tid >> 2, e = 1000 + (tid & 3); Vl[d*VSTR + e] = (f16)0; }
  __syncthreads();

  const int col = lane & 15, g = lane >> 4, g4 = g*4;
  const f32x4 zero = {0.f, 0.f, 0.f, 0.f};
  const int tA = min(2*w, 12), tB = min(2*w + 1, 12);   // waves 6,7 duplicate tile 12 (benign)
  const int mA = tA*16, mB = tB*16;
  const int mqA = min(mA + col, 199), mqB = min(mB + col, 199);
  const f16x4 qfA = *(const f16x4*)(qF + (size_t)bh*3200 + mqA*16 + g4);
  const f16x4 qfB = *(const f16x4*)(qF + (size_t)bh*3200 + mqB*16 + g4);
  const float kmx = kmaxA[bh];
  const float mbA = -kmx * qnA[bh*200 + mqA] * 0.360673760f;
  const float mbB = -kmx * qnA[bh*200 + mqB] * 0.360673760f;
  const float* mpA = mask + ((size_t)b*200 + mqA)*1000;
  const float* mpB = mask + ((size_t)b*200 + mqB)*1000;

  f32x4 OA = zero, OB = zero;
  float lA0=0.f, lA1=0.f, lA2=0.f, lA3=0.f;
  float lB0=0.f, lB1=0.f, lB2=0.f, lB3=0.f;
  #pragma unroll 2
  for (int t = 0; t < 62; ++t) {
    const int n0 = t*16 + g4;
    const f16x4 kf = *(const f16x4*)(Kl + (t*16+col)*KSTR + g4);
    f32x4 sA = mfma16(kf, qfA, zero);
    f32x4 sB = mfma16(kf, qfB, zero);
    const float4 mkA = *(const float4*)(mpA + n0);
    const float4 mkB = *(const float4*)(mpB + n0);
    const float pA0 = exp2f(fmaf(sA[0], 0.360673760f, fmaf(mkA.x, 1.44269504f, mbA)));
    const float pA1 = exp2f(fmaf(sA[1], 0.360673760f, fmaf(mkA.y, 1.44269504f, mbA)));
    const float pA2 = exp2f(fmaf(sA[2], 0.360673760f, fmaf(mkA.z, 1.44269504f, mbA)));
    const float pA3 = exp2f(fmaf(sA[3], 0.360673760f, fmaf(mkA.w, 1.44269504f, mbA)));
    const float pB0 = exp2f(fmaf(sB[0], 0.360673760f, fmaf(mkB.x, 1.44269504f, mbB)));
    const float pB1 = exp2f(fmaf(sB[1], 0.360673760f, fmaf(mkB.y, 1.44269504f, mbB)));
    const float pB2 = exp2f(fmaf(sB[2], 0.360673760f, fmaf(mkB.z, 1.44269504f, mbB)));
    const float pB3 = exp2f(fmaf(sB[3], 0.360673760f, fmaf(mkB.w, 1.44269504f, mbB)));
    lA0 += pA0; lA1 += pA1; lA2 += pA2; lA3 += pA3;
    lB0 += pB0; lB1 += pB1; lB2 += pB2; lB3 += pB3;
    const f16x4 pfA = __builtin_shufflevector(pkrtz(pA0,pA1), pkrtz(pA2,pA3), 0,1,2,3);
    const f16x4 pfB = __builtin_shufflevector(pkrtz(pB0,pB1), pkrtz(pB2,pB3), 0,1,2,3);
    const f16x4 vf = *(const f16x4*)(Vl + col*VSTR + n0);
    OA = mfma16(vf, pfA, OA);
    OB = mfma16(vf, pfB, OB);
  }
  { // t = 62 tail: n = 992+g4+r valid only for g<2
    const int n0 = 62*16 + g4;
    const f16x4 kf = *(const f16x4*)(Kl + (62*16+col)*KSTR + g4);
    f32x4 sA = mfma16(kf, qfA, zero);
    f32x4 sB = mfma16(kf, qfB, zero);
    float pA0=0.f,pA1=0.f,pA2=0.f,pA3=0.f, pB0=0.f,pB1=0.f,pB2=0.f,pB3=0.f;
    if (g < 2) {
      const float4 mkA = *(const float4*)(mpA + n0);
      const float4 mkB = *(const float4*)(mpB + n0);
      pA0 = exp2f(fmaf(sA[0], 0.360673760f, fmaf(mkA.x, 1.44269504f, mbA)));
      pA1 = exp2f(fmaf(sA[1], 0.360673760f, fmaf(mkA.y, 1.44269504f, mbA)));
      pA2 = exp2f(fmaf(sA[2], 0.360673760f, fmaf(mkA.z, 1.44269504f, mbA)));
      pA3 = exp2f(fmaf(sA[3], 0.360673760f, fmaf(mkA.w, 1.44269504f, mbA)));
      pB0 = exp2f(fmaf(sB[0], 0.360673760f, fmaf(mkB.x, 1.44269504f, mbB)));
      pB1 = exp2f(fmaf(sB[1], 0.360673760f, fmaf(mkB.y, 1.44269504f, mbB)));
      pB2 = exp2f(fmaf(sB[2], 0.360673760f, fmaf(mkB.z, 1.44269504f, mbB)));
      pB3 = exp2f(fmaf(sB[3], 0.360673760f, fmaf(mkB.w, 1.44269504f, mbB)));
      lA0 += pA0; lA1 += pA1; lA2 += pA2; lA3 += pA3;
      lB0 += pB0; lB1 += pB1; lB2 += pB2; lB3 += pB3;
    }
    const f16x4 pfA = __builtin_shufflevector(pkrtz(pA0,pA1), pkrtz(pA2,pA3), 0,1,2,3);
    const f16x4 pfB = __builtin_shufflevector(pkrtz(pB0,pB1), pkrtz(pB2,pB3), 0,1,2,3);
    const f16x4 vf = *(const f16x4*)(Vl + col*VSTR + ((g < 2) ? n0 : 0));
    OA = mfma16(vf, pfA, OA);
    OB = mfma16(vf, pfB, OB);
  }
  float lA = (lA0 + lA1) + (lA2 + lA3);
  float lB = (lB0 + lB1) + (lB2 + lB3);
  lA += __shfl_xor(lA, 16, 64); lA += __shfl_xor(lA, 32, 64);
  lB += __shfl_xor(lB, 16, 64); lB += __shfl_xor(lB, 32, 64);
  const float invA = 1.f / fmaxf(lA, 1e-35f);
  const float invB = 1.f / fmaxf(lB, 1e-35f);
  if (mA + col < 200) {
    const f16x4 ov = __builtin_shufflevector(pkrtz(OA[0]*invA, OA[1]*invA),
                                             pkrtz(OA[2]*invA, OA[3]*invA), 0,1,2,3);
    *(f16x4*)(ocF + ((size_t)b*200 + mA + col)*128 + h*16 + g4) = ov;
  }
  if (mB + col < 200) {
    const f16x4 ov = __builtin_shufflevector(pkrtz(OB[0]*invB, OB[1]*invB),
                                             pkrtz(OB[2]*invB, OB[3]*invB), 0,1,2,3);
    *(f16x4*)(ocF + ((size_t)b*200 + mB + col)*128 + h*16 + g4) = ov;
  }
}

// ---------------- k4: mh = oc@Wc^T + bc + LoRA ----------------
__global__ __launch_bounds__(256) void k4_comb(const f16* __restrict__ ocF,
    const float* __restrict__ Wc, const float* __restrict__ bc,
    const float* __restrict__ lcA, const float* __restrict__ lcB,
    f16* __restrict__ mhF)
{
  __shared__ f16 ocr[32*128];
  __shared__ float t16[32*16];
  const int tid = threadIdx.x;
  const int row0 = blockIdx.x * 32;
  {
    const f16x8* s1 = (const f16x8*)(ocF + (size_t)row0*128);
    f16x8* d1 = (f16x8*)ocr;
    for (int i = tid; i < 512; i += 256) d1[i] = s1[i];
  }
  __syncthreads();
  for (int idx = tid; idx < 32*16; idx += 256) {
    const int r = idx >> 4, kk = idx & 15;
    const f16x8* lrow = (const f16x8*)(ocr + r*128);
    const float* arow = lcA + kk*128;
    float s = 0.f;
    #pragma unroll
    for (int cc = 0; cc < 16; ++cc) {
      f16x8 a = lrow[cc];
      float4 wa = *(const float4*)(arow + cc*8);
      float4 wb = *(const float4*)(arow + cc*8 + 4);
      s = fdot2f(pk2(a[0],a[1]), pkrtz(wa.x,wa.y), s);
      s = fdot2f(pk2(a[2],a[3]), pkrtz(wa.z,wa.w), s);
      s = fdot2f(pk2(a[4],a[5]), pkrtz(wb.x,wb.y), s);
      s = fdot2f(pk2(a[6],a[7]), pkrtz(wb.z,wb.w), s);
    }
    t16[idx] = s;
  }
  __syncthreads();
  const int c = tid & 127, rg = tid >> 7, rb = rg*16;
  float acc[16];
  const float bias = bc[c];
  #pragma unroll
  for (int r = 0; r < 16; ++r) acc[r] = bias;
  const float* wrow = Wc + c*128;
  for (int c0 = 0; c0 < 128; c0 += 16) {
    float4 w0 = *(const float4*)(wrow + c0);
    float4 w1 = *(const float4*)(wrow + c0 + 4);
    float4 w2 = *(const float4*)(wrow + c0 + 8);
    float4 w3 = *(const float4*)(wrow + c0 + 12);
    f16x2 wv[8] = { pkrtz(w0.x,w0.y), pkrtz(w0.z,w0.w), pkrtz(w1.x,w1.y), pkrtz(w1.z,w1.w),
                    pkrtz(w2.x,w2.y), pkrtz(w2.z,w2.w), pkrtz(w3.x,w3.y), pkrtz(w3.z,w3.w) };
    #pragma unroll
    for (int r = 0; r < 16; ++r) {
      const f16x8* op = (const f16x8*)(ocr + (rb+r)*128 + c0);
      f16x8 a0 = op[0], a1 = op[1];
      float s = acc[r];
      s = fdot2f(pk2(a0[0],a0[1]), wv[0], s);
      s = fdot2f(pk2(a0[2],a0[3]), wv[1], s);
      s = fdot2f(pk2(a0[4],a0[5]), wv[2], s);
      s = fdot2f(pk2(a0[6],a0[7]), wv[3], s);
      s = fdot2f(pk2(a1[0],a1[1]), wv[4], s);
      s = fdot2f(pk2(a1[2],a1[3]), wv[5], s);
      s = fdot2f(pk2(a1[4],a1[5]), wv[6], s);
      s = fdot2f(pk2(a1[6],a1[7]), wv[7], s);
      acc[r] = s;
    }
  }
  const float* lb = lcB + c*16;
  float lbv[16];
  #pragma unroll
  for (int i = 0; i < 16; i += 4) {
    float4 t = *(const float4*)(lb + i);
    lbv[i] = t.x; lbv[i+1] = t.y; lbv[i+2] = t.z; lbv[i+3] = t.w;
  }
  #pragma unroll
  for (int r = 0; r < 16; ++r) {
    float dl = 0.f;
    #pragma unroll
    for (int kk = 0; kk < 16; ++kk) dl += t16[(rb+r)*16 + kk] * lbv[kk];
    acc[r] += dl * LORA_SCALE;
  }
  #pragma unroll
  for (int r = 0; r < 16; ++r) {
    mhF[(size_t)(row0 + rb + r)*128 + c] = (f16)acc[r];
  }
}

// ---------------- k5: MFMA probs = softmax(10*tanh(mh@nodes^T/sqrt(128)) + mask) ----------------
// grid (64, 13), 512 thr (8 waves). Block = (b, 16 m-rows); wave covers n-tiles w+8i.
// Unnormalized exps kept as PACKED F16 (pf[8] = 8 VGPRs, not 32) -> no scratch spill,
// leaves registers for the 8 independent MFMA chains to pipeline.
__global__ __launch_bounds__(512) void k5_final(const f16* __restrict__ mhF,
    const f16* __restrict__ nodesF, const float* __restrict__ mask,
    float* __restrict__ out)
{
  __shared__ float sums[8][16];
  const int tid = threadIdx.x, lane = tid & 63, w = tid >> 6;
  const int b = blockIdx.x, mt = blockIdx.y;
  const int col = lane & 15, g = lane >> 4, g4 = g*4;
  const int m = mt*16 + col;
  const int mq = min(m, 199);
  f16x4 bf[8];
  const f16* mb = mhF + (size_t)(b*200 + mq)*128;
  #pragma unroll
  for (int kk = 0; kk < 8; ++kk) bf[kk] = *(const f16x4*)(mb + kk*16 + g4);
  const float* mrow = mask + (size_t)(b*200 + mq)*1000;
  const f16* nb = nodesF + (size_t)b*128000;
  f16x4 pf[8];
  float lsum = 0.f;
  #pragma unroll
  for (int i = 0; i < 8; ++i) {
    const int t = w + i*8;
    float p0 = 0.f, p1 = 0.f, p2 = 0.f, p3 = 0.f;
    if (t < 63) {
      const int nr = min(t*16 + col, 999);
      const f16* na = nb + nr*128;
      f32x4 acc = {0.f, 0.f, 0.f, 0.f};
      #pragma unroll
      for (int kk = 0; kk < 8; ++kk) {
        f16x4 af = *(const f16x4*)(na + kk*16 + g4);
        acc = mfma16(af, bf[kk], acc);
      }
      const int n0 = t*16 + g4;
      float mkv[4] = {0.f, 0.f, 0.f, 0.f};
      if (n0 + 3 < 1000) {
        float4 mk = *(const float4*)(mrow + n0);
        mkv[0] = mk.x; mkv[1] = mk.y; mkv[2] = mk.z; mkv[3] = mk.w;
      }
      float pv[4];
      #pragma unroll
      for (int r = 0; r < 4; ++r) {
        float x = acc[r] * 0.08838834764831845f;            // /sqrt(128)
        float e = exp2f(x * 2.8853900817779268f);           // e^{2x}
        float th = 1.f - 2.f/(e + 1.f);                     // tanh(x)
        float scv = 10.f*th + mkv[r];
        float t0 = exp2f(scv * 1.44269504f);                // no-max softmax: sc <= 10
        pv[r] = (n0 + r < 1000) ? t0 : 0.f;
        lsum += pv[r];
      }
      p0 = pv[0]; p1 = pv[1]; p2 = pv[2]; p3 = pv[3];
    }
    pf[i] = __builtin_shufflevector(pkrtz(p0, p1), pkrtz(p2, p3), 0, 1, 2, 3);
  }
  lsum += __shfl_xor(lsum, 16, 64);
  lsum += __shfl_xor(lsum, 32, 64);
  if (lane < 16) sums[w][lane] = lsum;
  __syncthreads();
  float S = 0.f;
  #pragma unroll
  for (int ww = 0; ww < 8; ++ww) S += sums[ww][col];
  const float inv = 1.f / S;
  if (m < 200) {
    float* ob = out + (size_t)(b*200 + m)*1000;
    #pragma unroll
    for (int i = 0; i < 8; ++i) {
      const int t = w + i*8;
      if (t < 63) {
        const int n0 = t*16 + g4;
        const f16x4 pv = pf[i];
        if (n0 + 3 < 1000) {
          float4 o;
          o.x = (float)pv[0]*inv; o.y = (float)pv[1]*inv;
          o.z = (float)pv[2]*inv; o.w = (float)pv[3]*inv;
          *(float4*)(ob + n0) = o;
        } else {
          #pragma unroll
          for (int r = 0; r < 4; ++r) if (n0 + r < 1000) ob[n0+r] = (float)pv[r]*inv;
        }
      }
    }
  }
}

extern "C" void kernel_launch(void* const* d_in, const int* in_sizes, int n_in,
                              void* d_out, int out_size, void* d_ws, size_t ws_size,
                              hipStream_t stream)
{
  (void)in_sizes; (void)n_in; (void)out_size; (void)ws_size;
  const float* nodes = (const float*)d_in[0];
  const float* q1    = (const float*)d_in[1];
  const float* last  = (const float*)d_in[2];
  const float* mask  = (const float*)d_in[3];
  const float* Wqf   = (const float*)d_in[4];
  const float* Wql   = (const float*)d_in[5];
  const float* Wk    = (const float*)d_in[6];
  const float* Wv    = (const float*)d_in[7];
  const float* Wc    = (const float*)d_in[8];
  const float* bc    = (const float*)d_in[9];
  const float* lqA   = (const float*)d_in[10];
  const float* lqB   = (const float*)d_in[11];
  const float* lcA   = (const float*)d_in[12];
  const float* lcB   = (const float*)d_in[13];
  float* out = (float*)d_out;
  char* ws = (char*)d_ws;
  // ws layout (bytes):
  f16* nodesF = (f16*)(ws);               // 16,384,000
  f16* Kp     = (f16*)(ws + 16384000);    // 16,384,000
  f16* Vt     = (f16*)(ws + 32768000);    // 16,384,000
  f16* qF     = (f16*)(ws + 49152000);    //  3,276,800
  f16* ocF    = (f16*)(ws + 52428800);    //  3,276,800
  f16* mhF    = (f16*)(ws + 55705600);    //  3,276,800
  f16* WkvF   = (f16*)(ws + 58982400);    //     65,536
  float* kmaxA = (float*)(ws + 59047936); //      2,048
  float* qnA   = (float*)(ws + 59049984); //    409,600  (end 59,459,584)

  k0_wconv<<<dim3(32), 256, 0, stream>>>(Wk, Wv, WkvF);
  k1_proj<<<dim3(16, 64), 256, 0, stream>>>(nodes, WkvF, nodesF, Kp, Vt);
  k1b_kmax<<<dim3(512), 256, 0, stream>>>(Kp, kmaxA);
  k2_q<<<dim3(400), 256, 0, stream>>>(q1, last, Wqf, Wql, lqA, lqB, qF);
  k2b_qnorm<<<dim3(400), 256, 0, stream>>>(qF, qnA);
  k3_attn<<<dim3(64, 8), 512, 72448, stream>>>(Kp, Vt, qF, mask, kmaxA, qnA, ocF);
  k4_comb<<<dim3(400), 256, 0, stream>>>(ocF, Wc, bc, lcA, lcB, mhF);
  k5_final<<<dim3(64, 13), 512, 0, stream>>>(mhF, nodesF, mask, out);
}